// Round 1
// 676.529 us; speedup vs baseline: 2.8934x; 2.8934x over previous
//
#include <hip/hip_runtime.h>
#include <hip/hip_bf16.h>

typedef __hip_bfloat16 bf16;
typedef _Float16 f16;
typedef __attribute__((ext_vector_type(8))) short short8;
typedef __attribute__((ext_vector_type(4))) float f32x4;
typedef __attribute__((ext_vector_type(8))) _Float16 f16x8;
typedef __attribute__((ext_vector_type(4))) _Float16 f16x4;

#define Q_LEN 1024
#define B_SZ 4
#define DM 1024
#define H_CNT 16
#define HD 64
#define MEM_LEN 512
#define KLEN 1536
#define MLP 4096

__device__ __forceinline__ void store_c(float* p, float v) { *p = v; }
__device__ __forceinline__ void store_c(bf16* p, float v) { *p = __float2bfloat16(v); }
__device__ __forceinline__ void store_c(f16* p, float v) { *p = (f16)v; }

__device__ __forceinline__ float b2f(short s) {
  union { unsigned u; float f; } x;
  x.u = ((unsigned)(unsigned short)s) << 16;
  return x.f;
}
__device__ __forceinline__ short f2b(float f) {
  union { float f; unsigned u; } x;
  x.f = f;
  unsigned r = x.u + 0x7fff + ((x.u >> 16) & 1);  // RNE; inputs finite
  return (short)(r >> 16);
}

// async global->LDS, 16B per lane; LDS dest = wave-uniform base + lane*16
__device__ __forceinline__ void gload16(const void* g, void* l) {
  __builtin_amdgcn_global_load_lds(
      (__attribute__((address_space(1))) unsigned int*)(g),
      (__attribute__((address_space(3))) unsigned int*)(l), 16, 0, 0);
}

// ---------------- fp32 -> fp16 elementwise convert ----------------
__global__ __launch_bounds__(256) void convh_kernel(
    const float* __restrict__ X, f16* __restrict__ Y, int n4) {
  const int i = blockIdx.x * 256 + threadIdx.x;
  if (i < n4) {
    f32x4 v = *(const f32x4*)&X[(size_t)i * 4];
    f16x4 h;
#pragma unroll
    for (int j = 0; j < 4; ++j) h[j] = (f16)v[j];
    *(f16x4*)&Y[(size_t)i * 4] = h;
  }
}

// ---------------- fp32 [K][N] -> fp16 transposed [N][K] ----------------
__global__ __launch_bounds__(256) void convT_kernel(
    const float* __restrict__ W, f16* __restrict__ WT, int K, int N) {
  __shared__ float tile[64][65];
  const int tid = threadIdx.x;
  const int k0 = blockIdx.y * 64, n0 = blockIdx.x * 64;
  const int tn = tid & 63, tk4 = tid >> 6;
#pragma unroll
  for (int p = 0; p < 16; ++p) {
    const int kk = tk4 + p * 4;
    tile[kk][tn] = W[(size_t)(k0 + kk) * N + n0 + tn];
  }
  __syncthreads();
#pragma unroll
  for (int p = 0; p < 16; ++p) {
    const int nn = tk4 + p * 4;
    WT[(size_t)(n0 + nn) * K + k0 + tn] = (f16)tile[tn][nn];
  }
}

// ---------------- fp16 MFMA GEMM: C = A[M,K] * BT[N,K]^T ----------------
// 128x128 tile, BK=32, 4 waves in 2x2 (each owns 64x64), 16x16x32_f16 MFMA.
// LDS: double-buffered A/B tiles [128][32] f16, row stride 64B.
// Chunk swizzle: LDS row rt, 16B chunk c holds global k-chunk c ^ ((rt>>1)&3)
// (pre-swizzled global source; linear LDS dest for global_load_lds; same XOR
//  on ds_read addr) -> service-order-balanced banks on ds_read_b128.
// Row split: blocks with row0 >= split use (Aalt, Calt) with row0-split.
template <typename TC>
__global__ __launch_bounds__(256, 2) void hgemm_kernel(
    const f16* __restrict__ A, const f16* __restrict__ BT, TC* __restrict__ C,
    int M, int N, int K, const float* __restrict__ bias, int relu,
    const f16* __restrict__ Aalt, TC* __restrict__ Calt, int split) {
  __shared__ __align__(16) f16 sA[2][128 * 32];
  __shared__ __align__(16) f16 sB[2][128 * 32];
  const int tid = threadIdx.x;
  const int w = tid >> 6, lane = tid & 63;
  const int quad = lane >> 4, m16 = lane & 15;
  const int wr = w >> 1, wc = w & 1;
  const int col0 = blockIdx.x * 128;
  int r0 = blockIdx.y * 128;
  const f16* Ause = A;
  TC* Cuse = C;
  if (r0 >= split) { Ause = Aalt; Cuse = Calt; r0 -= split; }

  // staging addresses: thread t covers LDS row (t>>2) (+64 for 2nd call),
  // chunk t&3; fetches global chunk (t&3) ^ ((row>>1)&3)
  const int strow = tid >> 2;
  const int schunk = tid & 3;
  const int sw = schunk ^ ((strow >> 1) & 3);
  const f16* gA0 = Ause + (size_t)(r0 + strow) * K + sw * 8;
  const f16* gB0 = BT + (size_t)(col0 + strow) * K + sw * 8;
  f16* ldsA0 = &sA[0][0] + (size_t)w * 512;
  f16* ldsB0 = &sB[0][0] + (size_t)w * 512;

  // ds_read offsets (f16 elems): row rt, swizzled chunk quad^((rt>>1)&3)
  const int qs = quad ^ ((m16 >> 1) & 3);
  int aoff[4], boff[4];
#pragma unroll
  for (int i = 0; i < 4; ++i) {
    aoff[i] = (wr * 64 + i * 16 + m16) * 32 + qs * 8;
    boff[i] = (wc * 64 + i * 16 + m16) * 32 + qs * 8;
  }

  const int nkt = K >> 5;
  f32x4 acc[4][4] = {};

  auto stage = [&](int buf, int t) {
    const int k0 = t << 5;
    const size_t bufo = (size_t)buf * 4096;
    gload16(gA0 + k0, ldsA0 + bufo);
    gload16(gA0 + (size_t)64 * K + k0, ldsA0 + bufo + 2048);
    gload16(gB0 + k0, ldsB0 + bufo);
    gload16(gB0 + (size_t)64 * K + k0, ldsB0 + bufo + 2048);
  };

  stage(0, 0);
  asm volatile("s_waitcnt vmcnt(0)" ::: "memory");
  __syncthreads();
  int cur = 0;
  for (int t = 0; t < nkt; ++t) {
    if (t + 1 < nkt) stage(cur ^ 1, t + 1);
    f16x8 af[4], bfr[4];
#pragma unroll
    for (int i = 0; i < 4; ++i) af[i] = *(const f16x8*)&sA[cur][aoff[i]];
#pragma unroll
    for (int i = 0; i < 4; ++i) bfr[i] = *(const f16x8*)&sB[cur][boff[i]];
#pragma unroll
    for (int mi = 0; mi < 4; ++mi)
#pragma unroll
      for (int ni = 0; ni < 4; ++ni)
        acc[mi][ni] = __builtin_amdgcn_mfma_f32_16x16x32_f16(
            af[mi], bfr[ni], acc[mi][ni], 0, 0, 0);
    asm volatile("s_waitcnt vmcnt(0)" ::: "memory");
    __syncthreads();
    cur ^= 1;
  }

  // Epilogue: D layout col=lane&15, row=quad*4+rg (16x16 family)
#pragma unroll
  for (int mi = 0; mi < 4; ++mi) {
    const int row = r0 + wr * 64 + mi * 16 + quad * 4;
#pragma unroll
    for (int ni = 0; ni < 4; ++ni) {
      const int col = col0 + wc * 64 + ni * 16 + m16;
      const float bv = bias ? bias[col] : 0.f;
#pragma unroll
      for (int rg = 0; rg < 4; ++rg) {
        float vv = acc[mi][ni][rg] + bv;
        if (relu) vv = vv > 0.f ? vv : 0.f;
        store_c(&Cuse[(size_t)(row + rg) * N + col], vv);
      }
    }
  }
}

// ---------------- Fused flash-MFMA attention (unchanged, passing) ----------------
__global__ __launch_bounds__(256, 3) void fattn_kernel(
    const bf16* __restrict__ qkvp,  // [1536*4, 3072] rows k*B+b, bf16
    const bf16* __restrict__ rhp,   // [1536, 1024] bf16
    const float* __restrict__ u, const float* __restrict__ v,
    float* __restrict__ ctx) {      // [4096, 1024] fp32 (in d_out)
  const int i0 = blockIdx.x * 64;
  const int b = blockIdx.y, h = blockIdx.z;
  const int tid = threadIdx.x;
  const int w = tid >> 6, lane = tid & 63;
  const int quad = lane >> 4, m16 = lane & 15;

  __shared__ short sQu[64 * 72];
  __shared__ short sK[32 * 72];
  __shared__ short sVt[64 * 40];
  __shared__ short sR[96 * 72];
  __shared__ short sProb[64 * 40];
  __shared__ float sPm[64 * 48];
  __shared__ float vr_s[96];
  __shared__ float su_s[64];
  __shared__ float wv_s[64];

  const short* qkv = (const short*)qkvp;
  const short* rh  = (const short*)rhp;

  if (tid < 64) su_s[tid] = u[h * 64 + tid];
  else if (tid < 128) wv_s[tid - 64] = v[h * 64 + (tid - 64)] - u[h * 64 + (tid - 64)];
  __syncthreads();

  {
    const int row_ = tid >> 3, d0 = (tid & 7) * 8;
#pragma unroll
    for (int p = 0; p < 2; ++p) {
      const int row = p * 32 + row_;
      short8 q8 = *(const short8*)&qkv[((size_t)(512 + i0 + row) * 4 + b) * 3072 + h * 64 + d0];
      short8 o;
#pragma unroll
      for (int q = 0; q < 8; ++q) o[q] = f2b(b2f(q8[q]) + su_s[d0 + q]);
      *(short8*)&sQu[row * 72 + d0] = o;
    }
  }
  __syncthreads();

  const short8 aQu0 = *(const short8*)&sQu[(w * 16 + m16) * 72 + quad * 8];
  const short8 aQu1 = *(const short8*)&sQu[(w * 16 + m16) * 72 + 32 + quad * 8];

  f32x4 O[4] = {};
  float m_r[4] = {-1e30f, -1e30f, -1e30f, -1e30f};
  float l_r[4] = {0.f, 0.f, 0.f, 0.f};

  const int n_kt = ((i0 + 575) >> 5) + 1;
  for (int kt = 0; kt < n_kt; ++kt) {
    const int j0 = kt * 32;
    const int tbase = j0 - i0 + 960;
    __syncthreads();

    {
      const int row = tid >> 3, d0 = (tid & 7) * 8;
      *(short8*)&sK[row * 72 + d0] =
          *(const short8*)&qkv[((size_t)(j0 + row) * 4 + b) * 3072 + 1024 + h * 64 + d0];
    }
    {
      const int j = lane & 31, d0 = w * 16 + (lane >> 5) * 8;
      short8 v8 = *(const short8*)&qkv[((size_t)(j0 + j) * 4 + b) * 3072 + 2048 + h * 64 + d0];
#pragma unroll
      for (int q = 0; q < 8; ++q) sVt[(d0 + q) * 40 + j] = v8[q];
    }
    {
      const int row_ = tid >> 3, d0 = (tid & 7) * 8;
#pragma unroll
      for (int p = 0; p < 3; ++p) {
        const int row = p * 32 + row_;
        int t = tbase + row;
        t = t < 0 ? 0 : (t > 1535 ? 1535 : t);
        short8 r8 = *(const short8*)&rh[(size_t)t * 1024 + h * 64 + d0];
        *(short8*)&sR[row * 72 + d0] = r8;
        float part = 0.f;
#pragma unroll
        for (int q = 0; q < 8; ++q) part += wv_s[d0 + q] * b2f(r8[q]);
        part += __shfl_xor(part, 1);
        part += __shfl_xor(part, 2);
        part += __shfl_xor(part, 4);
        if ((tid & 7) == 0) vr_s[row] = part;
      }
    }
    __syncthreads();

#pragma unroll
    for (int pt = 0; pt < 3; ++pt) {
      const int p0 = 48 - 16 * w + 16 * pt;
      short8 bR0 = *(const short8*)&sR[(p0 + m16) * 72 + quad * 8];
      short8 bR1 = *(const short8*)&sR[(p0 + m16) * 72 + 32 + quad * 8];
      f32x4 pf = {};
      pf = __builtin_amdgcn_mfma_f32_16x16x32_bf16(aQu0, bR0, pf, 0, 0, 0);
      pf = __builtin_amdgcn_mfma_f32_16x16x32_bf16(aQu1, bR1, pf, 0, 0, 0);
      const float vrv = vr_s[p0 + m16];
#pragma unroll
      for (int rg = 0; rg < 4; ++rg)
        sPm[(w * 16 + quad * 4 + rg) * 48 + pt * 16 + m16] = pf[rg] + vrv;
    }
    f32x4 ac[2];
#pragma unroll
    for (int n0i = 0; n0i < 2; ++n0i) {
      short8 bK0 = *(const short8*)&sK[(n0i * 16 + m16) * 72 + quad * 8];
      short8 bK1 = *(const short8*)&sK[(n0i * 16 + m16) * 72 + 32 + quad * 8];
      f32x4 a = {};
      a = __builtin_amdgcn_mfma_f32_16x16x32_bf16(aQu0, bK0, a, 0, 0, 0);
      a = __builtin_amdgcn_mfma_f32_16x16x32_bf16(aQu1, bK1, a, 0, 0, 0);
      ac[n0i] = a;
    }
#pragma unroll
    for (int rg = 0; rg < 4; ++rg) {
      const int rloc = quad * 4 + rg;
      const int irow = i0 + w * 16 + rloc;
      const int c0 = m16 - rloc + 15;
      const float p0v = sPm[(w * 16 + rloc) * 48 + c0];
      const float p1v = sPm[(w * 16 + rloc) * 48 + c0 + 16];
      float s0 = (ac[0][rg] + p0v) * 0.125f;
      float s1 = (ac[1][rg] + p1v) * 0.125f;
      if (j0 + m16 > irow + 512) s0 = -1e30f;
      if (j0 + 16 + m16 > irow + 512) s1 = -1e30f;
      float mx = fmaxf(s0, s1);
      mx = fmaxf(mx, __shfl_xor(mx, 1));
      mx = fmaxf(mx, __shfl_xor(mx, 2));
      mx = fmaxf(mx, __shfl_xor(mx, 4));
      mx = fmaxf(mx, __shfl_xor(mx, 8));
      const float mnew = fmaxf(m_r[rg], mx);
      const float al = __expf(m_r[rg] - mnew);
      const float e0 = __expf(s0 - mnew);
      const float e1 = __expf(s1 - mnew);
      float rs = e0 + e1;
      rs += __shfl_xor(rs, 1);
      rs += __shfl_xor(rs, 2);
      rs += __shfl_xor(rs, 4);
      rs += __shfl_xor(rs, 8);
      m_r[rg] = mnew;
      l_r[rg] = l_r[rg] * al + rs;
      sProb[(w * 16 + rloc) * 40 + m16] = f2b(e0);
      sProb[(w * 16 + rloc) * 40 + 16 + m16] = f2b(e1);
#pragma unroll
      for (int d0i = 0; d0i < 4; ++d0i) O[d0i][rg] *= al;
    }
    const short8 aP = *(const short8*)&sProb[(w * 16 + m16) * 40 + quad * 8];
#pragma unroll
    for (int d0i = 0; d0i < 4; ++d0i) {
      short8 bV = *(const short8*)&sVt[(d0i * 16 + m16) * 40 + quad * 8];
      O[d0i] = __builtin_amdgcn_mfma_f32_16x16x32_bf16(aP, bV, O[d0i], 0, 0, 0);
    }
  }
#pragma unroll
  for (int d0i = 0; d0i < 4; ++d0i) {
#pragma unroll
    for (int rg = 0; rg < 4; ++rg) {
      const int irow = i0 + w * 16 + quad * 4 + rg;
      ctx[((size_t)irow * 4 + b) * 1024 + h * 64 + d0i * 16 + m16] = O[d0i][rg] / l_r[rg];
    }
  }
}

// ---------------- LayerNorms ----------------
__global__ __launch_bounds__(256) void ln1_kernel(
    const bf16* __restrict__ y, const float* __restrict__ inp,
    const float* __restrict__ g, const float* __restrict__ beta,
    float* __restrict__ xo, f16* __restrict__ xh) {
  const int r = blockIdx.x, tid = threadIdx.x;
  __shared__ float red[256];
  float t[4];
  float s = 0.f;
#pragma unroll
  for (int q = 0; q < 4; ++q) {
    int c = tid + q * 256;
    t[q] = __bfloat162float(y[(size_t)r * DM + c]) + inp[(size_t)r * DM + c];
    s += t[q];
  }
  red[tid] = s;
  __syncthreads();
  for (int st = 128; st > 0; st >>= 1) {
    if (tid < st) red[tid] += red[tid + st];
    __syncthreads();
  }
  const float mean = red[0] * (1.f / DM);
  __syncthreads();
  float vs = 0.f;
#pragma unroll
  for (int q = 0; q < 4; ++q) {
    float d0 = t[q] - mean;
    vs += d0 * d0;
  }
  red[tid] = vs;
  __syncthreads();
  for (int st = 128; st > 0; st >>= 1) {
    if (tid < st) red[tid] += red[tid + st];
    __syncthreads();
  }
  const float rstd = rsqrtf(red[0] * (1.f / DM) + 1e-5f);
#pragma unroll
  for (int q = 0; q < 4; ++q) {
    int c = tid + q * 256;
    const float val = (t[q] - mean) * rstd * g[c] + beta[c];
    xo[(size_t)r * DM + c] = val;
    xh[(size_t)r * DM + c] = (f16)val;
  }
}

__global__ __launch_bounds__(256) void ln2_kernel(
    const float* __restrict__ x, const bf16* __restrict__ y2,
    const float* __restrict__ b2, const float* __restrict__ g,
    const float* __restrict__ beta, float* __restrict__ out) {
  const int r = blockIdx.x, tid = threadIdx.x;
  __shared__ float red[256];
  float t[4];
  float s = 0.f;
#pragma unroll
  for (int q = 0; q < 4; ++q) {
    int c = tid + q * 256;
    t[q] = x[(size_t)r * DM + c] + __bfloat162float(y2[(size_t)r * DM + c]) + b2[c];
    s += t[q];
  }
  red[tid] = s;
  __syncthreads();
  for (int st = 128; st > 0; st >>= 1) {
    if (tid < st) red[tid] += red[tid + st];
    __syncthreads();
  }
  const float mean = red[0] * (1.f / DM);
  __syncthreads();
  float vs = 0.f;
#pragma unroll
  for (int q = 0; q < 4; ++q) {
    float d0 = t[q] - mean;
    vs += d0 * d0;
  }
  red[tid] = vs;
  __syncthreads();
  for (int st = 128; st > 0; st >>= 1) {
    if (tid < st) red[tid] += red[tid + st];
    __syncthreads();
  }
  const float rstd = rsqrtf(red[0] * (1.f / DM) + 1e-5f);
#pragma unroll
  for (int q = 0; q < 4; ++q) {
    int c = tid + q * 256;
    out[(size_t)r * DM + c] = (t[q] - mean) * rstd * g[c] + beta[c];
  }
}

extern "C" void kernel_launch(void* const* d_in, const int* in_sizes, int n_in,
                              void* d_out, int out_size, void* d_ws, size_t ws_size,
                              hipStream_t stream) {
  const int o = (n_in >= 17) ? 1 : 0;
  const float* inputs = (const float*)d_in[0];
  const float* r      = (const float*)d_in[1];
  const float* u      = (const float*)d_in[2];
  const float* v      = (const float*)d_in[3];
  const float* memp   = (const float*)d_in[4];
  const float* W_qkv  = (const float*)d_in[5 + o];
  const float* W_r    = (const float*)d_in[6 + o];
  const float* W_o    = (const float*)d_in[7 + o];
  const float* ln1_g  = (const float*)d_in[8 + o];
  const float* ln1_b  = (const float*)d_in[9 + o];
  const float* ln2_g  = (const float*)d_in[10 + o];
  const float* ln2_b  = (const float*)d_in[11 + o];
  const float* W1     = (const float*)d_in[12 + o];
  const float* b1     = (const float*)d_in[13 + o];
  const float* W2     = (const float*)d_in[14 + o];
  const float* b2     = (const float*)d_in[15 + o];

  // Workspace liveness plan (peak 52,428,800 B):
  // phase 1 (attention prep):
  //   WqkvT  @ 0         (6,291,456)   fp16 [3072][1024]
  //   r16    @ 6291456   (3,145,728)   fp16 [1536][1024]
  //   WrT    @ 9437184   (2,097,152)   fp16 [1024][1024]
  //   qkv    @ 11534336  (37,748,736)  bf16 [6144][3072]
  //   rh     @ 49283072  (3,145,728)   bf16 [1536][1024]
  //   cat_h  @ d_out     (12,582,912)  fp16 [6144][1024]
  // phase 2 (post-attention; all phase-1 ws dead):
  //   ctx_h  @ 0         (8,388,608)   fp16 [4096][1024]
  //   WoT    @ 8388608   (2,097,152)
  //   y      @ 10485760  (8,388,608)   bf16
  //   x      @ 18874368  (16,777,216)  fp32 (live to ln2)
  //   x_h    @ 35651584  (8,388,608)   fp16
  //   W1T    @ 44040192  (8,388,608)   fp16 [4096][1024]
  //   h_lo   @ d_out     (16,777,216)  fp16 [2048][4096]
  //   h_hi   @ 0         (16,777,216)  fp16 [2048][4096]
  //   W2T    @ 35651584  (8,388,608)   fp16 [1024][4096]  (x_h dead)
  //   y2     @ 44040192  (8,388,608)   bf16               (W1T dead)
  char* ws = (char*)d_ws;
  f16*  WqkvT = (f16*)(ws);
  f16*  r16   = (f16*)(ws + 6291456);
  f16*  WrT   = (f16*)(ws + 9437184);
  bf16* qkv   = (bf16*)(ws + 11534336);
  bf16* rh    = (bf16*)(ws + 49283072);
  f16*  cat_h = (f16*)d_out;
  float* ctx  = (float*)d_out;
  f16*  ctx_h = (f16*)(ws);
  f16*  WoT   = (f16*)(ws + 8388608);
  bf16* y     = (bf16*)(ws + 10485760);
  float* x    = (float*)(ws + 18874368);
  f16*  x_h   = (f16*)(ws + 35651584);
  f16*  W1T   = (f16*)(ws + 44040192);
  f16*  h_lo  = (f16*)d_out;
  f16*  h_hi  = (f16*)(ws);
  f16*  W2T   = (f16*)(ws + 35651584);
  bf16* y2    = (bf16*)(ws + 44040192);

  dim3 blk(256);
  const int BIG = 1 << 30;

  // --- phase 1: QKV / R projections + attention ---
  convh_kernel<<<dim3(2048), blk, 0, stream>>>(memp, cat_h, 524288);
  convh_kernel<<<dim3(4096), blk, 0, stream>>>(inputs, cat_h + (size_t)2048 * 1024, 1048576);
  convh_kernel<<<dim3(1536), blk, 0, stream>>>(r, r16, 393216);
  convT_kernel<<<dim3(48, 16), blk, 0, stream>>>(W_qkv, WqkvT, 1024, 3072);
  convT_kernel<<<dim3(16, 16), blk, 0, stream>>>(W_r, WrT, 1024, 1024);
  hgemm_kernel<bf16><<<dim3(24, 48), blk, 0, stream>>>(
      cat_h, WqkvT, qkv, 6144, 3072, 1024, nullptr, 0, nullptr, nullptr, BIG);
  hgemm_kernel<bf16><<<dim3(8, 12), blk, 0, stream>>>(
      r16, WrT, rh, 1536, 1024, 1024, nullptr, 0, nullptr, nullptr, BIG);
  fattn_kernel<<<dim3(16, 4, 16), blk, 0, stream>>>(qkv, rh, u, v, ctx);

  // --- phase 2: output proj + LN1 + MLP + LN2 ---
  convh_kernel<<<dim3(4096), blk, 0, stream>>>(ctx, ctx_h, 1048576);
  convT_kernel<<<dim3(16, 16), blk, 0, stream>>>(W_o, WoT, 1024, 1024);
  hgemm_kernel<bf16><<<dim3(8, 32), blk, 0, stream>>>(
      ctx_h, WoT, y, 4096, 1024, 1024, nullptr, 0, nullptr, nullptr, BIG);
  ln1_kernel<<<dim3(4096), blk, 0, stream>>>(y, inputs, ln1_g, ln1_b, x, x_h);
  convT_kernel<<<dim3(64, 16), blk, 0, stream>>>(W1, W1T, 1024, 4096);
  hgemm_kernel<f16><<<dim3(32, 32), blk, 0, stream>>>(
      x_h, W1T, h_lo, 4096, 4096, 1024, b1, 1,
      x_h + (size_t)2048 * 1024, h_hi, 2048);
  convT_kernel<<<dim3(16, 64), blk, 0, stream>>>(W2, W2T, 4096, 1024);
  hgemm_kernel<bf16><<<dim3(8, 32), blk, 0, stream>>>(
      h_lo, W2T, y2, 4096, 1024, 4096, nullptr, 0,
      h_hi, y2 + (size_t)2048 * 1024, 2048);
  ln2_kernel<<<dim3(4096), blk, 0, stream>>>(x, y2, b2, ln2_g, ln2_b, (float*)d_out);
}

// Round 2
// 639.321 us; speedup vs baseline: 3.0618x; 1.0582x over previous
//
#include <hip/hip_runtime.h>
#include <hip/hip_bf16.h>

typedef __hip_bfloat16 bf16;
typedef _Float16 f16;
typedef __attribute__((ext_vector_type(8))) short short8;
typedef __attribute__((ext_vector_type(4))) float f32x4;
typedef __attribute__((ext_vector_type(8))) _Float16 f16x8;
typedef __attribute__((ext_vector_type(4))) _Float16 f16x4;

#define Q_LEN 1024
#define B_SZ 4
#define DM 1024
#define H_CNT 16
#define HD 64
#define MEM_LEN 512
#define KLEN 1536
#define MLP 4096

__device__ __forceinline__ void store_c(float* p, float v) { *p = v; }
__device__ __forceinline__ void store_c(bf16* p, float v) { *p = __float2bfloat16(v); }
__device__ __forceinline__ void store_c(f16* p, float v) { *p = (f16)v; }

__device__ __forceinline__ float b2f(short s) {
  union { unsigned u; float f; } x;
  x.u = ((unsigned)(unsigned short)s) << 16;
  return x.f;
}
__device__ __forceinline__ short f2b(float f) {
  union { float f; unsigned u; } x;
  x.f = f;
  unsigned r = x.u + 0x7fff + ((x.u >> 16) & 1);  // RNE; inputs finite
  return (short)(r >> 16);
}

// async global->LDS, 16B per lane; LDS dest = wave-uniform base + lane*16
__device__ __forceinline__ void gload16(const void* g, void* l) {
  __builtin_amdgcn_global_load_lds(
      (__attribute__((address_space(1))) unsigned int*)(g),
      (__attribute__((address_space(3))) unsigned int*)(l), 16, 0, 0);
}

// ---------------- fp32 -> fp16 elementwise convert ----------------
__global__ __launch_bounds__(256) void convh_kernel(
    const float* __restrict__ X, f16* __restrict__ Y, int n4) {
  const int i = blockIdx.x * 256 + threadIdx.x;
  if (i < n4) {
    f32x4 v = *(const f32x4*)&X[(size_t)i * 4];
    f16x4 h;
#pragma unroll
    for (int j = 0; j < 4; ++j) h[j] = (f16)v[j];
    *(f16x4*)&Y[(size_t)i * 4] = h;
  }
}

// ---------------- fp32 [K][N] -> fp16 transposed [N][K] ----------------
__global__ __launch_bounds__(256) void convT_kernel(
    const float* __restrict__ W, f16* __restrict__ WT, int K, int N) {
  __shared__ float tile[64][65];
  const int tid = threadIdx.x;
  const int k0 = blockIdx.y * 64, n0 = blockIdx.x * 64;
  const int tn = tid & 63, tk4 = tid >> 6;
#pragma unroll
  for (int p = 0; p < 16; ++p) {
    const int kk = tk4 + p * 4;
    tile[kk][tn] = W[(size_t)(k0 + kk) * N + n0 + tn];
  }
  __syncthreads();
#pragma unroll
  for (int p = 0; p < 16; ++p) {
    const int nn = tk4 + p * 4;
    WT[(size_t)(n0 + nn) * K + k0 + tn] = (f16)tile[tn][nn];
  }
}

// ---------------- fp16 MFMA GEMM: C = A[M,K] * BT[N,K]^T ----------------
// (unchanged, passing) 128x128 tile, BK=32, 4 waves 2x2, 16x16x32_f16.
template <typename TC>
__global__ __launch_bounds__(256, 2) void hgemm_kernel(
    const f16* __restrict__ A, const f16* __restrict__ BT, TC* __restrict__ C,
    int M, int N, int K, const float* __restrict__ bias, int relu,
    const f16* __restrict__ Aalt, TC* __restrict__ Calt, int split) {
  __shared__ __align__(16) f16 sA[2][128 * 32];
  __shared__ __align__(16) f16 sB[2][128 * 32];
  const int tid = threadIdx.x;
  const int w = tid >> 6, lane = tid & 63;
  const int quad = lane >> 4, m16 = lane & 15;
  const int wr = w >> 1, wc = w & 1;
  const int col0 = blockIdx.x * 128;
  int r0 = blockIdx.y * 128;
  const f16* Ause = A;
  TC* Cuse = C;
  if (r0 >= split) { Ause = Aalt; Cuse = Calt; r0 -= split; }

  const int strow = tid >> 2;
  const int schunk = tid & 3;
  const int sw = schunk ^ ((strow >> 1) & 3);
  const f16* gA0 = Ause + (size_t)(r0 + strow) * K + sw * 8;
  const f16* gB0 = BT + (size_t)(col0 + strow) * K + sw * 8;
  f16* ldsA0 = &sA[0][0] + (size_t)w * 512;
  f16* ldsB0 = &sB[0][0] + (size_t)w * 512;

  const int qs = quad ^ ((m16 >> 1) & 3);
  int aoff[4], boff[4];
#pragma unroll
  for (int i = 0; i < 4; ++i) {
    aoff[i] = (wr * 64 + i * 16 + m16) * 32 + qs * 8;
    boff[i] = (wc * 64 + i * 16 + m16) * 32 + qs * 8;
  }

  const int nkt = K >> 5;
  f32x4 acc[4][4] = {};

  auto stage = [&](int buf, int t) {
    const int k0 = t << 5;
    const size_t bufo = (size_t)buf * 4096;
    gload16(gA0 + k0, ldsA0 + bufo);
    gload16(gA0 + (size_t)64 * K + k0, ldsA0 + bufo + 2048);
    gload16(gB0 + k0, ldsB0 + bufo);
    gload16(gB0 + (size_t)64 * K + k0, ldsB0 + bufo + 2048);
  };

  stage(0, 0);
  asm volatile("s_waitcnt vmcnt(0)" ::: "memory");
  __syncthreads();
  int cur = 0;
  for (int t = 0; t < nkt; ++t) {
    if (t + 1 < nkt) stage(cur ^ 1, t + 1);
    f16x8 af[4], bfr[4];
#pragma unroll
    for (int i = 0; i < 4; ++i) af[i] = *(const f16x8*)&sA[cur][aoff[i]];
#pragma unroll
    for (int i = 0; i < 4; ++i) bfr[i] = *(const f16x8*)&sB[cur][boff[i]];
#pragma unroll
    for (int mi = 0; mi < 4; ++mi)
#pragma unroll
      for (int ni = 0; ni < 4; ++ni)
        acc[mi][ni] = __builtin_amdgcn_mfma_f32_16x16x32_f16(
            af[mi], bfr[ni], acc[mi][ni], 0, 0, 0);
    asm volatile("s_waitcnt vmcnt(0)" ::: "memory");
    __syncthreads();
    cur ^= 1;
  }

#pragma unroll
  for (int mi = 0; mi < 4; ++mi) {
    const int row = r0 + wr * 64 + mi * 16 + quad * 4;
#pragma unroll
    for (int ni = 0; ni < 4; ++ni) {
      const int col = col0 + wc * 64 + ni * 16 + m16;
      const float bv = bias ? bias[col] : 0.f;
#pragma unroll
      for (int rg = 0; rg < 4; ++rg) {
        float vv = acc[mi][ni][rg] + bv;
        if (relu) vv = vv > 0.f ? vv : 0.f;
        store_c(&Cuse[(size_t)(row + rg) * N + col], vv);
      }
    }
  }
}

// ---------------- Fused flash-MFMA attention ----------------
// R2 changes vs R1:
//  - async-stage split: kt+1 K/V/R tiles loaded to regs during kt compute,
//    ds_write'd after the read barrier (hides global latency).
//  - sPm LDS eliminated: rel-shift gather of P row values done with 3
//    __shfl + 2 selects per rg (same quad, same reg index). -12.3KB LDS.
//  - 38.8KB LDS -> __launch_bounds__(256,4): 4 blocks/CU.
//  - LPT: blockIdx.x reversed so heaviest (large i0) blocks dispatch first.
__global__ __launch_bounds__(256, 4) void fattn_kernel(
    const bf16* __restrict__ qkvp,  // [1536*4, 3072] rows k*B+b, bf16
    const bf16* __restrict__ rhp,   // [1536, 1024] bf16
    const float* __restrict__ u, const float* __restrict__ v,
    float* __restrict__ ctx) {      // [4096, 1024] fp32 (in d_out)
  const int i0 = ((int)gridDim.x - 1 - (int)blockIdx.x) * 64;
  const int b = blockIdx.y, h = blockIdx.z;
  const int tid = threadIdx.x;
  const int w = tid >> 6, lane = tid & 63;
  const int quad = lane >> 4, m16 = lane & 15;

  __shared__ short sQu[64 * 72];   // (q+u) tile, bf16
  __shared__ short sK[32 * 72];    // K tile
  __shared__ short sVt[64 * 40];   // V^T tile: [d][j]
  __shared__ short sR[96 * 72];    // R window
  __shared__ short sProb[64 * 40]; // probs bf16
  __shared__ float vr_s[96];       // (v-u)·r_t per staged row
  __shared__ float su_s[64];
  __shared__ float wv_s[64];

  const short* qkv = (const short*)qkvp;
  const short* rh  = (const short*)rhp;

  if (tid < 64) su_s[tid] = u[h * 64 + tid];
  else if (tid < 128) wv_s[tid - 64] = v[h * 64 + (tid - 64)] - u[h * 64 + (tid - 64)];
  __syncthreads();

  // Stage Qu = q + u (bf16)
  {
    const int row_ = tid >> 3, d0 = (tid & 7) * 8;
#pragma unroll
    for (int p = 0; p < 2; ++p) {
      const int row = p * 32 + row_;
      short8 q8 = *(const short8*)&qkv[((size_t)(512 + i0 + row) * 4 + b) * 3072 + h * 64 + d0];
      short8 o;
#pragma unroll
      for (int q = 0; q < 8; ++q) o[q] = f2b(b2f(q8[q]) + su_s[d0 + q]);
      *(short8*)&sQu[row * 72 + d0] = o;
    }
  }

  // staging thread mappings
  const int st_row = tid >> 3, st_d0 = (tid & 7) * 8;  // K (32 rows) / R (96 rows)
  const int vj = lane & 31, vd0 = w * 16 + (lane >> 5) * 8;  // V^T

  short8 rK, rV, rR[3];
  auto load_tile = [&](int kt) {
    const int j0 = kt * 32;
    rK = *(const short8*)&qkv[((size_t)(j0 + st_row) * 4 + b) * 3072 + 1024 + h * 64 + st_d0];
    rV = *(const short8*)&qkv[((size_t)(j0 + vj) * 4 + b) * 3072 + 2048 + h * 64 + vd0];
    const int tbase = j0 - i0 + 960;
#pragma unroll
    for (int p = 0; p < 3; ++p) {
      int t = tbase + p * 32 + st_row;
      t = t < 0 ? 0 : (t > 1535 ? 1535 : t);  // clamped rows only feed masked elems
      rR[p] = *(const short8*)&rh[(size_t)t * 1024 + h * 64 + st_d0];
    }
  };
  auto write_tile = [&]() {
    *(short8*)&sK[st_row * 72 + st_d0] = rK;
#pragma unroll
    for (int q = 0; q < 8; ++q) sVt[(vd0 + q) * 40 + vj] = rV[q];
#pragma unroll
    for (int p = 0; p < 3; ++p) {
      const int row = p * 32 + st_row;
      *(short8*)&sR[row * 72 + st_d0] = rR[p];
      float part = 0.f;
#pragma unroll
      for (int q = 0; q < 8; ++q) part += wv_s[st_d0 + q] * b2f(rR[p][q]);
      part += __shfl_xor(part, 1);
      part += __shfl_xor(part, 2);
      part += __shfl_xor(part, 4);
      if ((tid & 7) == 0) vr_s[row] = part;
    }
  };

  load_tile(0);
  __syncthreads();  // sQu visible

  const short8 aQu0 = *(const short8*)&sQu[(w * 16 + m16) * 72 + quad * 8];
  const short8 aQu1 = *(const short8*)&sQu[(w * 16 + m16) * 72 + 32 + quad * 8];

  write_tile();  // tile 0 regs -> LDS

  f32x4 O[4] = {};
  float m_r[4] = {-1e30f, -1e30f, -1e30f, -1e30f};
  float l_r[4] = {0.f, 0.f, 0.f, 0.f};

  const int n_kt = ((i0 + 575) >> 5) + 1;  // valid j <= i+512, i <= i0+63
  for (int kt = 0; kt < n_kt; ++kt) {
    const int j0 = kt * 32;
    __syncthreads();  // tile writes visible
    if (kt + 1 < n_kt) load_tile(kt + 1);  // async prefetch into regs

    // P tiles -> registers (wave trel window [48-16w, 94-16w], 3 tiles of 16)
    f32x4 pb[3];
#pragma unroll
    for (int pt = 0; pt < 3; ++pt) {
      const int p0 = 48 - 16 * w + 16 * pt;
      short8 bR0 = *(const short8*)&sR[(p0 + m16) * 72 + quad * 8];
      short8 bR1 = *(const short8*)&sR[(p0 + m16) * 72 + 32 + quad * 8];
      f32x4 pf = {};
      pf = __builtin_amdgcn_mfma_f32_16x16x32_bf16(aQu0, bR0, pf, 0, 0, 0);
      pf = __builtin_amdgcn_mfma_f32_16x16x32_bf16(aQu1, bR1, pf, 0, 0, 0);
      const float vrv = vr_s[p0 + m16];
#pragma unroll
      for (int rg = 0; rg < 4; ++rg) pb[pt][rg] = pf[rg] + vrv;
    }
    // AC tiles: 2 subtiles of 16 key-cols
    f32x4 ac[2];
#pragma unroll
    for (int n0i = 0; n0i < 2; ++n0i) {
      short8 bK0 = *(const short8*)&sK[(n0i * 16 + m16) * 72 + quad * 8];
      short8 bK1 = *(const short8*)&sK[(n0i * 16 + m16) * 72 + 32 + quad * 8];
      f32x4 a = {};
      a = __builtin_amdgcn_mfma_f32_16x16x32_bf16(aQu0, bK0, a, 0, 0, 0);
      a = __builtin_amdgcn_mfma_f32_16x16x32_bf16(aQu1, bK1, a, 0, 0, 0);
      ac[n0i] = a;
    }
    // Scores + online softmax; rel-shift P gather via in-wave shuffles:
    // P[rloc][c] held by lane (quad, c&15) in pb[c>>4][rg] (same quad/rg).
#pragma unroll
    for (int rg = 0; rg < 4; ++rg) {
      const int rloc = quad * 4 + rg;
      const int irow = i0 + w * 16 + rloc;
      const int c0 = m16 - rloc + 15;  // in [0,30]
      const int src = (lane & 48) | (c0 & 15);
      const float t0 = __shfl(pb[0][rg], src);
      const float t1 = __shfl(pb[1][rg], src);
      const float t2 = __shfl(pb[2][rg], src);
      const float p0v = (c0 < 16) ? t0 : t1;
      const float p1v = (c0 < 16) ? t1 : t2;
      float s0 = (ac[0][rg] + p0v) * 0.125f;
      float s1 = (ac[1][rg] + p1v) * 0.125f;
      if (j0 + m16 > irow + 512) s0 = -1e30f;
      if (j0 + 16 + m16 > irow + 512) s1 = -1e30f;
      float mx = fmaxf(s0, s1);
      mx = fmaxf(mx, __shfl_xor(mx, 1));
      mx = fmaxf(mx, __shfl_xor(mx, 2));
      mx = fmaxf(mx, __shfl_xor(mx, 4));
      mx = fmaxf(mx, __shfl_xor(mx, 8));
      const float mnew = fmaxf(m_r[rg], mx);
      const float al = __expf(m_r[rg] - mnew);
      const float e0 = __expf(s0 - mnew);
      const float e1 = __expf(s1 - mnew);
      float rs = e0 + e1;
      rs += __shfl_xor(rs, 1);
      rs += __shfl_xor(rs, 2);
      rs += __shfl_xor(rs, 4);
      rs += __shfl_xor(rs, 8);
      m_r[rg] = mnew;
      l_r[rg] = l_r[rg] * al + rs;
      sProb[(w * 16 + rloc) * 40 + m16] = f2b(e0);
      sProb[(w * 16 + rloc) * 40 + 16 + m16] = f2b(e1);
#pragma unroll
      for (int d0i = 0; d0i < 4; ++d0i) O[d0i][rg] *= al;
    }
    // PV
    const short8 aP = *(const short8*)&sProb[(w * 16 + m16) * 40 + quad * 8];
#pragma unroll
    for (int d0i = 0; d0i < 4; ++d0i) {
      short8 bV = *(const short8*)&sVt[(d0i * 16 + m16) * 40 + quad * 8];
      O[d0i] = __builtin_amdgcn_mfma_f32_16x16x32_bf16(aP, bV, O[d0i], 0, 0, 0);
    }
    __syncthreads();  // all reads done before restage
    if (kt + 1 < n_kt) write_tile();
  }
  // Epilogue
#pragma unroll
  for (int d0i = 0; d0i < 4; ++d0i) {
#pragma unroll
    for (int rg = 0; rg < 4; ++rg) {
      const int irow = i0 + w * 16 + quad * 4 + rg;
      ctx[((size_t)irow * 4 + b) * 1024 + h * 64 + d0i * 16 + m16] = O[d0i][rg] / l_r[rg];
    }
  }
}

// ---------------- LayerNorms ----------------
__global__ __launch_bounds__(256) void ln1_kernel(
    const bf16* __restrict__ y, const float* __restrict__ inp,
    const float* __restrict__ g, const float* __restrict__ beta,
    float* __restrict__ xo, f16* __restrict__ xh) {
  const int r = blockIdx.x, tid = threadIdx.x;
  __shared__ float red[256];
  float t[4];
  float s = 0.f;
#pragma unroll
  for (int q = 0; q < 4; ++q) {
    int c = tid + q * 256;
    t[q] = __bfloat162float(y[(size_t)r * DM + c]) + inp[(size_t)r * DM + c];
    s += t[q];
  }
  red[tid] = s;
  __syncthreads();
  for (int st = 128; st > 0; st >>= 1) {
    if (tid < st) red[tid] += red[tid + st];
    __syncthreads();
  }
  const float mean = red[0] * (1.f / DM);
  __syncthreads();
  float vs = 0.f;
#pragma unroll
  for (int q = 0; q < 4; ++q) {
    float d0 = t[q] - mean;
    vs += d0 * d0;
  }
  red[tid] = vs;
  __syncthreads();
  for (int st = 128; st > 0; st >>= 1) {
    if (tid < st) red[tid] += red[tid + st];
    __syncthreads();
  }
  const float rstd = rsqrtf(red[0] * (1.f / DM) + 1e-5f);
#pragma unroll
  for (int q = 0; q < 4; ++q) {
    int c = tid + q * 256;
    const float val = (t[q] - mean) * rstd * g[c] + beta[c];
    xo[(size_t)r * DM + c] = val;
    xh[(size_t)r * DM + c] = (f16)val;
  }
}

__global__ __launch_bounds__(256) void ln2_kernel(
    const float* __restrict__ x, const bf16* __restrict__ y2,
    const float* __restrict__ b2, const float* __restrict__ g,
    const float* __restrict__ beta, float* __restrict__ out) {
  const int r = blockIdx.x, tid = threadIdx.x;
  __shared__ float red[256];
  float t[4];
  float s = 0.f;
#pragma unroll
  for (int q = 0; q < 4; ++q) {
    int c = tid + q * 256;
    t[q] = x[(size_t)r * DM + c] + __bfloat162float(y2[(size_t)r * DM + c]) + b2[c];
    s += t[q];
  }
  red[tid] = s;
  __syncthreads();
  for (int st = 128; st > 0; st >>= 1) {
    if (tid < st) red[tid] += red[tid + st];
    __syncthreads();
  }
  const float mean = red[0] * (1.f / DM);
  __syncthreads();
  float vs = 0.f;
#pragma unroll
  for (int q = 0; q < 4; ++q) {
    float d0 = t[q] - mean;
    vs += d0 * d0;
  }
  red[tid] = vs;
  __syncthreads();
  for (int st = 128; st > 0; st >>= 1) {
    if (tid < st) red[tid] += red[tid + st];
    __syncthreads();
  }
  const float rstd = rsqrtf(red[0] * (1.f / DM) + 1e-5f);
#pragma unroll
  for (int q = 0; q < 4; ++q) {
    int c = tid + q * 256;
    out[(size_t)r * DM + c] = (t[q] - mean) * rstd * g[c] + beta[c];
  }
}

extern "C" void kernel_launch(void* const* d_in, const int* in_sizes, int n_in,
                              void* d_out, int out_size, void* d_ws, size_t ws_size,
                              hipStream_t stream) {
  const int o = (n_in >= 17) ? 1 : 0;
  const float* inputs = (const float*)d_in[0];
  const float* r      = (const float*)d_in[1];
  const float* u      = (const float*)d_in[2];
  const float* v      = (const float*)d_in[3];
  const float* memp   = (const float*)d_in[4];
  const float* W_qkv  = (const float*)d_in[5 + o];
  const float* W_r    = (const float*)d_in[6 + o];
  const float* W_o    = (const float*)d_in[7 + o];
  const float* ln1_g  = (const float*)d_in[8 + o];
  const float* ln1_b  = (const float*)d_in[9 + o];
  const float* ln2_g  = (const float*)d_in[10 + o];
  const float* ln2_b  = (const float*)d_in[11 + o];
  const float* W1     = (const float*)d_in[12 + o];
  const float* b1     = (const float*)d_in[13 + o];
  const float* W2     = (const float*)d_in[14 + o];
  const float* b2     = (const float*)d_in[15 + o];

  // Workspace liveness plan (peak 52,428,800 B) — unchanged from R1
  char* ws = (char*)d_ws;
  f16*  WqkvT = (f16*)(ws);
  f16*  r16   = (f16*)(ws + 6291456);
  f16*  WrT   = (f16*)(ws + 9437184);
  bf16* qkv   = (bf16*)(ws + 11534336);
  bf16* rh    = (bf16*)(ws + 49283072);
  f16*  cat_h = (f16*)d_out;
  float* ctx  = (float*)d_out;
  f16*  ctx_h = (f16*)(ws);
  f16*  WoT   = (f16*)(ws + 8388608);
  bf16* y     = (bf16*)(ws + 10485760);
  float* x    = (float*)(ws + 18874368);
  f16*  x_h   = (f16*)(ws + 35651584);
  f16*  W1T   = (f16*)(ws + 44040192);
  f16*  h_lo  = (f16*)d_out;
  f16*  h_hi  = (f16*)(ws);
  f16*  W2T   = (f16*)(ws + 35651584);
  bf16* y2    = (bf16*)(ws + 44040192);

  dim3 blk(256);
  const int BIG = 1 << 30;

  // --- phase 1: QKV / R projections + attention ---
  convh_kernel<<<dim3(2048), blk, 0, stream>>>(memp, cat_h, 524288);
  convh_kernel<<<dim3(4096), blk, 0, stream>>>(inputs, cat_h + (size_t)2048 * 1024, 1048576);
  convh_kernel<<<dim3(1536), blk, 0, stream>>>(r, r16, 393216);
  convT_kernel<<<dim3(48, 16), blk, 0, stream>>>(W_qkv, WqkvT, 1024, 3072);
  convT_kernel<<<dim3(16, 16), blk, 0, stream>>>(W_r, WrT, 1024, 1024);
  hgemm_kernel<bf16><<<dim3(24, 48), blk, 0, stream>>>(
      cat_h, WqkvT, qkv, 6144, 3072, 1024, nullptr, 0, nullptr, nullptr, BIG);
  hgemm_kernel<bf16><<<dim3(8, 12), blk, 0, stream>>>(
      r16, WrT, rh, 1536, 1024, 1024, nullptr, 0, nullptr, nullptr, BIG);
  fattn_kernel<<<dim3(16, 4, 16), blk, 0, stream>>>(qkv, rh, u, v, ctx);

  // --- phase 2: output proj + LN1 + MLP + LN2 ---
  convh_kernel<<<dim3(4096), blk, 0, stream>>>(ctx, ctx_h, 1048576);
  convT_kernel<<<dim3(16, 16), blk, 0, stream>>>(W_o, WoT, 1024, 1024);
  hgemm_kernel<bf16><<<dim3(8, 32), blk, 0, stream>>>(
      ctx_h, WoT, y, 4096, 1024, 1024, nullptr, 0, nullptr, nullptr, BIG);
  ln1_kernel<<<dim3(4096), blk, 0, stream>>>(y, inputs, ln1_g, ln1_b, x, x_h);
  convT_kernel<<<dim3(64, 16), blk, 0, stream>>>(W1, W1T, 1024, 4096);
  hgemm_kernel<f16><<<dim3(32, 32), blk, 0, stream>>>(
      x_h, W1T, h_lo, 4096, 4096, 1024, b1, 1,
      x_h + (size_t)2048 * 1024, h_hi, 2048);
  convT_kernel<<<dim3(16, 64), blk, 0, stream>>>(W2, W2T, 4096, 1024);
  hgemm_kernel<bf16><<<dim3(8, 32), blk, 0, stream>>>(
      h_lo, W2T, y2, 4096, 1024, 4096, nullptr, 0,
      h_hi, y2 + (size_t)2048 * 1024, 2048);
  ln2_kernel<<<dim3(4096), blk, 0, stream>>>(x, y2, b2, ln2_g, ln2_b, (float*)d_out);
}

// Round 3
// 557.818 us; speedup vs baseline: 3.5092x; 1.1461x over previous
//
#include <hip/hip_runtime.h>
#include <hip/hip_bf16.h>

typedef __hip_bfloat16 bf16;
typedef _Float16 f16;
typedef __attribute__((ext_vector_type(8))) short short8;
typedef __attribute__((ext_vector_type(4))) float f32x4;
typedef __attribute__((ext_vector_type(8))) _Float16 f16x8;
typedef __attribute__((ext_vector_type(4))) _Float16 f16x4;

#define Q_LEN 1024
#define B_SZ 4
#define DM 1024
#define H_CNT 16
#define HD 64
#define MEM_LEN 512
#define KLEN 1536
#define MLP 4096

__device__ __forceinline__ void store_c(float* p, float v) { *p = v; }
__device__ __forceinline__ void store_c(bf16* p, float v) { *p = __float2bfloat16(v); }
__device__ __forceinline__ void store_c(f16* p, float v) { *p = (f16)v; }

__device__ __forceinline__ float b2f(short s) {
  union { unsigned u; float f; } x;
  x.u = ((unsigned)(unsigned short)s) << 16;
  return x.f;
}
__device__ __forceinline__ short f2b(float f) {
  union { float f; unsigned u; } x;
  x.f = f;
  unsigned r = x.u + 0x7fff + ((x.u >> 16) & 1);  // RNE; inputs finite
  return (short)(r >> 16);
}

// async global->LDS, 16B per lane; LDS dest = wave-uniform base + lane*16
__device__ __forceinline__ void gload16(const void* g, void* l) {
  __builtin_amdgcn_global_load_lds(
      (__attribute__((address_space(1))) unsigned int*)(g),
      (__attribute__((address_space(3))) unsigned int*)(l), 16, 0, 0);
}

// ---------------- fp32 -> fp16 elementwise convert ----------------
__global__ __launch_bounds__(256) void convh_kernel(
    const float* __restrict__ X, f16* __restrict__ Y, int n4) {
  const int i = blockIdx.x * 256 + threadIdx.x;
  if (i < n4) {
    f32x4 v = *(const f32x4*)&X[(size_t)i * 4];
    f16x4 h;
#pragma unroll
    for (int j = 0; j < 4; ++j) h[j] = (f16)v[j];
    *(f16x4*)&Y[(size_t)i * 4] = h;
  }
}

// ---------------- fp32 [K][N] -> fp16 transposed [N][K] ----------------
__global__ __launch_bounds__(256) void convT_kernel(
    const float* __restrict__ W, f16* __restrict__ WT, int K, int N) {
  __shared__ float tile[64][65];
  const int tid = threadIdx.x;
  const int k0 = blockIdx.y * 64, n0 = blockIdx.x * 64;
  const int tn = tid & 63, tk4 = tid >> 6;
#pragma unroll
  for (int p = 0; p < 16; ++p) {
    const int kk = tk4 + p * 4;
    tile[kk][tn] = W[(size_t)(k0 + kk) * N + n0 + tn];
  }
  __syncthreads();
#pragma unroll
  for (int p = 0; p < 16; ++p) {
    const int nn = tk4 + p * 4;
    WT[(size_t)(n0 + nn) * K + k0 + tn] = (f16)tile[tn][nn];
  }
}

// ---------------- fp16 MFMA GEMM: C = A[M,K] * BT[N,K]^T ----------------
// (unchanged, passing) 128x128 tile, BK=32, 4 waves 2x2, 16x16x32_f16.
template <typename TC>
__global__ __launch_bounds__(256, 2) void hgemm_kernel(
    const f16* __restrict__ A, const f16* __restrict__ BT, TC* __restrict__ C,
    int M, int N, int K, const float* __restrict__ bias, int relu,
    const f16* __restrict__ Aalt, TC* __restrict__ Calt, int split) {
  __shared__ __align__(16) f16 sA[2][128 * 32];
  __shared__ __align__(16) f16 sB[2][128 * 32];
  const int tid = threadIdx.x;
  const int w = tid >> 6, lane = tid & 63;
  const int quad = lane >> 4, m16 = lane & 15;
  const int wr = w >> 1, wc = w & 1;
  const int col0 = blockIdx.x * 128;
  int r0 = blockIdx.y * 128;
  const f16* Ause = A;
  TC* Cuse = C;
  if (r0 >= split) { Ause = Aalt; Cuse = Calt; r0 -= split; }

  const int strow = tid >> 2;
  const int schunk = tid & 3;
  const int sw = schunk ^ ((strow >> 1) & 3);
  const f16* gA0 = Ause + (size_t)(r0 + strow) * K + sw * 8;
  const f16* gB0 = BT + (size_t)(col0 + strow) * K + sw * 8;
  f16* ldsA0 = &sA[0][0] + (size_t)w * 512;
  f16* ldsB0 = &sB[0][0] + (size_t)w * 512;

  const int qs = quad ^ ((m16 >> 1) & 3);
  int aoff[4], boff[4];
#pragma unroll
  for (int i = 0; i < 4; ++i) {
    aoff[i] = (wr * 64 + i * 16 + m16) * 32 + qs * 8;
    boff[i] = (wc * 64 + i * 16 + m16) * 32 + qs * 8;
  }

  const int nkt = K >> 5;
  f32x4 acc[4][4] = {};

  auto stage = [&](int buf, int t) {
    const int k0 = t << 5;
    const size_t bufo = (size_t)buf * 4096;
    gload16(gA0 + k0, ldsA0 + bufo);
    gload16(gA0 + (size_t)64 * K + k0, ldsA0 + bufo + 2048);
    gload16(gB0 + k0, ldsB0 + bufo);
    gload16(gB0 + (size_t)64 * K + k0, ldsB0 + bufo + 2048);
  };

  stage(0, 0);
  asm volatile("s_waitcnt vmcnt(0)" ::: "memory");
  __syncthreads();
  int cur = 0;
  for (int t = 0; t < nkt; ++t) {
    if (t + 1 < nkt) stage(cur ^ 1, t + 1);
    f16x8 af[4], bfr[4];
#pragma unroll
    for (int i = 0; i < 4; ++i) af[i] = *(const f16x8*)&sA[cur][aoff[i]];
#pragma unroll
    for (int i = 0; i < 4; ++i) bfr[i] = *(const f16x8*)&sB[cur][boff[i]];
#pragma unroll
    for (int mi = 0; mi < 4; ++mi)
#pragma unroll
      for (int ni = 0; ni < 4; ++ni)
        acc[mi][ni] = __builtin_amdgcn_mfma_f32_16x16x32_f16(
            af[mi], bfr[ni], acc[mi][ni], 0, 0, 0);
    asm volatile("s_waitcnt vmcnt(0)" ::: "memory");
    __syncthreads();
    cur ^= 1;
  }

#pragma unroll
  for (int mi = 0; mi < 4; ++mi) {
    const int row = r0 + wr * 64 + mi * 16 + quad * 4;
#pragma unroll
    for (int ni = 0; ni < 4; ++ni) {
      const int col = col0 + wc * 64 + ni * 16 + m16;
      const float bv = bias ? bias[col] : 0.f;
#pragma unroll
      for (int rg = 0; rg < 4; ++rg) {
        float vv = acc[mi][ni][rg] + bv;
        if (relu) vv = vv > 0.f ? vv : 0.f;
        store_c(&Cuse[(size_t)(row + rg) * N + col], vv);
      }
    }
  }
}

// ---------------- Fused flash-MFMA attention ----------------
// R3 changes vs R2 (DS-pipe cost per iter ~halved):
//  - aQv = q+v fragment staged from global: BD = Qv.R directly; vr
//    recompute (9 bpermute + 24 FMA/iter) + vr_s/su_s/wv_s eliminated.
//  - Q and K fragments read per-lane from global (L2-resident, prefetched
//    to regs): sQu/sK LDS gone (-13.8KB, -5 DS ops/iter, -1 barrier).
//  - wave-shared softmax max (valid: any M >= rowmax; score spread << 80):
//    16 reduce-bpermutes -> 7 v_max + 6 butterfly shuffles.
//  - row-sums l via MFMA with all-ones B fragment (broadcast to all lanes):
//    16 sum-bpermutes -> 1 MFMA; l now sums bf16 p (consistent with PV).
//  - sR ring buffer (windows overlap 2/3): stage 32 new rows/iter not 96.
__global__ __launch_bounds__(256, 4) void fattn_kernel(
    const bf16* __restrict__ qkvp,  // [1536*4, 3072] rows k*B+b, bf16
    const bf16* __restrict__ rhp,   // [1536, 1024] bf16
    const float* __restrict__ u, const float* __restrict__ v,
    float* __restrict__ ctx) {      // [4096, 1024] fp32 (in d_out)
  const int i0 = ((int)gridDim.x - 1 - (int)blockIdx.x) * 64;
  const int b = blockIdx.y, h = blockIdx.z;
  const int tid = threadIdx.x;
  const int w = tid >> 6, lane = tid & 63;
  const int quad = lane >> 4, m16 = lane & 15;

  __shared__ short sVt[64 * 40];   // V^T tile: [d][j]
  __shared__ short sR[96 * 72];    // R ring buffer (phys = (32kt+trel)%96)
  __shared__ short sProb[64 * 40]; // probs bf16, per-wave strips

  const short* qkv = (const short*)qkvp;
  const short* rh  = (const short*)rhp;

  // Per-lane Q fragments: aQu = q+u (AC), aQv = q+v (BD). Rows w*16+m16.
  short8 aQu0, aQu1, aQv0, aQv1;
  {
    const size_t qro = ((size_t)(512 + i0 + w * 16 + m16) * 4 + b) * 3072 + h * 64 + quad * 8;
    short8 qa = *(const short8*)&qkv[qro];
    short8 qb = *(const short8*)&qkv[qro + 32];
    const float* up = u + h * 64 + quad * 8;
    const float* vp = v + h * 64 + quad * 8;
#pragma unroll
    for (int j = 0; j < 8; ++j) {
      const float qaf = b2f(qa[j]), qbf = b2f(qb[j]);
      aQu0[j] = f2b(qaf + up[j]);
      aQu1[j] = f2b(qbf + up[j + 32]);
      aQv0[j] = f2b(qaf + vp[j]);
      aQv1[j] = f2b(qbf + vp[j + 32]);
    }
  }

  // staging maps
  const int st_row = tid >> 3, st_d0 = (tid & 7) * 8;        // R chunk (32 rows)
  const int vj = lane & 31, vd0 = w * 16 + (lane >> 5) * 8;  // V^T scatter

  // Initial R window fill: trel 0..95, t = 960-i0+trel (never negative)
#pragma unroll
  for (int p = 0; p < 3; ++p) {
    int t = 960 - i0 + p * 32 + st_row;
    t = t > 1535 ? 1535 : t;  // clamped rows only feed masked elems
    *(short8*)&sR[(p * 32 + st_row) * 72 + st_d0] =
        *(const short8*)&rh[(size_t)t * 1024 + h * 64 + st_d0];
  }
  // V tile 0 scatter
  {
    short8 v8 = *(const short8*)&qkv[((size_t)vj * 4 + b) * 3072 + 2048 + h * 64 + vd0];
#pragma unroll
    for (int q = 0; q < 8; ++q) sVt[(vd0 + q) * 40 + vj] = v8[q];
  }
  // K fragments tile 0 (per-lane, direct from global)
  short8 rKf[4];
#pragma unroll
  for (int n0i = 0; n0i < 2; ++n0i) {
    const size_t kro = ((size_t)(n0i * 16 + m16) * 4 + b) * 3072 + 1024 + h * 64 + quad * 8;
    rKf[n0i * 2] = *(const short8*)&qkv[kro];
    rKf[n0i * 2 + 1] = *(const short8*)&qkv[kro + 32];
  }

  short8 ones;
#pragma unroll
  for (int q = 0; q < 8; ++q) ones[q] = (short)0x3F80;  // bf16 1.0

  f32x4 O[4] = {};
  f32x4 L = {};
  float m = -1e30f;
  int bk = 0;               // (32*kt) % 96: ring base; also write slot base
  int tnext = 1056 - i0;    // t-base of chunk staged for tile kt+1

  const int n_kt = ((i0 + 575) >> 5) + 1;  // valid j <= i+512, i <= i0+63
  for (int kt = 0; kt < n_kt; ++kt) {
    const int j0 = kt * 32;
    const bool pf = (kt + 1 < n_kt);
    __syncthreads();  // staged LDS writes visible

    // prefetch next tile: V + new R chunk into regs (latency hidden)
    short8 nV, nR;
    if (pf) {
      nV = *(const short8*)&qkv[((size_t)(j0 + 32 + vj) * 4 + b) * 3072 + 2048 + h * 64 + vd0];
      int t = tnext + st_row;
      t = t > 1535 ? 1535 : t;
      nR = *(const short8*)&rh[(size_t)t * 1024 + h * 64 + st_d0];
    }

    // AC tiles from register K fragments
    f32x4 ac[2];
#pragma unroll
    for (int n0i = 0; n0i < 2; ++n0i) {
      f32x4 a = {};
      a = __builtin_amdgcn_mfma_f32_16x16x32_bf16(aQu0, rKf[n0i * 2], a, 0, 0, 0);
      a = __builtin_amdgcn_mfma_f32_16x16x32_bf16(aQu1, rKf[n0i * 2 + 1], a, 0, 0, 0);
      ac[n0i] = a;
    }
    // prefetch next K fragments (regs free after AC)
    if (pf) {
#pragma unroll
      for (int n0i = 0; n0i < 2; ++n0i) {
        const size_t kro = ((size_t)(j0 + 32 + n0i * 16 + m16) * 4 + b) * 3072 + 1024 + h * 64 + quad * 8;
        rKf[n0i * 2] = *(const short8*)&qkv[kro];
        rKf[n0i * 2 + 1] = *(const short8*)&qkv[kro + 32];
      }
    }

    // P = Qv.R tiles (ring rows), wave trel window [48-16w, 94-16w]
    f32x4 pb[3];
#pragma unroll
    for (int pt = 0; pt < 3; ++pt) {
      const int p0 = 48 - 16 * w + 16 * pt;
      int pr = bk + p0;
      if (pr >= 96) pr -= 96;
      int row = pr + m16;
      if (row >= 96) row -= 96;
      const short8 bR0 = *(const short8*)&sR[row * 72 + quad * 8];
      const short8 bR1 = *(const short8*)&sR[row * 72 + 32 + quad * 8];
      f32x4 pf_ = {};
      pf_ = __builtin_amdgcn_mfma_f32_16x16x32_bf16(aQv0, bR0, pf_, 0, 0, 0);
      pf_ = __builtin_amdgcn_mfma_f32_16x16x32_bf16(aQv1, bR1, pf_, 0, 0, 0);
      pb[pt] = pf_;
    }

    // Scores; rel-shift P gather via in-wave shuffles (same quad, same rg)
    float S0[4], S1[4];
    float mxl = -1e30f;
#pragma unroll
    for (int rg = 0; rg < 4; ++rg) {
      const int rloc = quad * 4 + rg;
      const int irow = i0 + w * 16 + rloc;
      const int c0 = m16 - rloc + 15;  // in [0,30]
      const int src = (lane & 48) | (c0 & 15);
      const float t0 = __shfl(pb[0][rg], src);
      const float t1 = __shfl(pb[1][rg], src);
      const float t2 = __shfl(pb[2][rg], src);
      const float p0v = (c0 < 16) ? t0 : t1;
      const float p1v = (c0 < 16) ? t1 : t2;
      float s0 = (ac[0][rg] + p0v) * 0.125f;
      float s1 = (ac[1][rg] + p1v) * 0.125f;
      if (j0 + m16 > irow + 512) s0 = -1e30f;
      if (j0 + 16 + m16 > irow + 512) s1 = -1e30f;
      S0[rg] = s0;
      S1[rg] = s1;
      mxl = fmaxf(mxl, fmaxf(s0, s1));
    }
    // wave-shared max (valid upper bound for all 16 rows of this wave)
    mxl = fmaxf(mxl, __shfl_xor(mxl, 1));
    mxl = fmaxf(mxl, __shfl_xor(mxl, 2));
    mxl = fmaxf(mxl, __shfl_xor(mxl, 4));
    mxl = fmaxf(mxl, __shfl_xor(mxl, 8));
    mxl = fmaxf(mxl, __shfl_xor(mxl, 16));
    mxl = fmaxf(mxl, __shfl_xor(mxl, 32));
    const float mnew = fmaxf(m, mxl);
    const float al = __expf(m - mnew);
    m = mnew;
#pragma unroll
    for (int rg = 0; rg < 4; ++rg) {
      const int rloc = quad * 4 + rg;
      sProb[(w * 16 + rloc) * 40 + m16] = f2b(__expf(S0[rg] - mnew));
      sProb[(w * 16 + rloc) * 40 + 16 + m16] = f2b(__expf(S1[rg] - mnew));
    }
#pragma unroll
    for (int d0i = 0; d0i < 4; ++d0i)
#pragma unroll
      for (int rg = 0; rg < 4; ++rg) O[d0i][rg] *= al;
#pragma unroll
    for (int rg = 0; rg < 4; ++rg) L[rg] *= al;

    // PV + row-sum accumulation (ones B-fragment broadcasts l to all cols)
    const short8 aP = *(const short8*)&sProb[(w * 16 + m16) * 40 + quad * 8];
    L = __builtin_amdgcn_mfma_f32_16x16x32_bf16(aP, ones, L, 0, 0, 0);
#pragma unroll
    for (int d0i = 0; d0i < 4; ++d0i) {
      const short8 bV = *(const short8*)&sVt[(d0i * 16 + m16) * 40 + quad * 8];
      O[d0i] = __builtin_amdgcn_mfma_f32_16x16x32_bf16(aP, bV, O[d0i], 0, 0, 0);
    }

    __syncthreads();  // all LDS reads done before restage
    if (pf) {
#pragma unroll
      for (int q = 0; q < 8; ++q) sVt[(vd0 + q) * 40 + vj] = nV[q];
      *(short8*)&sR[(bk + st_row) * 72 + st_d0] = nR;  // new chunk slot
    }
    bk += 32;
    if (bk >= 96) bk = 0;
    tnext += 32;
  }

  // Epilogue: ctx[i*B+b][h*64+d] = O/L (every lane holds its rows' L)
#pragma unroll
  for (int d0i = 0; d0i < 4; ++d0i) {
#pragma unroll
    for (int rg = 0; rg < 4; ++rg) {
      const int irow = i0 + w * 16 + quad * 4 + rg;
      ctx[((size_t)irow * 4 + b) * 1024 + h * 64 + d0i * 16 + m16] = O[d0i][rg] / L[rg];
    }
  }
}

// ---------------- LayerNorms ----------------
__global__ __launch_bounds__(256) void ln1_kernel(
    const bf16* __restrict__ y, const float* __restrict__ inp,
    const float* __restrict__ g, const float* __restrict__ beta,
    float* __restrict__ xo, f16* __restrict__ xh) {
  const int r = blockIdx.x, tid = threadIdx.x;
  __shared__ float red[256];
  float t[4];
  float s = 0.f;
#pragma unroll
  for (int q = 0; q < 4; ++q) {
    int c = tid + q * 256;
    t[q] = __bfloat162float(y[(size_t)r * DM + c]) + inp[(size_t)r * DM + c];
    s += t[q];
  }
  red[tid] = s;
  __syncthreads();
  for (int st = 128; st > 0; st >>= 1) {
    if (tid < st) red[tid] += red[tid + st];
    __syncthreads();
  }
  const float mean = red[0] * (1.f / DM);
  __syncthreads();
  float vs = 0.f;
#pragma unroll
  for (int q = 0; q < 4; ++q) {
    float d0 = t[q] - mean;
    vs += d0 * d0;
  }
  red[tid] = vs;
  __syncthreads();
  for (int st = 128; st > 0; st >>= 1) {
    if (tid < st) red[tid] += red[tid + st];
    __syncthreads();
  }
  const float rstd = rsqrtf(red[0] * (1.f / DM) + 1e-5f);
#pragma unroll
  for (int q = 0; q < 4; ++q) {
    int c = tid + q * 256;
    const float val = (t[q] - mean) * rstd * g[c] + beta[c];
    xo[(size_t)r * DM + c] = val;
    xh[(size_t)r * DM + c] = (f16)val;
  }
}

__global__ __launch_bounds__(256) void ln2_kernel(
    const float* __restrict__ x, const bf16* __restrict__ y2,
    const float* __restrict__ b2, const float* __restrict__ g,
    const float* __restrict__ beta, float* __restrict__ out) {
  const int r = blockIdx.x, tid = threadIdx.x;
  __shared__ float red[256];
  float t[4];
  float s = 0.f;
#pragma unroll
  for (int q = 0; q < 4; ++q) {
    int c = tid + q * 256;
    t[q] = x[(size_t)r * DM + c] + __bfloat162float(y2[(size_t)r * DM + c]) + b2[c];
    s += t[q];
  }
  red[tid] = s;
  __syncthreads();
  for (int st = 128; st > 0; st >>= 1) {
    if (tid < st) red[tid] += red[tid + st];
    __syncthreads();
  }
  const float mean = red[0] * (1.f / DM);
  __syncthreads();
  float vs = 0.f;
#pragma unroll
  for (int q = 0; q < 4; ++q) {
    float d0 = t[q] - mean;
    vs += d0 * d0;
  }
  red[tid] = vs;
  __syncthreads();
  for (int st = 128; st > 0; st >>= 1) {
    if (tid < st) red[tid] += red[tid + st];
    __syncthreads();
  }
  const float rstd = rsqrtf(red[0] * (1.f / DM) + 1e-5f);
#pragma unroll
  for (int q = 0; q < 4; ++q) {
    int c = tid + q * 256;
    out[(size_t)r * DM + c] = (t[q] - mean) * rstd * g[c] + beta[c];
  }
}

extern "C" void kernel_launch(void* const* d_in, const int* in_sizes, int n_in,
                              void* d_out, int out_size, void* d_ws, size_t ws_size,
                              hipStream_t stream) {
  const int o = (n_in >= 17) ? 1 : 0;
  const float* inputs = (const float*)d_in[0];
  const float* r      = (const float*)d_in[1];
  const float* u      = (const float*)d_in[2];
  const float* v      = (const float*)d_in[3];
  const float* memp   = (const float*)d_in[4];
  const float* W_qkv  = (const float*)d_in[5 + o];
  const float* W_r    = (const float*)d_in[6 + o];
  const float* W_o    = (const float*)d_in[7 + o];
  const float* ln1_g  = (const float*)d_in[8 + o];
  const float* ln1_b  = (const float*)d_in[9 + o];
  const float* ln2_g  = (const float*)d_in[10 + o];
  const float* ln2_b  = (const float*)d_in[11 + o];
  const float* W1     = (const float*)d_in[12 + o];
  const float* b1     = (const float*)d_in[13 + o];
  const float* W2     = (const float*)d_in[14 + o];
  const float* b2     = (const float*)d_in[15 + o];

  // Workspace liveness plan (peak 52,428,800 B) — unchanged from R1
  char* ws = (char*)d_ws;
  f16*  WqkvT = (f16*)(ws);
  f16*  r16   = (f16*)(ws + 6291456);
  f16*  WrT   = (f16*)(ws + 9437184);
  bf16* qkv   = (bf16*)(ws + 11534336);
  bf16* rh    = (bf16*)(ws + 49283072);
  f16*  cat_h = (f16*)d_out;
  float* ctx  = (float*)d_out;
  f16*  ctx_h = (f16*)(ws);
  f16*  WoT   = (f16*)(ws + 8388608);
  bf16* y     = (bf16*)(ws + 10485760);
  float* x    = (float*)(ws + 18874368);
  f16*  x_h   = (f16*)(ws + 35651584);
  f16*  W1T   = (f16*)(ws + 44040192);
  f16*  h_lo  = (f16*)d_out;
  f16*  h_hi  = (f16*)(ws);
  f16*  W2T   = (f16*)(ws + 35651584);
  bf16* y2    = (bf16*)(ws + 44040192);

  dim3 blk(256);
  const int BIG = 1 << 30;

  // --- phase 1: QKV / R projections + attention ---
  convh_kernel<<<dim3(2048), blk, 0, stream>>>(memp, cat_h, 524288);
  convh_kernel<<<dim3(4096), blk, 0, stream>>>(inputs, cat_h + (size_t)2048 * 1024, 1048576);
  convh_kernel<<<dim3(1536), blk, 0, stream>>>(r, r16, 393216);
  convT_kernel<<<dim3(48, 16), blk, 0, stream>>>(W_qkv, WqkvT, 1024, 3072);
  convT_kernel<<<dim3(16, 16), blk, 0, stream>>>(W_r, WrT, 1024, 1024);
  hgemm_kernel<bf16><<<dim3(24, 48), blk, 0, stream>>>(
      cat_h, WqkvT, qkv, 6144, 3072, 1024, nullptr, 0, nullptr, nullptr, BIG);
  hgemm_kernel<bf16><<<dim3(8, 12), blk, 0, stream>>>(
      r16, WrT, rh, 1536, 1024, 1024, nullptr, 0, nullptr, nullptr, BIG);
  fattn_kernel<<<dim3(16, 4, 16), blk, 0, stream>>>(qkv, rh, u, v, ctx);

  // --- phase 2: output proj + LN1 + MLP + LN2 ---
  convh_kernel<<<dim3(4096), blk, 0, stream>>>(ctx, ctx_h, 1048576);
  convT_kernel<<<dim3(16, 16), blk, 0, stream>>>(W_o, WoT, 1024, 1024);
  hgemm_kernel<bf16><<<dim3(8, 32), blk, 0, stream>>>(
      ctx_h, WoT, y, 4096, 1024, 1024, nullptr, 0, nullptr, nullptr, BIG);
  ln1_kernel<<<dim3(4096), blk, 0, stream>>>(y, inputs, ln1_g, ln1_b, x, x_h);
  convT_kernel<<<dim3(64, 16), blk, 0, stream>>>(W1, W1T, 1024, 4096);
  hgemm_kernel<f16><<<dim3(32, 32), blk, 0, stream>>>(
      x_h, W1T, h_lo, 4096, 4096, 1024, b1, 1,
      x_h + (size_t)2048 * 1024, h_hi, 2048);
  convT_kernel<<<dim3(16, 64), blk, 0, stream>>>(W2, W2T, 4096, 1024);
  hgemm_kernel<bf16><<<dim3(8, 32), blk, 0, stream>>>(
      h_lo, W2T, y2, 4096, 1024, 4096, nullptr, 0,
      h_hi, y2 + (size_t)2048 * 1024, 2048);
  ln2_kernel<<<dim3(4096), blk, 0, stream>>>(x, y2, b2, ln2_g, ln2_b, (float*)d_out);
}

// Round 4
// 529.030 us; speedup vs baseline: 3.7001x; 1.0544x over previous
//
#include <hip/hip_runtime.h>
#include <hip/hip_bf16.h>

typedef __hip_bfloat16 bf16;
typedef _Float16 f16;
typedef __attribute__((ext_vector_type(8))) short short8;
typedef __attribute__((ext_vector_type(4))) float f32x4;
typedef __attribute__((ext_vector_type(8))) _Float16 f16x8;
typedef __attribute__((ext_vector_type(4))) _Float16 f16x4;

#define Q_LEN 1024
#define B_SZ 4
#define DM 1024
#define H_CNT 16
#define HD 64
#define MEM_LEN 512
#define KLEN 1536
#define MLP 4096

__device__ __forceinline__ void store_c(float* p, float v) { *p = v; }
__device__ __forceinline__ void store_c(bf16* p, float v) { *p = __float2bfloat16(v); }
__device__ __forceinline__ void store_c(f16* p, float v) { *p = (f16)v; }

__device__ __forceinline__ float b2f(short s) {
  union { unsigned u; float f; } x;
  x.u = ((unsigned)(unsigned short)s) << 16;
  return x.f;
}
__device__ __forceinline__ short f2b(float f) {
  union { float f; unsigned u; } x;
  x.f = f;
  unsigned r = x.u + 0x7fff + ((x.u >> 16) & 1);  // RNE; inputs finite
  return (short)(r >> 16);
}

// async global->LDS, 16B per lane; LDS dest = wave-uniform base + lane*16
__device__ __forceinline__ void gload16(const void* g, void* l) {
  __builtin_amdgcn_global_load_lds(
      (__attribute__((address_space(1))) unsigned int*)(g),
      (__attribute__((address_space(3))) unsigned int*)(l), 16, 0, 0);
}

// ---------------- fp32 -> fp16 elementwise convert ----------------
__global__ __launch_bounds__(256) void convh_kernel(
    const float* __restrict__ X, f16* __restrict__ Y, int n4) {
  const int i = blockIdx.x * 256 + threadIdx.x;
  if (i < n4) {
    f32x4 v = *(const f32x4*)&X[(size_t)i * 4];
    f16x4 h;
#pragma unroll
    for (int j = 0; j < 4; ++j) h[j] = (f16)v[j];
    *(f16x4*)&Y[(size_t)i * 4] = h;
  }
}

// ---------------- fp32 [K][N] -> fp16 transposed [N][K] ----------------
__global__ __launch_bounds__(256) void convT_kernel(
    const float* __restrict__ W, f16* __restrict__ WT, int K, int N) {
  __shared__ float tile[64][65];
  const int tid = threadIdx.x;
  const int k0 = blockIdx.y * 64, n0 = blockIdx.x * 64;
  const int tn = tid & 63, tk4 = tid >> 6;
#pragma unroll
  for (int p = 0; p < 16; ++p) {
    const int kk = tk4 + p * 4;
    tile[kk][tn] = W[(size_t)(k0 + kk) * N + n0 + tn];
  }
  __syncthreads();
#pragma unroll
  for (int p = 0; p < 16; ++p) {
    const int nn = tk4 + p * 4;
    WT[(size_t)(n0 + nn) * K + k0 + tn] = (f16)tile[tn][nn];
  }
}

// ---------------- fp16 MFMA GEMM: C = A[M,K] * BT[N,K]^T ----------------
// R4: 3-buffer pipeline, counted vmcnt(4) + raw s_barrier (no per-step
// vmcnt(0) drain), setprio around MFMA cluster, XCD-aware block swizzle.
// 128x128 tile, BK=32, 4 waves 2x2, 16x16x32_f16. LDS 48KB -> 3 blocks/CU.
template <typename TC>
__global__ __launch_bounds__(256, 3) void hgemm_kernel(
    const f16* __restrict__ A, const f16* __restrict__ BT, TC* __restrict__ C,
    int M, int N, int K, const float* __restrict__ bias, int relu,
    const f16* __restrict__ Aalt, TC* __restrict__ Calt, int split) {
  __shared__ __align__(16) f16 sA[3][128 * 32];
  __shared__ __align__(16) f16 sB[3][128 * 32];
  const int tid = threadIdx.x;
  const int w = tid >> 6, lane = tid & 63;
  const int quad = lane >> 4, m16 = lane & 15;
  const int wr = w >> 1, wc = w & 1;
  // XCD-aware swizzle: all our grids have nwg % 8 == 0 (bijective).
  const int gx = gridDim.x;
  const int nwg = gx * gridDim.y;
  const int lin = blockIdx.y * gx + blockIdx.x;
  const int cpx = nwg >> 3;
  const int swz = (lin & 7) * cpx + (lin >> 3);
  const int bx = swz % gx, by = swz / gx;
  const int col0 = bx * 128;
  int r0 = by * 128;
  const f16* Ause = A;
  TC* Cuse = C;
  if (r0 >= split) { Ause = Aalt; Cuse = Calt; r0 -= split; }

  // staging: thread t covers LDS row (t>>2) (+64 for 2nd call), chunk t&3;
  // fetches global chunk (t&3) ^ ((row>>1)&3) (pre-swizzled source)
  const int strow = tid >> 2;
  const int schunk = tid & 3;
  const int sw = schunk ^ ((strow >> 1) & 3);
  const f16* gA0 = Ause + (size_t)(r0 + strow) * K + sw * 8;
  const f16* gB0 = BT + (size_t)(col0 + strow) * K + sw * 8;
  f16* ldsA0 = &sA[0][0] + (size_t)w * 512;
  f16* ldsB0 = &sB[0][0] + (size_t)w * 512;

  // ds_read offsets (f16 elems): row rt, swizzled chunk quad^((rt>>1)&3)
  const int qs = quad ^ ((m16 >> 1) & 3);
  int aoff[4], boff[4];
#pragma unroll
  for (int i = 0; i < 4; ++i) {
    aoff[i] = (wr * 64 + i * 16 + m16) * 32 + qs * 8;
    boff[i] = (wc * 64 + i * 16 + m16) * 32 + qs * 8;
  }

  const int nkt = K >> 5;  // >= 32 in all our launches
  f32x4 acc[4][4] = {};

  auto stage = [&](int buf, int t) {
    const int k0 = t << 5;
    const size_t bufo = (size_t)buf * 4096;
    gload16(gA0 + k0, ldsA0 + bufo);
    gload16(gA0 + (size_t)64 * K + k0, ldsA0 + bufo + 2048);
    gload16(gB0 + k0, ldsB0 + bufo);
    gload16(gB0 + (size_t)64 * K + k0, ldsB0 + bufo + 2048);
  };

  stage(0, 0);
  stage(1, 1);
  int cur = 0;
  for (int t = 0; t < nkt; ++t) {
    // Tile t's 4 loads are the oldest outstanding; vmcnt(4) => they landed
    // while tile t+1's 4 stay in flight (never drain to 0 mid-loop).
    if (t + 1 < nkt) {
      asm volatile("s_waitcnt vmcnt(4)" ::: "memory");
    } else {
      asm volatile("s_waitcnt vmcnt(0)" ::: "memory");
    }
    __builtin_amdgcn_s_barrier();
    if (t + 2 < nkt) {
      int nb = cur + 2;
      if (nb >= 3) nb -= 3;
      stage(nb, t + 2);  // slot was last read in iter t-1; all waves past it
    }
    f16x8 af[4], bfr[4];
#pragma unroll
    for (int i = 0; i < 4; ++i) af[i] = *(const f16x8*)&sA[cur][aoff[i]];
#pragma unroll
    for (int i = 0; i < 4; ++i) bfr[i] = *(const f16x8*)&sB[cur][boff[i]];
    __builtin_amdgcn_s_setprio(1);
#pragma unroll
    for (int mi = 0; mi < 4; ++mi)
#pragma unroll
      for (int ni = 0; ni < 4; ++ni)
        acc[mi][ni] = __builtin_amdgcn_mfma_f32_16x16x32_f16(
            af[mi], bfr[ni], acc[mi][ni], 0, 0, 0);
    __builtin_amdgcn_s_setprio(0);
    cur = (cur + 1 == 3) ? 0 : cur + 1;
  }

  // Epilogue: D layout col=lane&15, row=quad*4+rg (16x16 family)
#pragma unroll
  for (int mi = 0; mi < 4; ++mi) {
    const int row = r0 + wr * 64 + mi * 16 + quad * 4;
#pragma unroll
    for (int ni = 0; ni < 4; ++ni) {
      const int col = col0 + wc * 64 + ni * 16 + m16;
      const float bv = bias ? bias[col] : 0.f;
#pragma unroll
      for (int rg = 0; rg < 4; ++rg) {
        float vv = acc[mi][ni][rg] + bv;
        if (relu) vv = vv > 0.f ? vv : 0.f;
        store_c(&Cuse[(size_t)(row + rg) * N + col], vv);
      }
    }
  }
}

// ---------------- Fused flash-MFMA attention ----------------
// R4 vs R3: 1D grid with XCD-locality decode — all 16 i0-blocks of one
// (b,h) share lin%8 (same XCD) so the (b,h) K/V/R window (~590KB) L2-hits;
// LPT kept (i0 descending). Kernel body unchanged from R3 (passing).
__global__ __launch_bounds__(256, 4) void fattn_kernel(
    const bf16* __restrict__ qkvp,  // [1536*4, 3072] rows k*B+b, bf16
    const bf16* __restrict__ rhp,   // [1536, 1024] bf16
    const float* __restrict__ u, const float* __restrict__ v,
    float* __restrict__ ctx) {      // [4096, 1024] fp32 (in d_out)
  const int lin = blockIdx.x;      // 1024 blocks
  const int p = lin & 63;          // (b,h) pair; p%8 = XCD
  const int b = p & 3, h = p >> 2;
  const int i0 = (15 - (lin >> 6)) * 64;  // heavy tiles first
  const int tid = threadIdx.x;
  const int w = tid >> 6, lane = tid & 63;
  const int quad = lane >> 4, m16 = lane & 15;

  __shared__ short sVt[64 * 40];   // V^T tile: [d][j]
  __shared__ short sR[96 * 72];    // R ring buffer (phys = (32kt+trel)%96)
  __shared__ short sProb[64 * 40]; // probs bf16, per-wave strips

  const short* qkv = (const short*)qkvp;
  const short* rh  = (const short*)rhp;

  // Per-lane Q fragments: aQu = q+u (AC), aQv = q+v (BD). Rows w*16+m16.
  short8 aQu0, aQu1, aQv0, aQv1;
  {
    const size_t qro = ((size_t)(512 + i0 + w * 16 + m16) * 4 + b) * 3072 + h * 64 + quad * 8;
    short8 qa = *(const short8*)&qkv[qro];
    short8 qb = *(const short8*)&qkv[qro + 32];
    const float* up = u + h * 64 + quad * 8;
    const float* vp = v + h * 64 + quad * 8;
#pragma unroll
    for (int j = 0; j < 8; ++j) {
      const float qaf = b2f(qa[j]), qbf = b2f(qb[j]);
      aQu0[j] = f2b(qaf + up[j]);
      aQu1[j] = f2b(qbf + up[j + 32]);
      aQv0[j] = f2b(qaf + vp[j]);
      aQv1[j] = f2b(qbf + vp[j + 32]);
    }
  }

  // staging maps
  const int st_row = tid >> 3, st_d0 = (tid & 7) * 8;        // R chunk (32 rows)
  const int vj = lane & 31, vd0 = w * 16 + (lane >> 5) * 8;  // V^T scatter

  // Initial R window fill: trel 0..95, t = 960-i0+trel (never negative)
#pragma unroll
  for (int p_ = 0; p_ < 3; ++p_) {
    int t = 960 - i0 + p_ * 32 + st_row;
    t = t > 1535 ? 1535 : t;  // clamped rows only feed masked elems
    *(short8*)&sR[(p_ * 32 + st_row) * 72 + st_d0] =
        *(const short8*)&rh[(size_t)t * 1024 + h * 64 + st_d0];
  }
  // V tile 0 scatter
  {
    short8 v8 = *(const short8*)&qkv[((size_t)vj * 4 + b) * 3072 + 2048 + h * 64 + vd0];
#pragma unroll
    for (int q = 0; q < 8; ++q) sVt[(vd0 + q) * 40 + vj] = v8[q];
  }
  // K fragments tile 0 (per-lane, direct from global)
  short8 rKf[4];
#pragma unroll
  for (int n0i = 0; n0i < 2; ++n0i) {
    const size_t kro = ((size_t)(n0i * 16 + m16) * 4 + b) * 3072 + 1024 + h * 64 + quad * 8;
    rKf[n0i * 2] = *(const short8*)&qkv[kro];
    rKf[n0i * 2 + 1] = *(const short8*)&qkv[kro + 32];
  }

  short8 ones;
#pragma unroll
  for (int q = 0; q < 8; ++q) ones[q] = (short)0x3F80;  // bf16 1.0

  f32x4 O[4] = {};
  f32x4 L = {};
  float m = -1e30f;
  int bk = 0;               // (32*kt) % 96: ring base; also write slot base
  int tnext = 1056 - i0;    // t-base of chunk staged for tile kt+1

  const int n_kt = ((i0 + 575) >> 5) + 1;  // valid j <= i+512, i <= i0+63
  for (int kt = 0; kt < n_kt; ++kt) {
    const int j0 = kt * 32;
    const bool pf = (kt + 1 < n_kt);
    __syncthreads();  // staged LDS writes visible

    // prefetch next tile: V + new R chunk into regs (latency hidden)
    short8 nV, nR;
    if (pf) {
      nV = *(const short8*)&qkv[((size_t)(j0 + 32 + vj) * 4 + b) * 3072 + 2048 + h * 64 + vd0];
      int t = tnext + st_row;
      t = t > 1535 ? 1535 : t;
      nR = *(const short8*)&rh[(size_t)t * 1024 + h * 64 + st_d0];
    }

    // AC tiles from register K fragments
    f32x4 ac[2];
#pragma unroll
    for (int n0i = 0; n0i < 2; ++n0i) {
      f32x4 a = {};
      a = __builtin_amdgcn_mfma_f32_16x16x32_bf16(aQu0, rKf[n0i * 2], a, 0, 0, 0);
      a = __builtin_amdgcn_mfma_f32_16x16x32_bf16(aQu1, rKf[n0i * 2 + 1], a, 0, 0, 0);
      ac[n0i] = a;
    }
    // prefetch next K fragments (regs free after AC)
    if (pf) {
#pragma unroll
      for (int n0i = 0; n0i < 2; ++n0i) {
        const size_t kro = ((size_t)(j0 + 32 + n0i * 16 + m16) * 4 + b) * 3072 + 1024 + h * 64 + quad * 8;
        rKf[n0i * 2] = *(const short8*)&qkv[kro];
        rKf[n0i * 2 + 1] = *(const short8*)&qkv[kro + 32];
      }
    }

    // P = Qv.R tiles (ring rows), wave trel window [48-16w, 94-16w]
    f32x4 pb[3];
#pragma unroll
    for (int pt = 0; pt < 3; ++pt) {
      const int p0 = 48 - 16 * w + 16 * pt;
      int pr = bk + p0;
      if (pr >= 96) pr -= 96;
      int row = pr + m16;
      if (row >= 96) row -= 96;
      const short8 bR0 = *(const short8*)&sR[row * 72 + quad * 8];
      const short8 bR1 = *(const short8*)&sR[row * 72 + 32 + quad * 8];
      f32x4 pf_ = {};
      pf_ = __builtin_amdgcn_mfma_f32_16x16x32_bf16(aQv0, bR0, pf_, 0, 0, 0);
      pf_ = __builtin_amdgcn_mfma_f32_16x16x32_bf16(aQv1, bR1, pf_, 0, 0, 0);
      pb[pt] = pf_;
    }

    // Scores; rel-shift P gather via in-wave shuffles (same quad, same rg)
    float S0[4], S1[4];
    float mxl = -1e30f;
#pragma unroll
    for (int rg = 0; rg < 4; ++rg) {
      const int rloc = quad * 4 + rg;
      const int irow = i0 + w * 16 + rloc;
      const int c0 = m16 - rloc + 15;  // in [0,30]
      const int src = (lane & 48) | (c0 & 15);
      const float t0 = __shfl(pb[0][rg], src);
      const float t1 = __shfl(pb[1][rg], src);
      const float t2 = __shfl(pb[2][rg], src);
      const float p0v = (c0 < 16) ? t0 : t1;
      const float p1v = (c0 < 16) ? t1 : t2;
      float s0 = (ac[0][rg] + p0v) * 0.125f;
      float s1 = (ac[1][rg] + p1v) * 0.125f;
      if (j0 + m16 > irow + 512) s0 = -1e30f;
      if (j0 + 16 + m16 > irow + 512) s1 = -1e30f;
      S0[rg] = s0;
      S1[rg] = s1;
      mxl = fmaxf(mxl, fmaxf(s0, s1));
    }
    // wave-shared max (valid upper bound for all 16 rows of this wave)
    mxl = fmaxf(mxl, __shfl_xor(mxl, 1));
    mxl = fmaxf(mxl, __shfl_xor(mxl, 2));
    mxl = fmaxf(mxl, __shfl_xor(mxl, 4));
    mxl = fmaxf(mxl, __shfl_xor(mxl, 8));
    mxl = fmaxf(mxl, __shfl_xor(mxl, 16));
    mxl = fmaxf(mxl, __shfl_xor(mxl, 32));
    const float mnew = fmaxf(m, mxl);
    const float al = __expf(m - mnew);
    m = mnew;
#pragma unroll
    for (int rg = 0; rg < 4; ++rg) {
      const int rloc = quad * 4 + rg;
      sProb[(w * 16 + rloc) * 40 + m16] = f2b(__expf(S0[rg] - mnew));
      sProb[(w * 16 + rloc) * 40 + 16 + m16] = f2b(__expf(S1[rg] - mnew));
    }
#pragma unroll
    for (int d0i = 0; d0i < 4; ++d0i)
#pragma unroll
      for (int rg = 0; rg < 4; ++rg) O[d0i][rg] *= al;
#pragma unroll
    for (int rg = 0; rg < 4; ++rg) L[rg] *= al;

    // PV + row-sum accumulation (ones B-fragment broadcasts l to all cols)
    const short8 aP = *(const short8*)&sProb[(w * 16 + m16) * 40 + quad * 8];
    L = __builtin_amdgcn_mfma_f32_16x16x32_bf16(aP, ones, L, 0, 0, 0);
#pragma unroll
    for (int d0i = 0; d0i < 4; ++d0i) {
      const short8 bV = *(const short8*)&sVt[(d0i * 16 + m16) * 40 + quad * 8];
      O[d0i] = __builtin_amdgcn_mfma_f32_16x16x32_bf16(aP, bV, O[d0i], 0, 0, 0);
    }

    __syncthreads();  // all LDS reads done before restage
    if (pf) {
#pragma unroll
      for (int q = 0; q < 8; ++q) sVt[(vd0 + q) * 40 + vj] = nV[q];
      *(short8*)&sR[(bk + st_row) * 72 + st_d0] = nR;  // new chunk slot
    }
    bk += 32;
    if (bk >= 96) bk = 0;
    tnext += 32;
  }

  // Epilogue: ctx[i*B+b][h*64+d] = O/L (every lane holds its rows' L)
#pragma unroll
  for (int d0i = 0; d0i < 4; ++d0i) {
#pragma unroll
    for (int rg = 0; rg < 4; ++rg) {
      const int irow = i0 + w * 16 + quad * 4 + rg;
      ctx[((size_t)irow * 4 + b) * 1024 + h * 64 + d0i * 16 + m16] = O[d0i][rg] / L[rg];
    }
  }
}

// ---------------- LayerNorms ----------------
__global__ __launch_bounds__(256) void ln1_kernel(
    const bf16* __restrict__ y, const float* __restrict__ inp,
    const float* __restrict__ g, const float* __restrict__ beta,
    float* __restrict__ xo, f16* __restrict__ xh) {
  const int r = blockIdx.x, tid = threadIdx.x;
  __shared__ float red[256];
  float t[4];
  float s = 0.f;
#pragma unroll
  for (int q = 0; q < 4; ++q) {
    int c = tid + q * 256;
    t[q] = __bfloat162float(y[(size_t)r * DM + c]) + inp[(size_t)r * DM + c];
    s += t[q];
  }
  red[tid] = s;
  __syncthreads();
  for (int st = 128; st > 0; st >>= 1) {
    if (tid < st) red[tid] += red[tid + st];
    __syncthreads();
  }
  const float mean = red[0] * (1.f / DM);
  __syncthreads();
  float vs = 0.f;
#pragma unroll
  for (int q = 0; q < 4; ++q) {
    float d0 = t[q] - mean;
    vs += d0 * d0;
  }
  red[tid] = vs;
  __syncthreads();
  for (int st = 128; st > 0; st >>= 1) {
    if (tid < st) red[tid] += red[tid + st];
    __syncthreads();
  }
  const float rstd = rsqrtf(red[0] * (1.f / DM) + 1e-5f);
#pragma unroll
  for (int q = 0; q < 4; ++q) {
    int c = tid + q * 256;
    const float val = (t[q] - mean) * rstd * g[c] + beta[c];
    xo[(size_t)r * DM + c] = val;
    xh[(size_t)r * DM + c] = (f16)val;
  }
}

__global__ __launch_bounds__(256) void ln2_kernel(
    const float* __restrict__ x, const bf16* __restrict__ y2,
    const float* __restrict__ b2, const float* __restrict__ g,
    const float* __restrict__ beta, float* __restrict__ out) {
  const int r = blockIdx.x, tid = threadIdx.x;
  __shared__ float red[256];
  float t[4];
  float s = 0.f;
#pragma unroll
  for (int q = 0; q < 4; ++q) {
    int c = tid + q * 256;
    t[q] = x[(size_t)r * DM + c] + __bfloat162float(y2[(size_t)r * DM + c]) + b2[c];
    s += t[q];
  }
  red[tid] = s;
  __syncthreads();
  for (int st = 128; st > 0; st >>= 1) {
    if (tid < st) red[tid] += red[tid + st];
    __syncthreads();
  }
  const float mean = red[0] * (1.f / DM);
  __syncthreads();
  float vs = 0.f;
#pragma unroll
  for (int q = 0; q < 4; ++q) {
    float d0 = t[q] - mean;
    vs += d0 * d0;
  }
  red[tid] = vs;
  __syncthreads();
  for (int st = 128; st > 0; st >>= 1) {
    if (tid < st) red[tid] += red[tid + st];
    __syncthreads();
  }
  const float rstd = rsqrtf(red[0] * (1.f / DM) + 1e-5f);
#pragma unroll
  for (int q = 0; q < 4; ++q) {
    int c = tid + q * 256;
    out[(size_t)r * DM + c] = (t[q] - mean) * rstd * g[c] + beta[c];
  }
}

extern "C" void kernel_launch(void* const* d_in, const int* in_sizes, int n_in,
                              void* d_out, int out_size, void* d_ws, size_t ws_size,
                              hipStream_t stream) {
  const int o = (n_in >= 17) ? 1 : 0;
  const float* inputs = (const float*)d_in[0];
  const float* r      = (const float*)d_in[1];
  const float* u      = (const float*)d_in[2];
  const float* v      = (const float*)d_in[3];
  const float* memp   = (const float*)d_in[4];
  const float* W_qkv  = (const float*)d_in[5 + o];
  const float* W_r    = (const float*)d_in[6 + o];
  const float* W_o    = (const float*)d_in[7 + o];
  const float* ln1_g  = (const float*)d_in[8 + o];
  const float* ln1_b  = (const float*)d_in[9 + o];
  const float* ln2_g  = (const float*)d_in[10 + o];
  const float* ln2_b  = (const float*)d_in[11 + o];
  const float* W1     = (const float*)d_in[12 + o];
  const float* b1     = (const float*)d_in[13 + o];
  const float* W2     = (const float*)d_in[14 + o];
  const float* b2     = (const float*)d_in[15 + o];

  // Workspace liveness plan (peak 52,428,800 B) — unchanged from R1
  char* ws = (char*)d_ws;
  f16*  WqkvT = (f16*)(ws);
  f16*  r16   = (f16*)(ws + 6291456);
  f16*  WrT   = (f16*)(ws + 9437184);
  bf16* qkv   = (bf16*)(ws + 11534336);
  bf16* rh    = (bf16*)(ws + 49283072);
  f16*  cat_h = (f16*)d_out;
  float* ctx  = (float*)d_out;
  f16*  ctx_h = (f16*)(ws);
  f16*  WoT   = (f16*)(ws + 8388608);
  bf16* y     = (bf16*)(ws + 10485760);
  float* x    = (float*)(ws + 18874368);
  f16*  x_h   = (f16*)(ws + 35651584);
  f16*  W1T   = (f16*)(ws + 44040192);
  f16*  h_lo  = (f16*)d_out;
  f16*  h_hi  = (f16*)(ws);
  f16*  W2T   = (f16*)(ws + 35651584);
  bf16* y2    = (bf16*)(ws + 44040192);

  dim3 blk(256);
  const int BIG = 1 << 30;

  // --- phase 1: QKV / R projections + attention ---
  convh_kernel<<<dim3(2048), blk, 0, stream>>>(memp, cat_h, 524288);
  convh_kernel<<<dim3(4096), blk, 0, stream>>>(inputs, cat_h + (size_t)2048 * 1024, 1048576);
  convh_kernel<<<dim3(1536), blk, 0, stream>>>(r, r16, 393216);
  convT_kernel<<<dim3(48, 16), blk, 0, stream>>>(W_qkv, WqkvT, 1024, 3072);
  convT_kernel<<<dim3(16, 16), blk, 0, stream>>>(W_r, WrT, 1024, 1024);
  hgemm_kernel<bf16><<<dim3(24, 48), blk, 0, stream>>>(
      cat_h, WqkvT, qkv, 6144, 3072, 1024, nullptr, 0, nullptr, nullptr, BIG);
  hgemm_kernel<bf16><<<dim3(8, 12), blk, 0, stream>>>(
      r16, WrT, rh, 1536, 1024, 1024, nullptr, 0, nullptr, nullptr, BIG);
  fattn_kernel<<<dim3(1024), blk, 0, stream>>>(qkv, rh, u, v, ctx);

  // --- phase 2: output proj + LN1 + MLP + LN2 ---
  convh_kernel<<<dim3(4096), blk, 0, stream>>>(ctx, ctx_h, 1048576);
  convT_kernel<<<dim3(16, 16), blk, 0, stream>>>(W_o, WoT, 1024, 1024);
  hgemm_kernel<bf16><<<dim3(8, 32), blk, 0, stream>>>(
      ctx_h, WoT, y, 4096, 1024, 1024, nullptr, 0, nullptr, nullptr, BIG);
  ln1_kernel<<<dim3(4096), blk, 0, stream>>>(y, inputs, ln1_g, ln1_b, x, x_h);
  convT_kernel<<<dim3(64, 16), blk, 0, stream>>>(W1, W1T, 1024, 4096);
  hgemm_kernel<f16><<<dim3(32, 32), blk, 0, stream>>>(
      x_h, W1T, h_lo, 4096, 4096, 1024, b1, 1,
      x_h + (size_t)2048 * 1024, h_hi, 2048);
  convT_kernel<<<dim3(16, 64), blk, 0, stream>>>(W2, W2T, 4096, 1024);
  hgemm_kernel<bf16><<<dim3(8, 32), blk, 0, stream>>>(
      h_lo, W2T, y2, 4096, 1024, 4096, nullptr, 0,
      h_hi, y2 + (size_t)2048 * 1024, 2048);
  ln2_kernel<<<dim3(4096), blk, 0, stream>>>(x, y2, b2, ln2_g, ln2_b, (float*)d_out);
}

// Round 5
// 483.370 us; speedup vs baseline: 4.0496x; 1.0945x over previous
//
#include <hip/hip_runtime.h>
#include <hip/hip_bf16.h>

typedef __hip_bfloat16 bf16;
typedef _Float16 f16;
typedef __attribute__((ext_vector_type(8))) short short8;
typedef __attribute__((ext_vector_type(4))) float f32x4;
typedef __attribute__((ext_vector_type(8))) _Float16 f16x8;
typedef __attribute__((ext_vector_type(4))) _Float16 f16x4;

#define Q_LEN 1024
#define B_SZ 4
#define DM 1024
#define H_CNT 16
#define HD 64
#define MEM_LEN 512
#define KLEN 1536
#define MLP 4096

__device__ __forceinline__ void store_c(float* p, float v) { *p = v; }
__device__ __forceinline__ void store_c(bf16* p, float v) { *p = __float2bfloat16(v); }
__device__ __forceinline__ void store_c(f16* p, float v) { *p = (f16)v; }

__device__ __forceinline__ float b2f(short s) {
  union { unsigned u; float f; } x;
  x.u = ((unsigned)(unsigned short)s) << 16;
  return x.f;
}
__device__ __forceinline__ short f2b(float f) {
  union { float f; unsigned u; } x;
  x.f = f;
  unsigned r = x.u + 0x7fff + ((x.u >> 16) & 1);  // RNE; inputs finite
  return (short)(r >> 16);
}

// async global->LDS, 16B per lane; LDS dest = wave-uniform base + lane*16
__device__ __forceinline__ void gload16(const void* g, void* l) {
  __builtin_amdgcn_global_load_lds(
      (__attribute__((address_space(1))) unsigned int*)(g),
      (__attribute__((address_space(3))) unsigned int*)(l), 16, 0, 0);
}

// ---------------- fp32 -> fp16 elementwise convert ----------------
__global__ __launch_bounds__(256) void convh_kernel(
    const float* __restrict__ X, f16* __restrict__ Y, int n4) {
  const int i = blockIdx.x * 256 + threadIdx.x;
  if (i < n4) {
    f32x4 v = *(const f32x4*)&X[(size_t)i * 4];
    f16x4 h;
#pragma unroll
    for (int j = 0; j < 4; ++j) h[j] = (f16)v[j];
    *(f16x4*)&Y[(size_t)i * 4] = h;
  }
}

// ---------------- fp32 [K][N] -> fp16 transposed [N][K] ----------------
__global__ __launch_bounds__(256) void convT_kernel(
    const float* __restrict__ W, f16* __restrict__ WT, int K, int N) {
  __shared__ float tile[64][65];
  const int tid = threadIdx.x;
  const int k0 = blockIdx.y * 64, n0 = blockIdx.x * 64;
  const int tn = tid & 63, tk4 = tid >> 6;
#pragma unroll
  for (int p = 0; p < 16; ++p) {
    const int kk = tk4 + p * 4;
    tile[kk][tn] = W[(size_t)(k0 + kk) * N + n0 + tn];
  }
  __syncthreads();
#pragma unroll
  for (int p = 0; p < 16; ++p) {
    const int nn = tk4 + p * 4;
    WT[(size_t)(n0 + nn) * K + k0 + tn] = (f16)tile[tn][nn];
  }
}

// ---------------- fp16 MFMA GEMM: C = A[M,K] * BT[N,K]^T ----------------
// R5: + split-K (ksplit=2): gridDim.y doubled; upper half computes K-half 2
// into (Cb,Cbalt) f16 partials (bias/relu must be off). Raises Wo/W2 from
// 1 to 2 resident blocks/CU. 3-buffer counted-vmcnt pipeline kept from R4.
template <typename TC>
__global__ __launch_bounds__(256, 3) void hgemm_kernel(
    const f16* __restrict__ A, const f16* __restrict__ BT, TC* C,
    int N, int K, const float* __restrict__ bias, int relu,
    const f16* __restrict__ Aalt, TC* Calt, int split,
    TC* Cb, TC* Cbalt, int ksplit) {
  __shared__ __align__(16) f16 sA[3][128 * 32];
  __shared__ __align__(16) f16 sB[3][128 * 32];
  const int tid = threadIdx.x;
  const int w = tid >> 6, lane = tid & 63;
  const int quad = lane >> 4, m16 = lane & 15;
  const int wr = w >> 1, wc = w & 1;
  // XCD-aware swizzle: all our grids have nwg % 8 == 0 (bijective).
  const int gx = gridDim.x;
  const int nwg = gx * gridDim.y;
  const int lin = blockIdx.y * gx + blockIdx.x;
  const int cpx = nwg >> 3;
  const int swz = (lin & 7) * cpx + (lin >> 3);
  const int bx = swz % gx;
  int by = swz / gx;
  int koff = 0, Kloc = K;
  if (ksplit == 2) {
    const int mh = gridDim.y >> 1;
    if (by >= mh) { by -= mh; koff = K >> 1; C = Cb; Calt = Cbalt; }
    Kloc = K >> 1;
  }
  const int col0 = bx * 128;
  int r0 = by * 128;
  const f16* Ause = A;
  TC* Cuse = C;
  if (r0 >= split) { Ause = Aalt; Cuse = Calt; r0 -= split; }

  // staging: thread t covers LDS row (t>>2) (+64 for 2nd call), chunk t&3;
  // fetches global chunk (t&3) ^ ((row>>1)&3) (pre-swizzled source)
  const int strow = tid >> 2;
  const int schunk = tid & 3;
  const int sw = schunk ^ ((strow >> 1) & 3);
  const f16* gA0 = Ause + (size_t)(r0 + strow) * K + koff + sw * 8;
  const f16* gB0 = BT + (size_t)(col0 + strow) * K + koff + sw * 8;
  f16* ldsA0 = &sA[0][0] + (size_t)w * 512;
  f16* ldsB0 = &sB[0][0] + (size_t)w * 512;

  // ds_read offsets (f16 elems): row rt, swizzled chunk quad^((rt>>1)&3)
  const int qs = quad ^ ((m16 >> 1) & 3);
  int aoff[4], boff[4];
#pragma unroll
  for (int i = 0; i < 4; ++i) {
    aoff[i] = (wr * 64 + i * 16 + m16) * 32 + qs * 8;
    boff[i] = (wc * 64 + i * 16 + m16) * 32 + qs * 8;
  }

  const int nkt = Kloc >> 5;  // >= 16 in all our launches
  f32x4 acc[4][4] = {};

  auto stage = [&](int buf, int t) {
    const int k0 = t << 5;
    const size_t bufo = (size_t)buf * 4096;
    gload16(gA0 + k0, ldsA0 + bufo);
    gload16(gA0 + (size_t)64 * K + k0, ldsA0 + bufo + 2048);
    gload16(gB0 + k0, ldsB0 + bufo);
    gload16(gB0 + (size_t)64 * K + k0, ldsB0 + bufo + 2048);
  };

  stage(0, 0);
  stage(1, 1);
  int cur = 0;
  for (int t = 0; t < nkt; ++t) {
    // Tile t's 4 loads are the oldest outstanding; vmcnt(4) => they landed
    // while tile t+1's 4 stay in flight (never drain to 0 mid-loop).
    if (t + 1 < nkt) {
      asm volatile("s_waitcnt vmcnt(4)" ::: "memory");
    } else {
      asm volatile("s_waitcnt vmcnt(0)" ::: "memory");
    }
    __builtin_amdgcn_s_barrier();
    if (t + 2 < nkt) {
      int nb = cur + 2;
      if (nb >= 3) nb -= 3;
      stage(nb, t + 2);  // slot was last read in iter t-1; all waves past it
    }
    f16x8 af[4], bfr[4];
#pragma unroll
    for (int i = 0; i < 4; ++i) af[i] = *(const f16x8*)&sA[cur][aoff[i]];
#pragma unroll
    for (int i = 0; i < 4; ++i) bfr[i] = *(const f16x8*)&sB[cur][boff[i]];
    __builtin_amdgcn_s_setprio(1);
#pragma unroll
    for (int mi = 0; mi < 4; ++mi)
#pragma unroll
      for (int ni = 0; ni < 4; ++ni)
        acc[mi][ni] = __builtin_amdgcn_mfma_f32_16x16x32_f16(
            af[mi], bfr[ni], acc[mi][ni], 0, 0, 0);
    __builtin_amdgcn_s_setprio(0);
    cur = (cur + 1 == 3) ? 0 : cur + 1;
  }

  // Epilogue: D layout col=lane&15, row=quad*4+rg (16x16 family)
#pragma unroll
  for (int mi = 0; mi < 4; ++mi) {
    const int row = r0 + wr * 64 + mi * 16 + quad * 4;
#pragma unroll
    for (int ni = 0; ni < 4; ++ni) {
      const int col = col0 + wc * 64 + ni * 16 + m16;
      const float bv = bias ? bias[col] : 0.f;
#pragma unroll
      for (int rg = 0; rg < 4; ++rg) {
        float vv = acc[mi][ni][rg] + bv;
        if (relu) vv = vv > 0.f ? vv : 0.f;
        store_c(&Cuse[(size_t)(row + rg) * N + col], vv);
      }
    }
  }
}

// ---------------- Fused flash-MFMA attention ----------------
// R5 vs R4: epilogue writes f16 ctx directly (kills the ctx->f16 convh
// kernel + halves epilogue store traffic). Body otherwise unchanged.
__global__ __launch_bounds__(256, 4) void fattn_kernel(
    const bf16* __restrict__ qkvp,  // [1536*4, 3072] rows k*B+b, bf16
    const bf16* __restrict__ rhp,   // [1536, 1024] bf16
    const float* __restrict__ u, const float* __restrict__ v,
    f16* __restrict__ ctxh) {       // [4096, 1024] f16
  const int lin = blockIdx.x;      // 1024 blocks
  const int p = lin & 63;          // (b,h) pair; p%8 = XCD
  const int b = p & 3, h = p >> 2;
  const int i0 = (15 - (lin >> 6)) * 64;  // heavy tiles first
  const int tid = threadIdx.x;
  const int w = tid >> 6, lane = tid & 63;
  const int quad = lane >> 4, m16 = lane & 15;

  __shared__ short sVt[64 * 40];   // V^T tile: [d][j]
  __shared__ short sR[96 * 72];    // R ring buffer (phys = (32kt+trel)%96)
  __shared__ short sProb[64 * 40]; // probs bf16, per-wave strips

  const short* qkv = (const short*)qkvp;
  const short* rh  = (const short*)rhp;

  // Per-lane Q fragments: aQu = q+u (AC), aQv = q+v (BD). Rows w*16+m16.
  short8 aQu0, aQu1, aQv0, aQv1;
  {
    const size_t qro = ((size_t)(512 + i0 + w * 16 + m16) * 4 + b) * 3072 + h * 64 + quad * 8;
    short8 qa = *(const short8*)&qkv[qro];
    short8 qb = *(const short8*)&qkv[qro + 32];
    const float* up = u + h * 64 + quad * 8;
    const float* vp = v + h * 64 + quad * 8;
#pragma unroll
    for (int j = 0; j < 8; ++j) {
      const float qaf = b2f(qa[j]), qbf = b2f(qb[j]);
      aQu0[j] = f2b(qaf + up[j]);
      aQu1[j] = f2b(qbf + up[j + 32]);
      aQv0[j] = f2b(qaf + vp[j]);
      aQv1[j] = f2b(qbf + vp[j + 32]);
    }
  }

  // staging maps
  const int st_row = tid >> 3, st_d0 = (tid & 7) * 8;        // R chunk (32 rows)
  const int vj = lane & 31, vd0 = w * 16 + (lane >> 5) * 8;  // V^T scatter

  // Initial R window fill: trel 0..95, t = 960-i0+trel (never negative)
#pragma unroll
  for (int p_ = 0; p_ < 3; ++p_) {
    int t = 960 - i0 + p_ * 32 + st_row;
    t = t > 1535 ? 1535 : t;  // clamped rows only feed masked elems
    *(short8*)&sR[(p_ * 32 + st_row) * 72 + st_d0] =
        *(const short8*)&rh[(size_t)t * 1024 + h * 64 + st_d0];
  }
  // V tile 0 scatter
  {
    short8 v8 = *(const short8*)&qkv[((size_t)vj * 4 + b) * 3072 + 2048 + h * 64 + vd0];
#pragma unroll
    for (int q = 0; q < 8; ++q) sVt[(vd0 + q) * 40 + vj] = v8[q];
  }
  // K fragments tile 0 (per-lane, direct from global)
  short8 rKf[4];
#pragma unroll
  for (int n0i = 0; n0i < 2; ++n0i) {
    const size_t kro = ((size_t)(n0i * 16 + m16) * 4 + b) * 3072 + 1024 + h * 64 + quad * 8;
    rKf[n0i * 2] = *(const short8*)&qkv[kro];
    rKf[n0i * 2 + 1] = *(const short8*)&qkv[kro + 32];
  }

  short8 ones;
#pragma unroll
  for (int q = 0; q < 8; ++q) ones[q] = (short)0x3F80;  // bf16 1.0

  f32x4 O[4] = {};
  f32x4 L = {};
  float m = -1e30f;
  int bk = 0;               // (32*kt) % 96: ring base; also write slot base
  int tnext = 1056 - i0;    // t-base of chunk staged for tile kt+1

  const int n_kt = ((i0 + 575) >> 5) + 1;  // valid j <= i+512, i <= i0+63
  for (int kt = 0; kt < n_kt; ++kt) {
    const int j0 = kt * 32;
    const bool pf = (kt + 1 < n_kt);
    __syncthreads();  // staged LDS writes visible

    // prefetch next tile: V + new R chunk into regs (latency hidden)
    short8 nV, nR;
    if (pf) {
      nV = *(const short8*)&qkv[((size_t)(j0 + 32 + vj) * 4 + b) * 3072 + 2048 + h * 64 + vd0];
      int t = tnext + st_row;
      t = t > 1535 ? 1535 : t;
      nR = *(const short8*)&rh[(size_t)t * 1024 + h * 64 + st_d0];
    }

    // AC tiles from register K fragments
    f32x4 ac[2];
#pragma unroll
    for (int n0i = 0; n0i < 2; ++n0i) {
      f32x4 a = {};
      a = __builtin_amdgcn_mfma_f32_16x16x32_bf16(aQu0, rKf[n0i * 2], a, 0, 0, 0);
      a = __builtin_amdgcn_mfma_f32_16x16x32_bf16(aQu1, rKf[n0i * 2 + 1], a, 0, 0, 0);
      ac[n0i] = a;
    }
    // prefetch next K fragments (regs free after AC)
    if (pf) {
#pragma unroll
      for (int n0i = 0; n0i < 2; ++n0i) {
        const size_t kro = ((size_t)(j0 + 32 + n0i * 16 + m16) * 4 + b) * 3072 + 1024 + h * 64 + quad * 8;
        rKf[n0i * 2] = *(const short8*)&qkv[kro];
        rKf[n0i * 2 + 1] = *(const short8*)&qkv[kro + 32];
      }
    }

    // P = Qv.R tiles (ring rows), wave trel window [48-16w, 94-16w]
    f32x4 pb[3];
#pragma unroll
    for (int pt = 0; pt < 3; ++pt) {
      const int p0 = 48 - 16 * w + 16 * pt;
      int pr = bk + p0;
      if (pr >= 96) pr -= 96;
      int row = pr + m16;
      if (row >= 96) row -= 96;
      const short8 bR0 = *(const short8*)&sR[row * 72 + quad * 8];
      const short8 bR1 = *(const short8*)&sR[row * 72 + 32 + quad * 8];
      f32x4 pf_ = {};
      pf_ = __builtin_amdgcn_mfma_f32_16x16x32_bf16(aQv0, bR0, pf_, 0, 0, 0);
      pf_ = __builtin_amdgcn_mfma_f32_16x16x32_bf16(aQv1, bR1, pf_, 0, 0, 0);
      pb[pt] = pf_;
    }

    // Scores; rel-shift P gather via in-wave shuffles (same quad, same rg)
    float S0[4], S1[4];
    float mxl = -1e30f;
#pragma unroll
    for (int rg = 0; rg < 4; ++rg) {
      const int rloc = quad * 4 + rg;
      const int irow = i0 + w * 16 + rloc;
      const int c0 = m16 - rloc + 15;  // in [0,30]
      const int src = (lane & 48) | (c0 & 15);
      const float t0 = __shfl(pb[0][rg], src);
      const float t1 = __shfl(pb[1][rg], src);
      const float t2 = __shfl(pb[2][rg], src);
      const float p0v = (c0 < 16) ? t0 : t1;
      const float p1v = (c0 < 16) ? t1 : t2;
      float s0 = (ac[0][rg] + p0v) * 0.125f;
      float s1 = (ac[1][rg] + p1v) * 0.125f;
      if (j0 + m16 > irow + 512) s0 = -1e30f;
      if (j0 + 16 + m16 > irow + 512) s1 = -1e30f;
      S0[rg] = s0;
      S1[rg] = s1;
      mxl = fmaxf(mxl, fmaxf(s0, s1));
    }
    // wave-shared max (valid upper bound for all 16 rows of this wave)
    mxl = fmaxf(mxl, __shfl_xor(mxl, 1));
    mxl = fmaxf(mxl, __shfl_xor(mxl, 2));
    mxl = fmaxf(mxl, __shfl_xor(mxl, 4));
    mxl = fmaxf(mxl, __shfl_xor(mxl, 8));
    mxl = fmaxf(mxl, __shfl_xor(mxl, 16));
    mxl = fmaxf(mxl, __shfl_xor(mxl, 32));
    const float mnew = fmaxf(m, mxl);
    const float al = __expf(m - mnew);
    m = mnew;
#pragma unroll
    for (int rg = 0; rg < 4; ++rg) {
      const int rloc = quad * 4 + rg;
      sProb[(w * 16 + rloc) * 40 + m16] = f2b(__expf(S0[rg] - mnew));
      sProb[(w * 16 + rloc) * 40 + 16 + m16] = f2b(__expf(S1[rg] - mnew));
    }
#pragma unroll
    for (int d0i = 0; d0i < 4; ++d0i)
#pragma unroll
      for (int rg = 0; rg < 4; ++rg) O[d0i][rg] *= al;
#pragma unroll
    for (int rg = 0; rg < 4; ++rg) L[rg] *= al;

    // PV + row-sum accumulation (ones B-fragment broadcasts l to all cols)
    const short8 aP = *(const short8*)&sProb[(w * 16 + m16) * 40 + quad * 8];
    L = __builtin_amdgcn_mfma_f32_16x16x32_bf16(aP, ones, L, 0, 0, 0);
#pragma unroll
    for (int d0i = 0; d0i < 4; ++d0i) {
      const short8 bV = *(const short8*)&sVt[(d0i * 16 + m16) * 40 + quad * 8];
      O[d0i] = __builtin_amdgcn_mfma_f32_16x16x32_bf16(aP, bV, O[d0i], 0, 0, 0);
    }

    __syncthreads();  // all LDS reads done before restage
    if (pf) {
#pragma unroll
      for (int q = 0; q < 8; ++q) sVt[(vd0 + q) * 40 + vj] = nV[q];
      *(short8*)&sR[(bk + st_row) * 72 + st_d0] = nR;  // new chunk slot
    }
    bk += 32;
    if (bk >= 96) bk = 0;
    tnext += 32;
  }

  // Epilogue: ctxh[i*B+b][h*64+d] = (f16)(O/L)
#pragma unroll
  for (int d0i = 0; d0i < 4; ++d0i) {
#pragma unroll
    for (int rg = 0; rg < 4; ++rg) {
      const int irow = i0 + w * 16 + quad * 4 + rg;
      ctxh[((size_t)irow * 4 + b) * 1024 + h * 64 + d0i * 16 + m16] =
          (f16)(O[d0i][rg] / L[rg]);
    }
  }
}

// ---------------- LayerNorms ----------------
// ln1: x = LN(ya + yb + inputs); emits f16 x_h only.
__global__ __launch_bounds__(256) void ln1_kernel(
    const f16* __restrict__ ya, const f16* __restrict__ yb,
    const float* __restrict__ inp, const float* __restrict__ g,
    const float* __restrict__ beta, f16* __restrict__ xh) {
  const int r = blockIdx.x, tid = threadIdx.x;
  __shared__ float red[256];
  float t[4];
  float s = 0.f;
#pragma unroll
  for (int q = 0; q < 4; ++q) {
    int c = tid + q * 256;
    t[q] = (float)ya[(size_t)r * DM + c] + (float)yb[(size_t)r * DM + c] +
           inp[(size_t)r * DM + c];
    s += t[q];
  }
  red[tid] = s;
  __syncthreads();
  for (int st = 128; st > 0; st >>= 1) {
    if (tid < st) red[tid] += red[tid + st];
    __syncthreads();
  }
  const float mean = red[0] * (1.f / DM);
  __syncthreads();
  float vs = 0.f;
#pragma unroll
  for (int q = 0; q < 4; ++q) {
    float d0 = t[q] - mean;
    vs += d0 * d0;
  }
  red[tid] = vs;
  __syncthreads();
  for (int st = 128; st > 0; st >>= 1) {
    if (tid < st) red[tid] += red[tid + st];
    __syncthreads();
  }
  const float rstd = rsqrtf(red[0] * (1.f / DM) + 1e-5f);
#pragma unroll
  for (int q = 0; q < 4; ++q) {
    int c = tid + q * 256;
    const float val = (t[q] - mean) * rstd * g[c] + beta[c];
    xh[(size_t)r * DM + c] = (f16)val;
  }
}

// ln2: out = LN(x_h + y2a + y2b + b2), fp32 out.
__global__ __launch_bounds__(256) void ln2_kernel(
    const f16* __restrict__ xh, const f16* __restrict__ y2a,
    const f16* __restrict__ y2b, const float* __restrict__ b2,
    const float* __restrict__ g, const float* __restrict__ beta,
    float* __restrict__ out) {
  const int r = blockIdx.x, tid = threadIdx.x;
  __shared__ float red[256];
  float t[4];
  float s = 0.f;
#pragma unroll
  for (int q = 0; q < 4; ++q) {
    int c = tid + q * 256;
    t[q] = (float)xh[(size_t)r * DM + c] + (float)y2a[(size_t)r * DM + c] +
           (float)y2b[(size_t)r * DM + c] + b2[c];
    s += t[q];
  }
  red[tid] = s;
  __syncthreads();
  for (int st = 128; st > 0; st >>= 1) {
    if (tid < st) red[tid] += red[tid + st];
    __syncthreads();
  }
  const float mean = red[0] * (1.f / DM);
  __syncthreads();
  float vs = 0.f;
#pragma unroll
  for (int q = 0; q < 4; ++q) {
    float d0 = t[q] - mean;
    vs += d0 * d0;
  }
  red[tid] = vs;
  __syncthreads();
  for (int st = 128; st > 0; st >>= 1) {
    if (tid < st) red[tid] += red[tid + st];
    __syncthreads();
  }
  const float rstd = rsqrtf(red[0] * (1.f / DM) + 1e-5f);
#pragma unroll
  for (int q = 0; q < 4; ++q) {
    int c = tid + q * 256;
    out[(size_t)r * DM + c] = (t[q] - mean) * rstd * g[c] + beta[c];
  }
}

extern "C" void kernel_launch(void* const* d_in, const int* in_sizes, int n_in,
                              void* d_out, int out_size, void* d_ws, size_t ws_size,
                              hipStream_t stream) {
  const int o = (n_in >= 17) ? 1 : 0;
  const float* inputs = (const float*)d_in[0];
  const float* r      = (const float*)d_in[1];
  const float* u      = (const float*)d_in[2];
  const float* v      = (const float*)d_in[3];
  const float* memp   = (const float*)d_in[4];
  const float* W_qkv  = (const float*)d_in[5 + o];
  const float* W_r    = (const float*)d_in[6 + o];
  const float* W_o    = (const float*)d_in[7 + o];
  const float* ln1_g  = (const float*)d_in[8 + o];
  const float* ln1_b  = (const float*)d_in[9 + o];
  const float* ln2_g  = (const float*)d_in[10 + o];
  const float* ln2_b  = (const float*)d_in[11 + o];
  const float* W1     = (const float*)d_in[12 + o];
  const float* b1     = (const float*)d_in[13 + o];
  const float* W2     = (const float*)d_in[14 + o];
  const float* b2     = (const float*)d_in[15 + o];

  // Workspace liveness plan (peak 52,428,800 B):
  // phase 1: WqkvT @0 (6.29M) | r16 @6291456 (3.15M) | WrT @9437184 (2.10M)
  //          qkv @11534336 (37.75M) | rh @49283072 (3.15M) | cat_h @d_out
  // phase 2 (after fattn, all phase-1 ws dead):
  //   ctx_h @0 (8.39M, f16, written by fattn)   dead after Wo
  //   WoT   @8388608  (2.10M)                   dead after Wo
  //   ya    @10485760 (8.39M f16)               dead after ln1
  //   yb    @18874368 (8.39M f16)               dead after ln1
  //   x_h   @27262976 (8.39M f16)               live till ln2
  //   W1T   @35651584 (8.39M)                   dead after MLP1 -> y2b reuse
  //   h_hi  @0        (16.78M, after ln1)       live till W2 done
  //   h_lo  @d_out    (16.78M)                  live till W2 done
  //   W2T   @44040192 (8.39M)
  //   y2a   @18874368 (over yb) | y2b @35651584 (over W1T)
  char* ws = (char*)d_ws;
  f16*  WqkvT = (f16*)(ws);
  f16*  r16   = (f16*)(ws + 6291456);
  f16*  WrT   = (f16*)(ws + 9437184);
  bf16* qkv   = (bf16*)(ws + 11534336);
  bf16* rh    = (bf16*)(ws + 49283072);
  f16*  cat_h = (f16*)d_out;
  f16*  ctx_h = (f16*)(ws);
  f16*  WoT   = (f16*)(ws + 8388608);
  f16*  ya    = (f16*)(ws + 10485760);
  f16*  yb    = (f16*)(ws + 18874368);
  f16*  x_h   = (f16*)(ws + 27262976);
  f16*  W1T   = (f16*)(ws + 35651584);
  f16*  h_hi  = (f16*)(ws);
  f16*  h_lo  = (f16*)d_out;
  f16*  W2T   = (f16*)(ws + 44040192);
  f16*  y2a   = (f16*)(ws + 18874368);
  f16*  y2b   = (f16*)(ws + 35651584);

  dim3 blk(256);
  const int BIG = 1 << 30;

  // --- phase 1: QKV / R projections + attention ---
  convh_kernel<<<dim3(2048), blk, 0, stream>>>(memp, cat_h, 524288);
  convh_kernel<<<dim3(4096), blk, 0, stream>>>(inputs, cat_h + (size_t)2048 * 1024, 1048576);
  convh_kernel<<<dim3(1536), blk, 0, stream>>>(r, r16, 393216);
  convT_kernel<<<dim3(48, 16), blk, 0, stream>>>(W_qkv, WqkvT, 1024, 3072);
  convT_kernel<<<dim3(16, 16), blk, 0, stream>>>(W_r, WrT, 1024, 1024);
  hgemm_kernel<bf16><<<dim3(24, 48), blk, 0, stream>>>(
      cat_h, WqkvT, qkv, 3072, 1024, nullptr, 0,
      nullptr, nullptr, BIG, nullptr, nullptr, 1);
  hgemm_kernel<bf16><<<dim3(8, 12), blk, 0, stream>>>(
      r16, WrT, rh, 1024, 1024, nullptr, 0,
      nullptr, nullptr, BIG, nullptr, nullptr, 1);
  fattn_kernel<<<dim3(1024), blk, 0, stream>>>(qkv, rh, u, v, ctx_h);

  // --- phase 2: output proj (split-K) + LN1 + MLP + LN2 ---
  convT_kernel<<<dim3(16, 16), blk, 0, stream>>>(W_o, WoT, 1024, 1024);
  hgemm_kernel<f16><<<dim3(8, 64), blk, 0, stream>>>(
      ctx_h, WoT, ya, 1024, 1024, nullptr, 0,
      nullptr, nullptr, BIG, yb, nullptr, 2);
  ln1_kernel<<<dim3(4096), blk, 0, stream>>>(ya, yb, inputs, ln1_g, ln1_b, x_h);
  convT_kernel<<<dim3(64, 16), blk, 0, stream>>>(W1, W1T, 1024, 4096);
  hgemm_kernel<f16><<<dim3(32, 32), blk, 0, stream>>>(
      x_h, W1T, h_lo, 4096, 1024, b1, 1,
      x_h + (size_t)2048 * 1024, h_hi, 2048, nullptr, nullptr, 1);
  convT_kernel<<<dim3(16, 64), blk, 0, stream>>>(W2, W2T, 4096, 1024);
  hgemm_kernel<f16><<<dim3(8, 64), blk, 0, stream>>>(
      h_lo, W2T, y2a, 1024, 4096, nullptr, 0,
      h_hi, y2a + (size_t)2048 * 1024, 2048,
      y2b, y2b + (size_t)2048 * 1024, 2);
  ln2_kernel<<<dim3(4096), blk, 0, stream>>>(x_h, y2a, y2b, b2, ln2_g, ln2_b,
                                             (float*)d_out);
}

// Round 6
// 478.309 us; speedup vs baseline: 4.0925x; 1.0106x over previous
//
#include <hip/hip_runtime.h>
#include <hip/hip_bf16.h>

typedef __hip_bfloat16 bf16;
typedef _Float16 f16;
typedef __attribute__((ext_vector_type(8))) short short8;
typedef __attribute__((ext_vector_type(4))) float f32x4;
typedef __attribute__((ext_vector_type(8))) _Float16 f16x8;
typedef __attribute__((ext_vector_type(4))) _Float16 f16x4;

#define Q_LEN 1024
#define B_SZ 4
#define DM 1024
#define H_CNT 16
#define HD 64
#define MEM_LEN 512
#define KLEN 1536
#define MLP 4096

__device__ __forceinline__ void store_c(float* p, float v) { *p = v; }
__device__ __forceinline__ void store_c(bf16* p, float v) { *p = __float2bfloat16(v); }
__device__ __forceinline__ void store_c(f16* p, float v) { *p = (f16)v; }

__device__ __forceinline__ float b2f(short s) {
  union { unsigned u; float f; } x;
  x.u = ((unsigned)(unsigned short)s) << 16;
  return x.f;
}
__device__ __forceinline__ short f2b(float f) {
  union { float f; unsigned u; } x;
  x.f = f;
  unsigned r = x.u + 0x7fff + ((x.u >> 16) & 1);  // RNE; inputs finite
  return (short)(r >> 16);
}

// async global->LDS, 16B per lane; LDS dest = wave-uniform base + lane*16
__device__ __forceinline__ void gload16(const void* g, void* l) {
  __builtin_amdgcn_global_load_lds(
      (__attribute__((address_space(1))) unsigned int*)(g),
      (__attribute__((address_space(3))) unsigned int*)(l), 16, 0, 0);
}

// ---------------- fp32 -> fp16 elementwise convert ----------------
__global__ __launch_bounds__(256) void convh_kernel(
    const float* __restrict__ X, f16* __restrict__ Y, int n4) {
  const int i = blockIdx.x * 256 + threadIdx.x;
  if (i < n4) {
    f32x4 v = *(const f32x4*)&X[(size_t)i * 4];
    f16x4 h;
#pragma unroll
    for (int j = 0; j < 4; ++j) h[j] = (f16)v[j];
    *(f16x4*)&Y[(size_t)i * 4] = h;
  }
}

// ---------------- fp32 [K][N] -> fp16 transposed [N][K] ----------------
__global__ __launch_bounds__(256) void convT_kernel(
    const float* __restrict__ W, f16* __restrict__ WT, int K, int N) {
  __shared__ float tile[64][65];
  const int tid = threadIdx.x;
  const int k0 = blockIdx.y * 64, n0 = blockIdx.x * 64;
  const int tn = tid & 63, tk4 = tid >> 6;
#pragma unroll
  for (int p = 0; p < 16; ++p) {
    const int kk = tk4 + p * 4;
    tile[kk][tn] = W[(size_t)(k0 + kk) * N + n0 + tn];
  }
  __syncthreads();
#pragma unroll
  for (int p = 0; p < 16; ++p) {
    const int nn = tk4 + p * 4;
    WT[(size_t)(n0 + nn) * K + k0 + tn] = (f16)tile[tn][nn];
  }
}

// ---------------- fp16 MFMA GEMM: C = A[M,K] * BT[N,K]^T ----------------
// R6: 2-buffer LDS (32KB) + __launch_bounds__(256,4): 4 blocks/CU
// (16 waves) for latency hiding; depth-1 prefetch, stage issued right
// after the barrier, vmcnt(0) one full k-step after issue. Split-K and
// XCD swizzle kept from R5.
template <typename TC>
__global__ __launch_bounds__(256, 4) void hgemm_kernel(
    const f16* __restrict__ A, const f16* __restrict__ BT, TC* C,
    int N, int K, const float* __restrict__ bias, int relu,
    const f16* __restrict__ Aalt, TC* Calt, int split,
    TC* Cb, TC* Cbalt, int ksplit) {
  __shared__ __align__(16) f16 sA[2][128 * 32];
  __shared__ __align__(16) f16 sB[2][128 * 32];
  const int tid = threadIdx.x;
  const int w = tid >> 6, lane = tid & 63;
  const int quad = lane >> 4, m16 = lane & 15;
  const int wr = w >> 1, wc = w & 1;
  // XCD-aware swizzle: all our grids have nwg % 8 == 0 (bijective).
  const int gx = gridDim.x;
  const int nwg = gx * gridDim.y;
  const int lin = blockIdx.y * gx + blockIdx.x;
  const int cpx = nwg >> 3;
  const int swz = (lin & 7) * cpx + (lin >> 3);
  const int bx = swz % gx;
  int by = swz / gx;
  int koff = 0, Kloc = K;
  if (ksplit == 2) {
    const int mh = gridDim.y >> 1;
    if (by >= mh) { by -= mh; koff = K >> 1; C = Cb; Calt = Cbalt; }
    Kloc = K >> 1;
  }
  const int col0 = bx * 128;
  int r0 = by * 128;
  const f16* Ause = A;
  TC* Cuse = C;
  if (r0 >= split) { Ause = Aalt; Cuse = Calt; r0 -= split; }

  // staging: thread t covers LDS row (t>>2) (+64 for 2nd call), chunk t&3;
  // fetches global chunk (t&3) ^ ((row>>1)&3) (pre-swizzled source)
  const int strow = tid >> 2;
  const int schunk = tid & 3;
  const int sw = schunk ^ ((strow >> 1) & 3);
  const f16* gA0 = Ause + (size_t)(r0 + strow) * K + koff + sw * 8;
  const f16* gB0 = BT + (size_t)(col0 + strow) * K + koff + sw * 8;
  f16* ldsA0 = &sA[0][0] + (size_t)w * 512;
  f16* ldsB0 = &sB[0][0] + (size_t)w * 512;

  // ds_read offsets (f16 elems): row rt, swizzled chunk quad^((rt>>1)&3)
  const int qs = quad ^ ((m16 >> 1) & 3);
  int aoff[4], boff[4];
#pragma unroll
  for (int i = 0; i < 4; ++i) {
    aoff[i] = (wr * 64 + i * 16 + m16) * 32 + qs * 8;
    boff[i] = (wc * 64 + i * 16 + m16) * 32 + qs * 8;
  }

  const int nkt = Kloc >> 5;  // >= 16 in all our launches
  f32x4 acc[4][4] = {};

  auto stage = [&](int buf, int t) {
    const int k0 = t << 5;
    const size_t bufo = (size_t)buf * 4096;
    gload16(gA0 + k0, ldsA0 + bufo);
    gload16(gA0 + (size_t)64 * K + k0, ldsA0 + bufo + 2048);
    gload16(gB0 + k0, ldsB0 + bufo);
    gload16(gB0 + (size_t)64 * K + k0, ldsB0 + bufo + 2048);
  };

  stage(0, 0);
  int cur = 0;
  for (int t = 0; t < nkt; ++t) {
    // own 4 loads for tile t (issued one full k-step ago) landed
    asm volatile("s_waitcnt vmcnt(0)" ::: "memory");
    __builtin_amdgcn_s_barrier();  // all waves' tile-t loads visible
    if (t + 1 < nkt) stage(cur ^ 1, t + 1);  // buf read at t-1; all past it
    f16x8 af[4], bfr[4];
#pragma unroll
    for (int i = 0; i < 4; ++i) af[i] = *(const f16x8*)&sA[cur][aoff[i]];
#pragma unroll
    for (int i = 0; i < 4; ++i) bfr[i] = *(const f16x8*)&sB[cur][boff[i]];
    __builtin_amdgcn_s_setprio(1);
#pragma unroll
    for (int mi = 0; mi < 4; ++mi)
#pragma unroll
      for (int ni = 0; ni < 4; ++ni)
        acc[mi][ni] = __builtin_amdgcn_mfma_f32_16x16x32_f16(
            af[mi], bfr[ni], acc[mi][ni], 0, 0, 0);
    __builtin_amdgcn_s_setprio(0);
    cur ^= 1;
  }

  // Epilogue: D layout col=lane&15, row=quad*4+rg (16x16 family)
#pragma unroll
  for (int mi = 0; mi < 4; ++mi) {
    const int row = r0 + wr * 64 + mi * 16 + quad * 4;
#pragma unroll
    for (int ni = 0; ni < 4; ++ni) {
      const int col = col0 + wc * 64 + ni * 16 + m16;
      const float bv = bias ? bias[col] : 0.f;
#pragma unroll
      for (int rg = 0; rg < 4; ++rg) {
        float vv = acc[mi][ni][rg] + bv;
        if (relu) vv = vv > 0.f ? vv : 0.f;
        store_c(&Cuse[(size_t)(row + rg) * N + col], vv);
      }
    }
  }
}

// ---------------- Fused flash-MFMA attention ----------------
// R6 vs R5: SINGLE barrier per iteration. sProb is wave-private (no
// barrier ever needed). R becomes a 128-row ring: write slot (bk+96)
// is disjoint from the read window [bk, bk+95]. V double-buffered.
// Also: defer-max (T13, skip rescale when mxl <= m+8; wave-uniform) and
// wave-uniform mask-skip branch (only the last tiles need masking).
__global__ __launch_bounds__(256, 4) void fattn_kernel(
    const bf16* __restrict__ qkvp,  // [1536*4, 3072] rows k*B+b, bf16
    const bf16* __restrict__ rhp,   // [1536, 1024] bf16
    const float* __restrict__ u, const float* __restrict__ v,
    f16* __restrict__ ctxh) {       // [4096, 1024] f16
  const int lin = blockIdx.x;      // 1024 blocks
  const int p = lin & 63;          // (b,h) pair; p%8 = XCD
  const int b = p & 3, h = p >> 2;
  const int i0 = (15 - (lin >> 6)) * 64;  // heavy tiles first
  const int tid = threadIdx.x;
  const int w = tid >> 6, lane = tid & 63;
  const int quad = lane >> 4, m16 = lane & 15;

  __shared__ short sVt[2][64 * 40]; // V^T tiles (double-buffered): [d][j]
  __shared__ short sR[128 * 72];    // R ring: phys = (32kt+trel)&127
  __shared__ short sProb[64 * 40];  // probs bf16 (wave-private strips)

  const short* qkv = (const short*)qkvp;
  const short* rh  = (const short*)rhp;

  // Per-lane Q fragments: aQu = q+u (AC), aQv = q+v (BD). Rows w*16+m16.
  short8 aQu0, aQu1, aQv0, aQv1;
  {
    const size_t qro = ((size_t)(512 + i0 + w * 16 + m16) * 4 + b) * 3072 + h * 64 + quad * 8;
    short8 qa = *(const short8*)&qkv[qro];
    short8 qb = *(const short8*)&qkv[qro + 32];
    const float* up = u + h * 64 + quad * 8;
    const float* vp = v + h * 64 + quad * 8;
#pragma unroll
    for (int j = 0; j < 8; ++j) {
      const float qaf = b2f(qa[j]), qbf = b2f(qb[j]);
      aQu0[j] = f2b(qaf + up[j]);
      aQu1[j] = f2b(qbf + up[j + 32]);
      aQv0[j] = f2b(qaf + vp[j]);
      aQv1[j] = f2b(qbf + vp[j + 32]);
    }
  }

  // staging maps
  const int st_row = tid >> 3, st_d0 = (tid & 7) * 8;        // R chunk (32 rows)
  const int vj = lane & 31, vd0 = w * 16 + (lane >> 5) * 8;  // V^T scatter

  // Initial R window fill: trel 0..95 -> phys 0..95, t = 960-i0+trel
#pragma unroll
  for (int p_ = 0; p_ < 3; ++p_) {
    int t = 960 - i0 + p_ * 32 + st_row;
    t = t > 1535 ? 1535 : t;  // clamped rows only feed masked elems
    *(short8*)&sR[(p_ * 32 + st_row) * 72 + st_d0] =
        *(const short8*)&rh[(size_t)t * 1024 + h * 64 + st_d0];
  }
  // V tile 0 scatter -> buf 0
  {
    short8 v8 = *(const short8*)&qkv[((size_t)vj * 4 + b) * 3072 + 2048 + h * 64 + vd0];
#pragma unroll
    for (int q = 0; q < 8; ++q) sVt[0][(vd0 + q) * 40 + vj] = v8[q];
  }
  // K fragments tile 0 (per-lane, direct from global)
  short8 rKf[4];
#pragma unroll
  for (int n0i = 0; n0i < 2; ++n0i) {
    const size_t kro = ((size_t)(n0i * 16 + m16) * 4 + b) * 3072 + 1024 + h * 64 + quad * 8;
    rKf[n0i * 2] = *(const short8*)&qkv[kro];
    rKf[n0i * 2 + 1] = *(const short8*)&qkv[kro + 32];
  }

  short8 ones;
#pragma unroll
  for (int q = 0; q < 8; ++q) ones[q] = (short)0x3F80;  // bf16 1.0

  f32x4 O[4] = {};
  f32x4 L = {};
  float m = -1e30f;
  int bk = 0;               // (32*kt) & 127: ring base
  int tnext = 1056 - i0;    // t-base of chunk staged for tile kt+1

  const int n_kt = ((i0 + 575) >> 5) + 1;  // valid j <= i+512, i <= i0+63
  for (int kt = 0; kt < n_kt; ++kt) {
    const int j0 = kt * 32;
    const bool pf = (kt + 1 < n_kt);
    const int vbuf = kt & 1;
    __syncthreads();  // staged V/R writes from prev iter visible

    // prefetch next tile: V + new R chunk into regs (latency hidden)
    short8 nV, nR;
    if (pf) {
      nV = *(const short8*)&qkv[((size_t)(j0 + 32 + vj) * 4 + b) * 3072 + 2048 + h * 64 + vd0];
      int t = tnext + st_row;
      t = t > 1535 ? 1535 : t;
      nR = *(const short8*)&rh[(size_t)t * 1024 + h * 64 + st_d0];
    }

    // AC tiles from register K fragments
    f32x4 ac[2];
#pragma unroll
    for (int n0i = 0; n0i < 2; ++n0i) {
      f32x4 a = {};
      a = __builtin_amdgcn_mfma_f32_16x16x32_bf16(aQu0, rKf[n0i * 2], a, 0, 0, 0);
      a = __builtin_amdgcn_mfma_f32_16x16x32_bf16(aQu1, rKf[n0i * 2 + 1], a, 0, 0, 0);
      ac[n0i] = a;
    }
    // prefetch next K fragments (regs free after AC)
    if (pf) {
#pragma unroll
      for (int n0i = 0; n0i < 2; ++n0i) {
        const size_t kro = ((size_t)(j0 + 32 + n0i * 16 + m16) * 4 + b) * 3072 + 1024 + h * 64 + quad * 8;
        rKf[n0i * 2] = *(const short8*)&qkv[kro];
        rKf[n0i * 2 + 1] = *(const short8*)&qkv[kro + 32];
      }
    }

    // P = Qv.R tiles (ring rows), wave trel window [48-16w, 94-16w]
    f32x4 pb[3];
#pragma unroll
    for (int pt = 0; pt < 3; ++pt) {
      const int p0 = 48 - 16 * w + 16 * pt;
      const int row = (bk + p0 + m16) & 127;
      const short8 bR0 = *(const short8*)&sR[row * 72 + quad * 8];
      const short8 bR1 = *(const short8*)&sR[row * 72 + 32 + quad * 8];
      f32x4 pf_ = {};
      pf_ = __builtin_amdgcn_mfma_f32_16x16x32_bf16(aQv0, bR0, pf_, 0, 0, 0);
      pf_ = __builtin_amdgcn_mfma_f32_16x16x32_bf16(aQv1, bR1, pf_, 0, 0, 0);
      pb[pt] = pf_;
    }

    // Scores; rel-shift P gather via in-wave shuffles (same quad, same rg)
    const bool needmask = (j0 + 31 > i0 + w * 16 + 512);
    float S0[4], S1[4];
    float mxl = -1e30f;
#pragma unroll
    for (int rg = 0; rg < 4; ++rg) {
      const int rloc = quad * 4 + rg;
      const int c0 = m16 - rloc + 15;  // in [0,30]
      const int src = (lane & 48) | (c0 & 15);
      const float t0 = __shfl(pb[0][rg], src);
      const float t1 = __shfl(pb[1][rg], src);
      const float t2 = __shfl(pb[2][rg], src);
      const float p0v = (c0 < 16) ? t0 : t1;
      const float p1v = (c0 < 16) ? t1 : t2;
      float s0 = (ac[0][rg] + p0v) * 0.125f;
      float s1 = (ac[1][rg] + p1v) * 0.125f;
      if (needmask) {
        const int irow = i0 + w * 16 + rloc;
        if (j0 + m16 > irow + 512) s0 = -1e30f;
        if (j0 + 16 + m16 > irow + 512) s1 = -1e30f;
      }
      S0[rg] = s0;
      S1[rg] = s1;
      mxl = fmaxf(mxl, fmaxf(s0, s1));
    }
    // wave-shared max (valid upper bound for all 16 rows of this wave)
    mxl = fmaxf(mxl, __shfl_xor(mxl, 1));
    mxl = fmaxf(mxl, __shfl_xor(mxl, 2));
    mxl = fmaxf(mxl, __shfl_xor(mxl, 4));
    mxl = fmaxf(mxl, __shfl_xor(mxl, 8));
    mxl = fmaxf(mxl, __shfl_xor(mxl, 16));
    mxl = fmaxf(mxl, __shfl_xor(mxl, 32));
    // defer-max: only rescale when the max actually grew materially
    if (mxl > m + 8.f) {
      const float al = __expf(m - mxl);
      m = mxl;
#pragma unroll
      for (int d0i = 0; d0i < 4; ++d0i)
#pragma unroll
        for (int rg = 0; rg < 4; ++rg) O[d0i][rg] *= al;
#pragma unroll
      for (int rg = 0; rg < 4; ++rg) L[rg] *= al;
    }
#pragma unroll
    for (int rg = 0; rg < 4; ++rg) {
      const int rloc = quad * 4 + rg;
      sProb[(w * 16 + rloc) * 40 + m16] = f2b(__expf(S0[rg] - m));
      sProb[(w * 16 + rloc) * 40 + 16 + m16] = f2b(__expf(S1[rg] - m));
    }

    // PV + row-sum accumulation (ones B-fragment broadcasts l to all cols)
    const short8 aP = *(const short8*)&sProb[(w * 16 + m16) * 40 + quad * 8];
    L = __builtin_amdgcn_mfma_f32_16x16x32_bf16(aP, ones, L, 0, 0, 0);
#pragma unroll
    for (int d0i = 0; d0i < 4; ++d0i) {
      const short8 bV = *(const short8*)&sVt[vbuf][(d0i * 16 + m16) * 40 + quad * 8];
      O[d0i] = __builtin_amdgcn_mfma_f32_16x16x32_bf16(aP, bV, O[d0i], 0, 0, 0);
    }

    // restage into disjoint slots: V -> other buffer, R -> ring rows
    // [bk+96, bk+127] (not in this iter's read window [bk, bk+95]).
    if (pf) {
#pragma unroll
      for (int q = 0; q < 8; ++q) sVt[vbuf ^ 1][(vd0 + q) * 40 + vj] = nV[q];
      *(short8*)&sR[(((bk + 96) & 127) + st_row) * 72 + st_d0] = nR;
    }
    bk = (bk + 32) & 127;
    tnext += 32;
  }

  // Epilogue: ctxh[i*B+b][h*64+d] = (f16)(O/L)
#pragma unroll
  for (int d0i = 0; d0i < 4; ++d0i) {
#pragma unroll
    for (int rg = 0; rg < 4; ++rg) {
      const int irow = i0 + w * 16 + quad * 4 + rg;
      ctxh[((size_t)irow * 4 + b) * 1024 + h * 64 + d0i * 16 + m16] =
          (f16)(O[d0i][rg] / L[rg]);
    }
  }
}

// ---------------- LayerNorms ----------------
// ln1: x = LN(ya + yb + inputs); emits f16 x_h only.
__global__ __launch_bounds__(256) void ln1_kernel(
    const f16* __restrict__ ya, const f16* __restrict__ yb,
    const float* __restrict__ inp, const float* __restrict__ g,
    const float* __restrict__ beta, f16* __restrict__ xh) {
  const int r = blockIdx.x, tid = threadIdx.x;
  __shared__ float red[256];
  float t[4];
  float s = 0.f;
#pragma unroll
  for (int q = 0; q < 4; ++q) {
    int c = tid + q * 256;
    t[q] = (float)ya[(size_t)r * DM + c] + (float)yb[(size_t)r * DM + c] +
           inp[(size_t)r * DM + c];
    s += t[q];
  }
  red[tid] = s;
  __syncthreads();
  for (int st = 128; st > 0; st >>= 1) {
    if (tid < st) red[tid] += red[tid + st];
    __syncthreads();
  }
  const float mean = red[0] * (1.f / DM);
  __syncthreads();
  float vs = 0.f;
#pragma unroll
  for (int q = 0; q < 4; ++q) {
    float d0 = t[q] - mean;
    vs += d0 * d0;
  }
  red[tid] = vs;
  __syncthreads();
  for (int st = 128; st > 0; st >>= 1) {
    if (tid < st) red[tid] += red[tid + st];
    __syncthreads();
  }
  const float rstd = rsqrtf(red[0] * (1.f / DM) + 1e-5f);
#pragma unroll
  for (int q = 0; q < 4; ++q) {
    int c = tid + q * 256;
    const float val = (t[q] - mean) * rstd * g[c] + beta[c];
    xh[(size_t)r * DM + c] = (f16)val;
  }
}

// ln2: out = LN(x_h + y2a + y2b + b2), fp32 out.
__global__ __launch_bounds__(256) void ln2_kernel(
    const f16* __restrict__ xh, const f16* __restrict__ y2a,
    const f16* __restrict__ y2b, const float* __restrict__ b2,
    const float* __restrict__ g, const float* __restrict__ beta,
    float* __restrict__ out) {
  const int r = blockIdx.x, tid = threadIdx.x;
  __shared__ float red[256];
  float t[4];
  float s = 0.f;
#pragma unroll
  for (int q = 0; q < 4; ++q) {
    int c = tid + q * 256;
    t[q] = (float)xh[(size_t)r * DM + c] + (float)y2a[(size_t)r * DM + c] +
           (float)y2b[(size_t)r * DM + c] + b2[c];
    s += t[q];
  }
  red[tid] = s;
  __syncthreads();
  for (int st = 128; st > 0; st >>= 1) {
    if (tid < st) red[tid] += red[tid + st];
    __syncthreads();
  }
  const float mean = red[0] * (1.f / DM);
  __syncthreads();
  float vs = 0.f;
#pragma unroll
  for (int q = 0; q < 4; ++q) {
    float d0 = t[q] - mean;
    vs += d0 * d0;
  }
  red[tid] = vs;
  __syncthreads();
  for (int st = 128; st > 0; st >>= 1) {
    if (tid < st) red[tid] += red[tid + st];
    __syncthreads();
  }
  const float rstd = rsqrtf(red[0] * (1.f / DM) + 1e-5f);
#pragma unroll
  for (int q = 0; q < 4; ++q) {
    int c = tid + q * 256;
    out[(size_t)r * DM + c] = (t[q] - mean) * rstd * g[c] + beta[c];
  }
}

extern "C" void kernel_launch(void* const* d_in, const int* in_sizes, int n_in,
                              void* d_out, int out_size, void* d_ws, size_t ws_size,
                              hipStream_t stream) {
  const int o = (n_in >= 17) ? 1 : 0;
  const float* inputs = (const float*)d_in[0];
  const float* r      = (const float*)d_in[1];
  const float* u      = (const float*)d_in[2];
  const float* v      = (const float*)d_in[3];
  const float* memp   = (const float*)d_in[4];
  const float* W_qkv  = (const float*)d_in[5 + o];
  const float* W_r    = (const float*)d_in[6 + o];
  const float* W_o    = (const float*)d_in[7 + o];
  const float* ln1_g  = (const float*)d_in[8 + o];
  const float* ln1_b  = (const float*)d_in[9 + o];
  const float* ln2_g  = (const float*)d_in[10 + o];
  const float* ln2_b  = (const float*)d_in[11 + o];
  const float* W1     = (const float*)d_in[12 + o];
  const float* b1     = (const float*)d_in[13 + o];
  const float* W2     = (const float*)d_in[14 + o];
  const float* b2     = (const float*)d_in[15 + o];

  // Workspace liveness plan (peak 52,428,800 B) — unchanged from R5
  char* ws = (char*)d_ws;
  f16*  WqkvT = (f16*)(ws);
  f16*  r16   = (f16*)(ws + 6291456);
  f16*  WrT   = (f16*)(ws + 9437184);
  bf16* qkv   = (bf16*)(ws + 11534336);
  bf16* rh    = (bf16*)(ws + 49283072);
  f16*  cat_h = (f16*)d_out;
  f16*  ctx_h = (f16*)(ws);
  f16*  WoT   = (f16*)(ws + 8388608);
  f16*  ya    = (f16*)(ws + 10485760);
  f16*  yb    = (f16*)(ws + 18874368);
  f16*  x_h   = (f16*)(ws + 27262976);
  f16*  W1T   = (f16*)(ws + 35651584);
  f16*  h_hi  = (f16*)(ws);
  f16*  h_lo  = (f16*)d_out;
  f16*  W2T   = (f16*)(ws + 44040192);
  f16*  y2a   = (f16*)(ws + 18874368);
  f16*  y2b   = (f16*)(ws + 35651584);

  dim3 blk(256);
  const int BIG = 1 << 30;

  // --- phase 1: QKV / R projections + attention ---
  convh_kernel<<<dim3(2048), blk, 0, stream>>>(memp, cat_h, 524288);
  convh_kernel<<<dim3(4096), blk, 0, stream>>>(inputs, cat_h + (size_t)2048 * 1024, 1048576);
  convh_kernel<<<dim3(1536), blk, 0, stream>>>(r, r16, 393216);
  convT_kernel<<<dim3(48, 16), blk, 0, stream>>>(W_qkv, WqkvT, 1024, 3072);
  convT_kernel<<<dim3(16, 16), blk, 0, stream>>>(W_r, WrT, 1024, 1024);
  hgemm_kernel<bf16><<<dim3(24, 48), blk, 0, stream>>>(
      cat_h, WqkvT, qkv, 3072, 1024, nullptr, 0,
      nullptr, nullptr, BIG, nullptr, nullptr, 1);
  hgemm_kernel<bf16><<<dim3(8, 12), blk, 0, stream>>>(
      r16, WrT, rh, 1024, 1024, nullptr, 0,
      nullptr, nullptr, BIG, nullptr, nullptr, 1);
  fattn_kernel<<<dim3(1024), blk, 0, stream>>>(qkv, rh, u, v, ctx_h);

  // --- phase 2: output proj (split-K) + LN1 + MLP + LN2 ---
  convT_kernel<<<dim3(16, 16), blk, 0, stream>>>(W_o, WoT, 1024, 1024);
  hgemm_kernel<f16><<<dim3(8, 64), blk, 0, stream>>>(
      ctx_h, WoT, ya, 1024, 1024, nullptr, 0,
      nullptr, nullptr, BIG, yb, nullptr, 2);
  ln1_kernel<<<dim3(4096), blk, 0, stream>>>(ya, yb, inputs, ln1_g, ln1_b, x_h);
  convT_kernel<<<dim3(64, 16), blk, 0, stream>>>(W1, W1T, 1024, 4096);
  hgemm_kernel<f16><<<dim3(32, 32), blk, 0, stream>>>(
      x_h, W1T, h_lo, 4096, 1024, b1, 1,
      x_h + (size_t)2048 * 1024, h_hi, 2048, nullptr, nullptr, 1);
  convT_kernel<<<dim3(16, 64), blk, 0, stream>>>(W2, W2T, 4096, 1024);
  hgemm_kernel<f16><<<dim3(8, 64), blk, 0, stream>>>(
      h_lo, W2T, y2a, 1024, 4096, nullptr, 0,
      h_hi, y2a + (size_t)2048 * 1024, 2048,
      y2b, y2b + (size_t)2048 * 1024, 2);
  ln2_kernel<<<dim3(4096), blk, 0, stream>>>(x_h, y2a, y2b, b2, ln2_g, ln2_b,
                                             (float*)d_out);
}

// Round 7
// 459.419 us; speedup vs baseline: 4.2607x; 1.0411x over previous
//
#include <hip/hip_runtime.h>
#include <hip/hip_bf16.h>

typedef __hip_bfloat16 bf16;
typedef _Float16 f16;
typedef __attribute__((ext_vector_type(8))) short short8;
typedef __attribute__((ext_vector_type(4))) float f32x4;
typedef __attribute__((ext_vector_type(8))) _Float16 f16x8;
typedef __attribute__((ext_vector_type(4))) _Float16 f16x4;

#define Q_LEN 1024
#define B_SZ 4
#define DM 1024
#define H_CNT 16
#define HD 64
#define MEM_LEN 512
#define KLEN 1536
#define MLP 4096

__device__ __forceinline__ void store_c(float* p, float v) { *p = v; }
__device__ __forceinline__ void store_c(bf16* p, float v) { *p = __float2bfloat16(v); }
__device__ __forceinline__ void store_c(f16* p, float v) { *p = (f16)v; }

__device__ __forceinline__ float b2f(short s) {
  union { unsigned u; float f; } x;
  x.u = ((unsigned)(unsigned short)s) << 16;
  return x.f;
}
__device__ __forceinline__ short f2b(float f) {
  union { float f; unsigned u; } x;
  x.f = f;
  unsigned r = x.u + 0x7fff + ((x.u >> 16) & 1);  // RNE; inputs finite
  return (short)(r >> 16);
}

// async global->LDS, 16B per lane; LDS dest = wave-uniform base + lane*16
__device__ __forceinline__ void gload16(const void* g, void* l) {
  __builtin_amdgcn_global_load_lds(
      (__attribute__((address_space(1))) unsigned int*)(g),
      (__attribute__((address_space(3))) unsigned int*)(l), 16, 0, 0);
}

// ------- merged fp32 -> fp16 convert: 3 segments in one launch -------
// seg0: blocks [0,2048)  : memp   -> Y0 (n4 = 524288, exact)
// seg1: [2048,6144)      : inputs -> Y1 (n4 = 1048576, exact)
// seg2: [6144,7680)      : r      -> Y2 (n4 = 393216, exact)
__global__ __launch_bounds__(256) void convh3_kernel(
    const float* __restrict__ X0, const float* __restrict__ X1,
    const float* __restrict__ X2, f16* __restrict__ Y0,
    f16* __restrict__ Y1, f16* __restrict__ Y2) {
  const int blk = blockIdx.x, tid = threadIdx.x;
  const float* X;
  f16* Y;
  int i;
  if (blk < 2048) { X = X0; Y = Y0; i = blk * 256 + tid; }
  else if (blk < 6144) { X = X1; Y = Y1; i = (blk - 2048) * 256 + tid; }
  else { X = X2; Y = Y2; i = (blk - 6144) * 256 + tid; }
  f32x4 v = *(const f32x4*)&X[(size_t)i * 4];
  f16x4 h;
#pragma unroll
  for (int j = 0; j < 4; ++j) h[j] = (f16)v[j];
  *(f16x4*)&Y[(size_t)i * 4] = h;
}

// ------- merged fp32 [K][N] -> fp16 [N][K] transpose: 3 descriptors -------
// blk < s1: desc0; blk < s2: desc1; else desc2. nx = N/64.
__global__ __launch_bounds__(256) void convTm_kernel(
    const float* W0, f16* T0, int K0, int N0, int nx0,
    int s1, const float* W1p, f16* T1, int K1, int N1, int nx1,
    int s2, const float* W2p, f16* T2, int K2, int N2, int nx2) {
  __shared__ float tile[64][65];
  const int blk = blockIdx.x, tid = threadIdx.x;
  const float* W;
  f16* WT;
  int K, N, nx, local;
  if (blk < s1) { W = W0; WT = T0; K = K0; N = N0; nx = nx0; local = blk; }
  else if (blk < s2) { W = W1p; WT = T1; K = K1; N = N1; nx = nx1; local = blk - s1; }
  else { W = W2p; WT = T2; K = K2; N = N2; nx = nx2; local = blk - s2; }
  const int n0 = (local % nx) * 64, k0 = (local / nx) * 64;
  const int tn = tid & 63, tk4 = tid >> 6;
#pragma unroll
  for (int p = 0; p < 16; ++p) {
    const int kk = tk4 + p * 4;
    tile[kk][tn] = W[(size_t)(k0 + kk) * N + n0 + tn];
  }
  __syncthreads();
#pragma unroll
  for (int p = 0; p < 16; ++p) {
    const int nn = tk4 + p * 4;
    WT[(size_t)(n0 + nn) * K + k0 + tn] = (f16)tile[tn][nn];
  }
}

// ---------------- fp16 MFMA GEMM: C = A[M,K] * BT[N,K]^T ----------------
// R6 structure (kept): 2-buffer LDS (32KB) + 4 blocks/CU; depth-1
// prefetch issued right after the barrier; split-K; XCD swizzle.
template <typename TC>
__global__ __launch_bounds__(256, 4) void hgemm_kernel(
    const f16* __restrict__ A, const f16* __restrict__ BT, TC* C,
    int N, int K, const float* __restrict__ bias, int relu,
    const f16* __restrict__ Aalt, TC* Calt, int split,
    TC* Cb, TC* Cbalt, int ksplit) {
  __shared__ __align__(16) f16 sA[2][128 * 32];
  __shared__ __align__(16) f16 sB[2][128 * 32];
  const int tid = threadIdx.x;
  const int w = tid >> 6, lane = tid & 63;
  const int quad = lane >> 4, m16 = lane & 15;
  const int wr = w >> 1, wc = w & 1;
  // XCD-aware swizzle: all our grids have nwg % 8 == 0 (bijective).
  const int gx = gridDim.x;
  const int nwg = gx * gridDim.y;
  const int lin = blockIdx.y * gx + blockIdx.x;
  const int cpx = nwg >> 3;
  const int swz = (lin & 7) * cpx + (lin >> 3);
  const int bx = swz % gx;
  int by = swz / gx;
  int koff = 0, Kloc = K;
  if (ksplit == 2) {
    const int mh = gridDim.y >> 1;
    if (by >= mh) { by -= mh; koff = K >> 1; C = Cb; Calt = Cbalt; }
    Kloc = K >> 1;
  }
  const int col0 = bx * 128;
  int r0 = by * 128;
  const f16* Ause = A;
  TC* Cuse = C;
  if (r0 >= split) { Ause = Aalt; Cuse = Calt; r0 -= split; }

  // staging: thread t covers LDS row (t>>2) (+64 for 2nd call), chunk t&3;
  // fetches global chunk (t&3) ^ ((row>>1)&3) (pre-swizzled source)
  const int strow = tid >> 2;
  const int schunk = tid & 3;
  const int sw = schunk ^ ((strow >> 1) & 3);
  const f16* gA0 = Ause + (size_t)(r0 + strow) * K + koff + sw * 8;
  const f16* gB0 = BT + (size_t)(col0 + strow) * K + koff + sw * 8;
  f16* ldsA0 = &sA[0][0] + (size_t)w * 512;
  f16* ldsB0 = &sB[0][0] + (size_t)w * 512;

  // ds_read offsets (f16 elems): row rt, swizzled chunk quad^((rt>>1)&3)
  const int qs = quad ^ ((m16 >> 1) & 3);
  int aoff[4], boff[4];
#pragma unroll
  for (int i = 0; i < 4; ++i) {
    aoff[i] = (wr * 64 + i * 16 + m16) * 32 + qs * 8;
    boff[i] = (wc * 64 + i * 16 + m16) * 32 + qs * 8;
  }

  const int nkt = Kloc >> 5;  // >= 16 in all our launches
  f32x4 acc[4][4] = {};

  auto stage = [&](int buf, int t) {
    const int k0 = t << 5;
    const size_t bufo = (size_t)buf * 4096;
    gload16(gA0 + k0, ldsA0 + bufo);
    gload16(gA0 + (size_t)64 * K + k0, ldsA0 + bufo + 2048);
    gload16(gB0 + k0, ldsB0 + bufo);
    gload16(gB0 + (size_t)64 * K + k0, ldsB0 + bufo + 2048);
  };

  stage(0, 0);
  int cur = 0;
  for (int t = 0; t < nkt; ++t) {
    // own 4 loads for tile t (issued one full k-step ago) landed
    asm volatile("s_waitcnt vmcnt(0)" ::: "memory");
    __builtin_amdgcn_s_barrier();  // all waves' tile-t loads visible
    if (t + 1 < nkt) stage(cur ^ 1, t + 1);  // buf read at t-1; all past it
    f16x8 af[4], bfr[4];
#pragma unroll
    for (int i = 0; i < 4; ++i) af[i] = *(const f16x8*)&sA[cur][aoff[i]];
#pragma unroll
    for (int i = 0; i < 4; ++i) bfr[i] = *(const f16x8*)&sB[cur][boff[i]];
    __builtin_amdgcn_s_setprio(1);
#pragma unroll
    for (int mi = 0; mi < 4; ++mi)
#pragma unroll
      for (int ni = 0; ni < 4; ++ni)
        acc[mi][ni] = __builtin_amdgcn_mfma_f32_16x16x32_f16(
            af[mi], bfr[ni], acc[mi][ni], 0, 0, 0);
    __builtin_amdgcn_s_setprio(0);
    cur ^= 1;
  }

  // Epilogue: D layout col=lane&15, row=quad*4+rg (16x16 family)
#pragma unroll
  for (int mi = 0; mi < 4; ++mi) {
    const int row = r0 + wr * 64 + mi * 16 + quad * 4;
#pragma unroll
    for (int ni = 0; ni < 4; ++ni) {
      const int col = col0 + wc * 64 + ni * 16 + m16;
      const float bv = bias ? bias[col] : 0.f;
#pragma unroll
      for (int rg = 0; rg < 4; ++rg) {
        float vv = acc[mi][ni][rg] + bv;
        if (relu) vv = vv > 0.f ? vv : 0.f;
        store_c(&Cuse[(size_t)(row + rg) * N + col], vv);
      }
    }
  }
}

// ---------------- Fused flash-MFMA attention ----------------
// R7: exact R5 body (110us proven; R6's single-barrier restructure
// regressed 8% and is reverted). f16 output kept. Two barriers/iter,
// 96-row R ring, wave-shared max, always-rescale.
__global__ __launch_bounds__(256, 4) void fattn_kernel(
    const bf16* __restrict__ qkvp,  // [1536*4, 3072] rows k*B+b, bf16
    const bf16* __restrict__ rhp,   // [1536, 1024] bf16
    const float* __restrict__ u, const float* __restrict__ v,
    f16* __restrict__ ctxh) {       // [4096, 1024] f16
  const int lin = blockIdx.x;      // 1024 blocks
  const int p = lin & 63;          // (b,h) pair; p%8 = XCD
  const int b = p & 3, h = p >> 2;
  const int i0 = (15 - (lin >> 6)) * 64;  // heavy tiles first
  const int tid = threadIdx.x;
  const int w = tid >> 6, lane = tid & 63;
  const int quad = lane >> 4, m16 = lane & 15;

  __shared__ short sVt[64 * 40];   // V^T tile: [d][j]
  __shared__ short sR[96 * 72];    // R ring buffer (phys = (32kt+trel)%96)
  __shared__ short sProb[64 * 40]; // probs bf16, per-wave strips

  const short* qkv = (const short*)qkvp;
  const short* rh  = (const short*)rhp;

  // Per-lane Q fragments: aQu = q+u (AC), aQv = q+v (BD). Rows w*16+m16.
  short8 aQu0, aQu1, aQv0, aQv1;
  {
    const size_t qro = ((size_t)(512 + i0 + w * 16 + m16) * 4 + b) * 3072 + h * 64 + quad * 8;
    short8 qa = *(const short8*)&qkv[qro];
    short8 qb = *(const short8*)&qkv[qro + 32];
    const float* up = u + h * 64 + quad * 8;
    const float* vp = v + h * 64 + quad * 8;
#pragma unroll
    for (int j = 0; j < 8; ++j) {
      const float qaf = b2f(qa[j]), qbf = b2f(qb[j]);
      aQu0[j] = f2b(qaf + up[j]);
      aQu1[j] = f2b(qbf + up[j + 32]);
      aQv0[j] = f2b(qaf + vp[j]);
      aQv1[j] = f2b(qbf + vp[j + 32]);
    }
  }

  // staging maps
  const int st_row = tid >> 3, st_d0 = (tid & 7) * 8;        // R chunk (32 rows)
  const int vj = lane & 31, vd0 = w * 16 + (lane >> 5) * 8;  // V^T scatter

  // Initial R window fill: trel 0..95, t = 960-i0+trel (never negative)
#pragma unroll
  for (int p_ = 0; p_ < 3; ++p_) {
    int t = 960 - i0 + p_ * 32 + st_row;
    t = t > 1535 ? 1535 : t;  // clamped rows only feed masked elems
    *(short8*)&sR[(p_ * 32 + st_row) * 72 + st_d0] =
        *(const short8*)&rh[(size_t)t * 1024 + h * 64 + st_d0];
  }
  // V tile 0 scatter
  {
    short8 v8 = *(const short8*)&qkv[((size_t)vj * 4 + b) * 3072 + 2048 + h * 64 + vd0];
#pragma unroll
    for (int q = 0; q < 8; ++q) sVt[(vd0 + q) * 40 + vj] = v8[q];
  }
  // K fragments tile 0 (per-lane, direct from global)
  short8 rKf[4];
#pragma unroll
  for (int n0i = 0; n0i < 2; ++n0i) {
    const size_t kro = ((size_t)(n0i * 16 + m16) * 4 + b) * 3072 + 1024 + h * 64 + quad * 8;
    rKf[n0i * 2] = *(const short8*)&qkv[kro];
    rKf[n0i * 2 + 1] = *(const short8*)&qkv[kro + 32];
  }

  short8 ones;
#pragma unroll
  for (int q = 0; q < 8; ++q) ones[q] = (short)0x3F80;  // bf16 1.0

  f32x4 O[4] = {};
  f32x4 L = {};
  float m = -1e30f;
  int bk = 0;               // (32*kt) % 96: ring base; also write slot base
  int tnext = 1056 - i0;    // t-base of chunk staged for tile kt+1

  const int n_kt = ((i0 + 575) >> 5) + 1;  // valid j <= i+512, i <= i0+63
  for (int kt = 0; kt < n_kt; ++kt) {
    const int j0 = kt * 32;
    const bool pf = (kt + 1 < n_kt);
    __syncthreads();  // staged LDS writes visible

    // prefetch next tile: V + new R chunk into regs (latency hidden)
    short8 nV, nR;
    if (pf) {
      nV = *(const short8*)&qkv[((size_t)(j0 + 32 + vj) * 4 + b) * 3072 + 2048 + h * 64 + vd0];
      int t = tnext + st_row;
      t = t > 1535 ? 1535 : t;
      nR = *(const short8*)&rh[(size_t)t * 1024 + h * 64 + st_d0];
    }

    // AC tiles from register K fragments
    f32x4 ac[2];
#pragma unroll
    for (int n0i = 0; n0i < 2; ++n0i) {
      f32x4 a = {};
      a = __builtin_amdgcn_mfma_f32_16x16x32_bf16(aQu0, rKf[n0i * 2], a, 0, 0, 0);
      a = __builtin_amdgcn_mfma_f32_16x16x32_bf16(aQu1, rKf[n0i * 2 + 1], a, 0, 0, 0);
      ac[n0i] = a;
    }
    // prefetch next K fragments (regs free after AC)
    if (pf) {
#pragma unroll
      for (int n0i = 0; n0i < 2; ++n0i) {
        const size_t kro = ((size_t)(j0 + 32 + n0i * 16 + m16) * 4 + b) * 3072 + 1024 + h * 64 + quad * 8;
        rKf[n0i * 2] = *(const short8*)&qkv[kro];
        rKf[n0i * 2 + 1] = *(const short8*)&qkv[kro + 32];
      }
    }

    // P = Qv.R tiles (ring rows), wave trel window [48-16w, 94-16w]
    f32x4 pb[3];
#pragma unroll
    for (int pt = 0; pt < 3; ++pt) {
      const int p0 = 48 - 16 * w + 16 * pt;
      int pr = bk + p0;
      if (pr >= 96) pr -= 96;
      int row = pr + m16;
      if (row >= 96) row -= 96;
      const short8 bR0 = *(const short8*)&sR[row * 72 + quad * 8];
      const short8 bR1 = *(const short8*)&sR[row * 72 + 32 + quad * 8];
      f32x4 pf_ = {};
      pf_ = __builtin_amdgcn_mfma_f32_16x16x32_bf16(aQv0, bR0, pf_, 0, 0, 0);
      pf_ = __builtin_amdgcn_mfma_f32_16x16x32_bf16(aQv1, bR1, pf_, 0, 0, 0);
      pb[pt] = pf_;
    }

    // Scores; rel-shift P gather via in-wave shuffles (same quad, same rg)
    float S0[4], S1[4];
    float mxl = -1e30f;
#pragma unroll
    for (int rg = 0; rg < 4; ++rg) {
      const int rloc = quad * 4 + rg;
      const int irow = i0 + w * 16 + rloc;
      const int c0 = m16 - rloc + 15;  // in [0,30]
      const int src = (lane & 48) | (c0 & 15);
      const float t0 = __shfl(pb[0][rg], src);
      const float t1 = __shfl(pb[1][rg], src);
      const float t2 = __shfl(pb[2][rg], src);
      const float p0v = (c0 < 16) ? t0 : t1;
      const float p1v = (c0 < 16) ? t1 : t2;
      float s0 = (ac[0][rg] + p0v) * 0.125f;
      float s1 = (ac[1][rg] + p1v) * 0.125f;
      if (j0 + m16 > irow + 512) s0 = -1e30f;
      if (j0 + 16 + m16 > irow + 512) s1 = -1e30f;
      S0[rg] = s0;
      S1[rg] = s1;
      mxl = fmaxf(mxl, fmaxf(s0, s1));
    }
    // wave-shared max (valid upper bound for all 16 rows of this wave)
    mxl = fmaxf(mxl, __shfl_xor(mxl, 1));
    mxl = fmaxf(mxl, __shfl_xor(mxl, 2));
    mxl = fmaxf(mxl, __shfl_xor(mxl, 4));
    mxl = fmaxf(mxl, __shfl_xor(mxl, 8));
    mxl = fmaxf(mxl, __shfl_xor(mxl, 16));
    mxl = fmaxf(mxl, __shfl_xor(mxl, 32));
    const float mnew = fmaxf(m, mxl);
    const float al = __expf(m - mnew);
    m = mnew;
#pragma unroll
    for (int rg = 0; rg < 4; ++rg) {
      const int rloc = quad * 4 + rg;
      sProb[(w * 16 + rloc) * 40 + m16] = f2b(__expf(S0[rg] - mnew));
      sProb[(w * 16 + rloc) * 40 + 16 + m16] = f2b(__expf(S1[rg] - mnew));
    }
#pragma unroll
    for (int d0i = 0; d0i < 4; ++d0i)
#pragma unroll
      for (int rg = 0; rg < 4; ++rg) O[d0i][rg] *= al;
#pragma unroll
    for (int rg = 0; rg < 4; ++rg) L[rg] *= al;

    // PV + row-sum accumulation (ones B-fragment broadcasts l to all cols)
    const short8 aP = *(const short8*)&sProb[(w * 16 + m16) * 40 + quad * 8];
    L = __builtin_amdgcn_mfma_f32_16x16x32_bf16(aP, ones, L, 0, 0, 0);
#pragma unroll
    for (int d0i = 0; d0i < 4; ++d0i) {
      const short8 bV = *(const short8*)&sVt[(d0i * 16 + m16) * 40 + quad * 8];
      O[d0i] = __builtin_amdgcn_mfma_f32_16x16x32_bf16(aP, bV, O[d0i], 0, 0, 0);
    }

    __syncthreads();  // all LDS reads done before restage
    if (pf) {
#pragma unroll
      for (int q = 0; q < 8; ++q) sVt[(vd0 + q) * 40 + vj] = nV[q];
      *(short8*)&sR[(bk + st_row) * 72 + st_d0] = nR;  // new chunk slot
    }
    bk += 32;
    if (bk >= 96) bk = 0;
    tnext += 32;
  }

  // Epilogue: ctxh[i*B+b][h*64+d] = (f16)(O/L)
#pragma unroll
  for (int d0i = 0; d0i < 4; ++d0i) {
#pragma unroll
    for (int rg = 0; rg < 4; ++rg) {
      const int irow = i0 + w * 16 + quad * 4 + rg;
      ctxh[((size_t)irow * 4 + b) * 1024 + h * 64 + d0i * 16 + m16] =
          (f16)(O[d0i][rg] / L[rg]);
    }
  }
}

// ---------------- LayerNorms ----------------
// ln1: x = LN(ya + yb + inputs); emits f16 x_h only.
__global__ __launch_bounds__(256) void ln1_kernel(
    const f16* __restrict__ ya, const f16* __restrict__ yb,
    const float* __restrict__ inp, const float* __restrict__ g,
    const float* __restrict__ beta, f16* __restrict__ xh) {
  const int r = blockIdx.x, tid = threadIdx.x;
  __shared__ float red[256];
  float t[4];
  float s = 0.f;
#pragma unroll
  for (int q = 0; q < 4; ++q) {
    int c = tid + q * 256;
    t[q] = (float)ya[(size_t)r * DM + c] + (float)yb[(size_t)r * DM + c] +
           inp[(size_t)r * DM + c];
    s += t[q];
  }
  red[tid] = s;
  __syncthreads();
  for (int st = 128; st > 0; st >>= 1) {
    if (tid < st) red[tid] += red[tid + st];
    __syncthreads();
  }
  const float mean = red[0] * (1.f / DM);
  __syncthreads();
  float vs = 0.f;
#pragma unroll
  for (int q = 0; q < 4; ++q) {
    float d0 = t[q] - mean;
    vs += d0 * d0;
  }
  red[tid] = vs;
  __syncthreads();
  for (int st = 128; st > 0; st >>= 1) {
    if (tid < st) red[tid] += red[tid + st];
    __syncthreads();
  }
  const float rstd = rsqrtf(red[0] * (1.f / DM) + 1e-5f);
#pragma unroll
  for (int q = 0; q < 4; ++q) {
    int c = tid + q * 256;
    const float val = (t[q] - mean) * rstd * g[c] + beta[c];
    xh[(size_t)r * DM + c] = (f16)val;
  }
}

// ln2: out = LN(x_h + y2a + y2b + b2), fp32 out.
__global__ __launch_bounds__(256) void ln2_kernel(
    const f16* __restrict__ xh, const f16* __restrict__ y2a,
    const f16* __restrict__ y2b, const float* __restrict__ b2,
    const float* __restrict__ g, const float* __restrict__ beta,
    float* __restrict__ out) {
  const int r = blockIdx.x, tid = threadIdx.x;
  __shared__ float red[256];
  float t[4];
  float s = 0.f;
#pragma unroll
  for (int q = 0; q < 4; ++q) {
    int c = tid + q * 256;
    t[q] = (float)xh[(size_t)r * DM + c] + (float)y2a[(size_t)r * DM + c] +
           (float)y2b[(size_t)r * DM + c] + b2[c];
    s += t[q];
  }
  red[tid] = s;
  __syncthreads();
  for (int st = 128; st > 0; st >>= 1) {
    if (tid < st) red[tid] += red[tid + st];
    __syncthreads();
  }
  const float mean = red[0] * (1.f / DM);
  __syncthreads();
  float vs = 0.f;
#pragma unroll
  for (int q = 0; q < 4; ++q) {
    float d0 = t[q] - mean;
    vs += d0 * d0;
  }
  red[tid] = vs;
  __syncthreads();
  for (int st = 128; st > 0; st >>= 1) {
    if (tid < st) red[tid] += red[tid + st];
    __syncthreads();
  }
  const float rstd = rsqrtf(red[0] * (1.f / DM) + 1e-5f);
#pragma unroll
  for (int q = 0; q < 4; ++q) {
    int c = tid + q * 256;
    out[(size_t)r * DM + c] = (t[q] - mean) * rstd * g[c] + beta[c];
  }
}

extern "C" void kernel_launch(void* const* d_in, const int* in_sizes, int n_in,
                              void* d_out, int out_size, void* d_ws, size_t ws_size,
                              hipStream_t stream) {
  const int o = (n_in >= 17) ? 1 : 0;
  const float* inputs = (const float*)d_in[0];
  const float* r      = (const float*)d_in[1];
  const float* u      = (const float*)d_in[2];
  const float* v      = (const float*)d_in[3];
  const float* memp   = (const float*)d_in[4];
  const float* W_qkv  = (const float*)d_in[5 + o];
  const float* W_r    = (const float*)d_in[6 + o];
  const float* W_o    = (const float*)d_in[7 + o];
  const float* ln1_g  = (const float*)d_in[8 + o];
  const float* ln1_b  = (const float*)d_in[9 + o];
  const float* ln2_g  = (const float*)d_in[10 + o];
  const float* ln2_b  = (const float*)d_in[11 + o];
  const float* W1     = (const float*)d_in[12 + o];
  const float* b1     = (const float*)d_in[13 + o];
  const float* W2     = (const float*)d_in[14 + o];
  const float* b2     = (const float*)d_in[15 + o];

  // Workspace liveness (peak 52,428,800 B):
  // phase 1: WqkvT@0 | r16@6291456 | WrT@9437184 | qkv@11534336 | rh@49283072
  //          cat_h@d_out
  // phase 2 (phase-1 ws dead after fattn):
  //   ctx_h@0 (fattn out) | WoT@8388608 | ya@10485760 | yb@18874368
  //   x_h@27262976 | W1T@35651584 | W2T@44040192 | h_hi@0 (after Wo dead)
  //   h_lo@d_out | y2a@18874368 (over yb) | y2b@35651584 (over W1T)
  char* ws = (char*)d_ws;
  f16*  WqkvT = (f16*)(ws);
  f16*  r16   = (f16*)(ws + 6291456);
  f16*  WrT   = (f16*)(ws + 9437184);
  bf16* qkv   = (bf16*)(ws + 11534336);
  bf16* rh    = (bf16*)(ws + 49283072);
  f16*  cat_h = (f16*)d_out;
  f16*  ctx_h = (f16*)(ws);
  f16*  WoT   = (f16*)(ws + 8388608);
  f16*  ya    = (f16*)(ws + 10485760);
  f16*  yb    = (f16*)(ws + 18874368);
  f16*  x_h   = (f16*)(ws + 27262976);
  f16*  W1T   = (f16*)(ws + 35651584);
  f16*  h_hi  = (f16*)(ws);
  f16*  h_lo  = (f16*)d_out;
  f16*  W2T   = (f16*)(ws + 44040192);
  f16*  y2a   = (f16*)(ws + 18874368);
  f16*  y2b   = (f16*)(ws + 35651584);

  dim3 blk(256);
  const int BIG = 1 << 30;

  // --- phase 1: converts + QKV/R projections + attention ---
  convh3_kernel<<<dim3(7680), blk, 0, stream>>>(
      memp, inputs, r, cat_h, cat_h + (size_t)2048 * 1024, r16);
  // {W_qkv: 768 tiles, W_r: 256} in one launch (desc2 unused: s2 = grid)
  convTm_kernel<<<dim3(1024), blk, 0, stream>>>(
      W_qkv, WqkvT, 1024, 3072, 48,
      768, W_r, WrT, 1024, 1024, 16,
      1024, nullptr, nullptr, 0, 0, 1);
  hgemm_kernel<bf16><<<dim3(24, 48), blk, 0, stream>>>(
      cat_h, WqkvT, qkv, 3072, 1024, nullptr, 0,
      nullptr, nullptr, BIG, nullptr, nullptr, 1);
  hgemm_kernel<bf16><<<dim3(8, 12), blk, 0, stream>>>(
      r16, WrT, rh, 1024, 1024, nullptr, 0,
      nullptr, nullptr, BIG, nullptr, nullptr, 1);
  fattn_kernel<<<dim3(1024), blk, 0, stream>>>(qkv, rh, u, v, ctx_h);

  // --- phase 2: weight transposes + output proj + LN1 + MLP + LN2 ---
  // {W_o: 256 tiles, W1: 1024, W2: 1024}; dests overlap now-dead qkv/rh
  convTm_kernel<<<dim3(2304), blk, 0, stream>>>(
      W_o, WoT, 1024, 1024, 16,
      256, W1, W1T, 1024, 4096, 64,
      1280, W2, W2T, 4096, 1024, 16);
  hgemm_kernel<f16><<<dim3(8, 64), blk, 0, stream>>>(
      ctx_h, WoT, ya, 1024, 1024, nullptr, 0,
      nullptr, nullptr, BIG, yb, nullptr, 2);
  ln1_kernel<<<dim3(4096), blk, 0, stream>>>(ya, yb, inputs, ln1_g, ln1_b, x_h);
  hgemm_kernel<f16><<<dim3(32, 32), blk, 0, stream>>>(
      x_h, W1T, h_lo, 4096, 1024, b1, 1,
      x_h + (size_t)2048 * 1024, h_hi, 2048, nullptr, nullptr, 1);
  hgemm_kernel<f16><<<dim3(8, 64), blk, 0, stream>>>(
      h_lo, W2T, y2a, 1024, 4096, nullptr, 0,
      h_hi, y2a + (size_t)2048 * 1024, 2048,
      y2b, y2b + (size_t)2048 * 1024, 2);
  ln2_kernel<<<dim3(4096), blk, 0, stream>>>(x_h, y2a, y2b, b2, ln2_g, ln2_b,
                                             (float*)d_out);
}

// Round 8
// 458.117 us; speedup vs baseline: 4.2729x; 1.0028x over previous
//
#include <hip/hip_runtime.h>
#include <hip/hip_bf16.h>

typedef __hip_bfloat16 bf16;
typedef _Float16 f16;
typedef __attribute__((ext_vector_type(8))) short short8;
typedef __attribute__((ext_vector_type(4))) float f32x4;
typedef __attribute__((ext_vector_type(8))) _Float16 f16x8;
typedef __attribute__((ext_vector_type(4))) _Float16 f16x4;

#define Q_LEN 1024
#define B_SZ 4
#define DM 1024
#define H_CNT 16
#define HD 64
#define MEM_LEN 512
#define KLEN 1536
#define MLP 4096

__device__ __forceinline__ void store_c(float* p, float v) { *p = v; }
__device__ __forceinline__ void store_c(bf16* p, float v) { *p = __float2bfloat16(v); }
__device__ __forceinline__ void store_c(f16* p, float v) { *p = (f16)v; }

__device__ __forceinline__ float b2f(short s) {
  union { unsigned u; float f; } x;
  x.u = ((unsigned)(unsigned short)s) << 16;
  return x.f;
}
__device__ __forceinline__ short f2b(float f) {
  union { float f; unsigned u; } x;
  x.f = f;
  unsigned r = x.u + 0x7fff + ((x.u >> 16) & 1);  // RNE; inputs finite
  return (short)(r >> 16);
}

// async global->LDS, 16B per lane; LDS dest = wave-uniform base + lane*16
__device__ __forceinline__ void gload16(const void* g, void* l) {
  __builtin_amdgcn_global_load_lds(
      (__attribute__((address_space(1))) unsigned int*)(g),
      (__attribute__((address_space(3))) unsigned int*)(l), 16, 0, 0);
}

// ------- merged fp32 -> fp16 convert: 3 segments in one launch -------
__global__ __launch_bounds__(256) void convh3_kernel(
    const float* __restrict__ X0, const float* __restrict__ X1,
    const float* __restrict__ X2, f16* __restrict__ Y0,
    f16* __restrict__ Y1, f16* __restrict__ Y2) {
  const int blk = blockIdx.x, tid = threadIdx.x;
  const float* X;
  f16* Y;
  int i;
  if (blk < 2048) { X = X0; Y = Y0; i = blk * 256 + tid; }
  else if (blk < 6144) { X = X1; Y = Y1; i = (blk - 2048) * 256 + tid; }
  else { X = X2; Y = Y2; i = (blk - 6144) * 256 + tid; }
  f32x4 v = *(const f32x4*)&X[(size_t)i * 4];
  f16x4 h;
#pragma unroll
  for (int j = 0; j < 4; ++j) h[j] = (f16)v[j];
  *(f16x4*)&Y[(size_t)i * 4] = h;
}

// ------- merged fp32 [K][N] -> fp16 [N][K] transpose: 3 descriptors -------
__global__ __launch_bounds__(256) void convTm_kernel(
    const float* W0, f16* T0, int K0, int N0, int nx0,
    int s1, const float* W1p, f16* T1, int K1, int N1, int nx1,
    int s2, const float* W2p, f16* T2, int K2, int N2, int nx2) {
  __shared__ float tile[64][65];
  const int blk = blockIdx.x, tid = threadIdx.x;
  const float* W;
  f16* WT;
  int K, N, nx, local;
  if (blk < s1) { W = W0; WT = T0; K = K0; N = N0; nx = nx0; local = blk; }
  else if (blk < s2) { W = W1p; WT = T1; K = K1; N = N1; nx = nx1; local = blk - s1; }
  else { W = W2p; WT = T2; K = K2; N = N2; nx = nx2; local = blk - s2; }
  const int n0 = (local % nx) * 64, k0 = (local / nx) * 64;
  const int tn = tid & 63, tk4 = tid >> 6;
#pragma unroll
  for (int p = 0; p < 16; ++p) {
    const int kk = tk4 + p * 4;
    tile[kk][tn] = W[(size_t)(k0 + kk) * N + n0 + tn];
  }
  __syncthreads();
#pragma unroll
  for (int p = 0; p < 16; ++p) {
    const int nn = tk4 + p * 4;
    WT[(size_t)(n0 + nn) * K + k0 + tn] = (f16)tile[tn][nn];
  }
}

// ---------------- fp16 MFMA GEMM: C = A[M,K] * BT[N,K]^T ----------------
// R6 structure (kept): 2-buffer LDS (32KB) + 4 blocks/CU; depth-1
// prefetch issued right after the barrier; split-K; XCD swizzle.
template <typename TC>
__global__ __launch_bounds__(256, 4) void hgemm_kernel(
    const f16* __restrict__ A, const f16* __restrict__ BT, TC* C,
    int N, int K, const float* __restrict__ bias, int relu,
    const f16* __restrict__ Aalt, TC* Calt, int split,
    TC* Cb, TC* Cbalt, int ksplit) {
  __shared__ __align__(16) f16 sA[2][128 * 32];
  __shared__ __align__(16) f16 sB[2][128 * 32];
  const int tid = threadIdx.x;
  const int w = tid >> 6, lane = tid & 63;
  const int quad = lane >> 4, m16 = lane & 15;
  const int wr = w >> 1, wc = w & 1;
  // XCD-aware swizzle: all our grids have nwg % 8 == 0 (bijective).
  const int gx = gridDim.x;
  const int nwg = gx * gridDim.y;
  const int lin = blockIdx.y * gx + blockIdx.x;
  const int cpx = nwg >> 3;
  const int swz = (lin & 7) * cpx + (lin >> 3);
  const int bx = swz % gx;
  int by = swz / gx;
  int koff = 0, Kloc = K;
  if (ksplit == 2) {
    const int mh = gridDim.y >> 1;
    if (by >= mh) { by -= mh; koff = K >> 1; C = Cb; Calt = Cbalt; }
    Kloc = K >> 1;
  }
  const int col0 = bx * 128;
  int r0 = by * 128;
  const f16* Ause = A;
  TC* Cuse = C;
  if (r0 >= split) { Ause = Aalt; Cuse = Calt; r0 -= split; }

  // staging: thread t covers LDS row (t>>2) (+64 for 2nd call), chunk t&3;
  // fetches global chunk (t&3) ^ ((row>>1)&3) (pre-swizzled source)
  const int strow = tid >> 2;
  const int schunk = tid & 3;
  const int sw = schunk ^ ((strow >> 1) & 3);
  const f16* gA0 = Ause + (size_t)(r0 + strow) * K + koff + sw * 8;
  const f16* gB0 = BT + (size_t)(col0 + strow) * K + koff + sw * 8;
  f16* ldsA0 = &sA[0][0] + (size_t)w * 512;
  f16* ldsB0 = &sB[0][0] + (size_t)w * 512;

  // ds_read offsets (f16 elems): row rt, swizzled chunk quad^((rt>>1)&3)
  const int qs = quad ^ ((m16 >> 1) & 3);
  int aoff[4], boff[4];
#pragma unroll
  for (int i = 0; i < 4; ++i) {
    aoff[i] = (wr * 64 + i * 16 + m16) * 32 + qs * 8;
    boff[i] = (wc * 64 + i * 16 + m16) * 32 + qs * 8;
  }

  const int nkt = Kloc >> 5;  // >= 16 in all our launches
  f32x4 acc[4][4] = {};

  auto stage = [&](int buf, int t) {
    const int k0 = t << 5;
    const size_t bufo = (size_t)buf * 4096;
    gload16(gA0 + k0, ldsA0 + bufo);
    gload16(gA0 + (size_t)64 * K + k0, ldsA0 + bufo + 2048);
    gload16(gB0 + k0, ldsB0 + bufo);
    gload16(gB0 + (size_t)64 * K + k0, ldsB0 + bufo + 2048);
  };

  stage(0, 0);
  int cur = 0;
  for (int t = 0; t < nkt; ++t) {
    // own 4 loads for tile t (issued one full k-step ago) landed
    asm volatile("s_waitcnt vmcnt(0)" ::: "memory");
    __builtin_amdgcn_s_barrier();  // all waves' tile-t loads visible
    if (t + 1 < nkt) stage(cur ^ 1, t + 1);  // buf read at t-1; all past it
    f16x8 af[4], bfr[4];
#pragma unroll
    for (int i = 0; i < 4; ++i) af[i] = *(const f16x8*)&sA[cur][aoff[i]];
#pragma unroll
    for (int i = 0; i < 4; ++i) bfr[i] = *(const f16x8*)&sB[cur][boff[i]];
    __builtin_amdgcn_s_setprio(1);
#pragma unroll
    for (int mi = 0; mi < 4; ++mi)
#pragma unroll
      for (int ni = 0; ni < 4; ++ni)
        acc[mi][ni] = __builtin_amdgcn_mfma_f32_16x16x32_f16(
            af[mi], bfr[ni], acc[mi][ni], 0, 0, 0);
    __builtin_amdgcn_s_setprio(0);
    cur ^= 1;
  }

  // Epilogue: D layout col=lane&15, row=quad*4+rg (16x16 family)
#pragma unroll
  for (int mi = 0; mi < 4; ++mi) {
    const int row = r0 + wr * 64 + mi * 16 + quad * 4;
#pragma unroll
    for (int ni = 0; ni < 4; ++ni) {
      const int col = col0 + wc * 64 + ni * 16 + m16;
      const float bv = bias ? bias[col] : 0.f;
#pragma unroll
      for (int rg = 0; rg < 4; ++rg) {
        float vv = acc[mi][ni][rg] + bv;
        if (relu) vv = vv > 0.f ? vv : 0.f;
        store_c(&Cuse[(size_t)(row + rg) * N + col], vv);
      }
    }
  }
}

// ---------------- Fused flash-MFMA attention ----------------
// R8 vs R7 (R5 body kept structurally):
//  - magic-square i0 permutation: per-CU n_kt sums equalized (was 120-144
//    under round-robin dispatch; now 132 everywhere). XCD map unchanged.
//  - defer-max (T13) alone: skip O/L rescale when mxl <= m+8 (wave-uniform
//    branch; P bounded by e^8; exact normalization at epilogue).
//  - v_cvt_pk_bf16_f32 (RNE, bit-identical to f2b) for prob stores.
__global__ __launch_bounds__(256, 4) void fattn_kernel(
    const bf16* __restrict__ qkvp,  // [1536*4, 3072] rows k*B+b, bf16
    const bf16* __restrict__ rhp,   // [1536, 1024] bf16
    const float* __restrict__ u, const float* __restrict__ v,
    f16* __restrict__ ctxh) {       // [4096, 1024] f16
  const int lin = blockIdx.x;      // 1024 blocks
  const int p = lin & 63;          // (b,h) pair; p%8 = XCD
  const int b = p & 3, h = p >> 2;
  // magic square: residue classes {k, k+4, k+8, k+12} all sum to 30
  const int permv[16] = {15, 14, 13, 12, 10, 11, 8, 9, 4, 5, 6, 7, 1, 0, 3, 2};
  const int i0 = permv[lin >> 6] * 64;
  const int tid = threadIdx.x;
  const int w = tid >> 6, lane = tid & 63;
  const int quad = lane >> 4, m16 = lane & 15;

  __shared__ short sVt[64 * 40];   // V^T tile: [d][j]
  __shared__ short sR[96 * 72];    // R ring buffer (phys = (32kt+trel)%96)
  __shared__ short sProb[64 * 40]; // probs bf16, per-wave strips

  const short* qkv = (const short*)qkvp;
  const short* rh  = (const short*)rhp;

  // Per-lane Q fragments: aQu = q+u (AC), aQv = q+v (BD). Rows w*16+m16.
  short8 aQu0, aQu1, aQv0, aQv1;
  {
    const size_t qro = ((size_t)(512 + i0 + w * 16 + m16) * 4 + b) * 3072 + h * 64 + quad * 8;
    short8 qa = *(const short8*)&qkv[qro];
    short8 qb = *(const short8*)&qkv[qro + 32];
    const float* up = u + h * 64 + quad * 8;
    const float* vp = v + h * 64 + quad * 8;
#pragma unroll
    for (int j = 0; j < 8; ++j) {
      const float qaf = b2f(qa[j]), qbf = b2f(qb[j]);
      aQu0[j] = f2b(qaf + up[j]);
      aQu1[j] = f2b(qbf + up[j + 32]);
      aQv0[j] = f2b(qaf + vp[j]);
      aQv1[j] = f2b(qbf + vp[j + 32]);
    }
  }

  // staging maps
  const int st_row = tid >> 3, st_d0 = (tid & 7) * 8;        // R chunk (32 rows)
  const int vj = lane & 31, vd0 = w * 16 + (lane >> 5) * 8;  // V^T scatter

  // Initial R window fill: trel 0..95, t = 960-i0+trel (never negative)
#pragma unroll
  for (int p_ = 0; p_ < 3; ++p_) {
    int t = 960 - i0 + p_ * 32 + st_row;
    t = t > 1535 ? 1535 : t;  // clamped rows only feed masked elems
    *(short8*)&sR[(p_ * 32 + st_row) * 72 + st_d0] =
        *(const short8*)&rh[(size_t)t * 1024 + h * 64 + st_d0];
  }
  // V tile 0 scatter
  {
    short8 v8 = *(const short8*)&qkv[((size_t)vj * 4 + b) * 3072 + 2048 + h * 64 + vd0];
#pragma unroll
    for (int q = 0; q < 8; ++q) sVt[(vd0 + q) * 40 + vj] = v8[q];
  }
  // K fragments tile 0 (per-lane, direct from global)
  short8 rKf[4];
#pragma unroll
  for (int n0i = 0; n0i < 2; ++n0i) {
    const size_t kro = ((size_t)(n0i * 16 + m16) * 4 + b) * 3072 + 1024 + h * 64 + quad * 8;
    rKf[n0i * 2] = *(const short8*)&qkv[kro];
    rKf[n0i * 2 + 1] = *(const short8*)&qkv[kro + 32];
  }

  short8 ones;
#pragma unroll
  for (int q = 0; q < 8; ++q) ones[q] = (short)0x3F80;  // bf16 1.0

  f32x4 O[4] = {};
  f32x4 L = {};
  float m = -1e30f;
  int bk = 0;               // (32*kt) % 96: ring base; also write slot base
  int tnext = 1056 - i0;    // t-base of chunk staged for tile kt+1

  const int n_kt = ((i0 + 575) >> 5) + 1;  // valid j <= i+512, i <= i0+63
  for (int kt = 0; kt < n_kt; ++kt) {
    const int j0 = kt * 32;
    const bool pf = (kt + 1 < n_kt);
    __syncthreads();  // staged LDS writes visible

    // prefetch next tile: V + new R chunk into regs (latency hidden)
    short8 nV, nR;
    if (pf) {
      nV = *(const short8*)&qkv[((size_t)(j0 + 32 + vj) * 4 + b) * 3072 + 2048 + h * 64 + vd0];
      int t = tnext + st_row;
      t = t > 1535 ? 1535 : t;
      nR = *(const short8*)&rh[(size_t)t * 1024 + h * 64 + st_d0];
    }

    // AC tiles from register K fragments
    f32x4 ac[2];
#pragma unroll
    for (int n0i = 0; n0i < 2; ++n0i) {
      f32x4 a = {};
      a = __builtin_amdgcn_mfma_f32_16x16x32_bf16(aQu0, rKf[n0i * 2], a, 0, 0, 0);
      a = __builtin_amdgcn_mfma_f32_16x16x32_bf16(aQu1, rKf[n0i * 2 + 1], a, 0, 0, 0);
      ac[n0i] = a;
    }
    // prefetch next K fragments (regs free after AC)
    if (pf) {
#pragma unroll
      for (int n0i = 0; n0i < 2; ++n0i) {
        const size_t kro = ((size_t)(j0 + 32 + n0i * 16 + m16) * 4 + b) * 3072 + 1024 + h * 64 + quad * 8;
        rKf[n0i * 2] = *(const short8*)&qkv[kro];
        rKf[n0i * 2 + 1] = *(const short8*)&qkv[kro + 32];
      }
    }

    // P = Qv.R tiles (ring rows), wave trel window [48-16w, 94-16w]
    f32x4 pb[3];
#pragma unroll
    for (int pt = 0; pt < 3; ++pt) {
      const int p0 = 48 - 16 * w + 16 * pt;
      int pr = bk + p0;
      if (pr >= 96) pr -= 96;
      int row = pr + m16;
      if (row >= 96) row -= 96;
      const short8 bR0 = *(const short8*)&sR[row * 72 + quad * 8];
      const short8 bR1 = *(const short8*)&sR[row * 72 + 32 + quad * 8];
      f32x4 pf_ = {};
      pf_ = __builtin_amdgcn_mfma_f32_16x16x32_bf16(aQv0, bR0, pf_, 0, 0, 0);
      pf_ = __builtin_amdgcn_mfma_f32_16x16x32_bf16(aQv1, bR1, pf_, 0, 0, 0);
      pb[pt] = pf_;
    }

    // Scores; rel-shift P gather via in-wave shuffles (same quad, same rg)
    float S0[4], S1[4];
    float mxl = -1e30f;
#pragma unroll
    for (int rg = 0; rg < 4; ++rg) {
      const int rloc = quad * 4 + rg;
      const int irow = i0 + w * 16 + rloc;
      const int c0 = m16 - rloc + 15;  // in [0,30]
      const int src = (lane & 48) | (c0 & 15);
      const float t0 = __shfl(pb[0][rg], src);
      const float t1 = __shfl(pb[1][rg], src);
      const float t2 = __shfl(pb[2][rg], src);
      const float p0v = (c0 < 16) ? t0 : t1;
      const float p1v = (c0 < 16) ? t1 : t2;
      float s0 = (ac[0][rg] + p0v) * 0.125f;
      float s1 = (ac[1][rg] + p1v) * 0.125f;
      if (j0 + m16 > irow + 512) s0 = -1e30f;
      if (j0 + 16 + m16 > irow + 512) s1 = -1e30f;
      S0[rg] = s0;
      S1[rg] = s1;
      mxl = fmaxf(mxl, fmaxf(s0, s1));
    }
    // wave-shared max (valid upper bound for all 16 rows of this wave)
    mxl = fmaxf(mxl, __shfl_xor(mxl, 1));
    mxl = fmaxf(mxl, __shfl_xor(mxl, 2));
    mxl = fmaxf(mxl, __shfl_xor(mxl, 4));
    mxl = fmaxf(mxl, __shfl_xor(mxl, 8));
    mxl = fmaxf(mxl, __shfl_xor(mxl, 16));
    mxl = fmaxf(mxl, __shfl_xor(mxl, 32));
    // defer-max (T13): rescale only when max grew materially (wave-uniform)
    if (mxl > m + 8.f) {
      const float al = __expf(m - mxl);
      m = mxl;
#pragma unroll
      for (int d0i = 0; d0i < 4; ++d0i)
#pragma unroll
        for (int rg = 0; rg < 4; ++rg) O[d0i][rg] *= al;
#pragma unroll
      for (int rg = 0; rg < 4; ++rg) L[rg] *= al;
    }
#pragma unroll
    for (int rg = 0; rg < 4; ++rg) {
      const int rloc = quad * 4 + rg;
      const float e0 = __expf(S0[rg] - m);
      const float e1 = __expf(S1[rg] - m);
      unsigned pk;
      asm("v_cvt_pk_bf16_f32 %0, %1, %2" : "=v"(pk) : "v"(e0), "v"(e1));
      sProb[(w * 16 + rloc) * 40 + m16] = (short)(pk & 0xffff);
      sProb[(w * 16 + rloc) * 40 + 16 + m16] = (short)(pk >> 16);
    }

    // PV + row-sum accumulation (ones B-fragment broadcasts l to all cols)
    const short8 aP = *(const short8*)&sProb[(w * 16 + m16) * 40 + quad * 8];
    L = __builtin_amdgcn_mfma_f32_16x16x32_bf16(aP, ones, L, 0, 0, 0);
#pragma unroll
    for (int d0i = 0; d0i < 4; ++d0i) {
      const short8 bV = *(const short8*)&sVt[(d0i * 16 + m16) * 40 + quad * 8];
      O[d0i] = __builtin_amdgcn_mfma_f32_16x16x32_bf16(aP, bV, O[d0i], 0, 0, 0);
    }

    __syncthreads();  // all LDS reads done before restage
    if (pf) {
#pragma unroll
      for (int q = 0; q < 8; ++q) sVt[(vd0 + q) * 40 + vj] = nV[q];
      *(short8*)&sR[(bk + st_row) * 72 + st_d0] = nR;  // new chunk slot
    }
    bk += 32;
    if (bk >= 96) bk = 0;
    tnext += 32;
  }

  // Epilogue: ctxh[i*B+b][h*64+d] = (f16)(O/L)
#pragma unroll
  for (int d0i = 0; d0i < 4; ++d0i) {
#pragma unroll
    for (int rg = 0; rg < 4; ++rg) {
      const int irow = i0 + w * 16 + quad * 4 + rg;
      ctxh[((size_t)irow * 4 + b) * 1024 + h * 64 + d0i * 16 + m16] =
          (f16)(O[d0i][rg] / L[rg]);
    }
  }
}

// ---------------- LayerNorms ----------------
// ln1: x = LN(ya + yb + inputs); emits f16 x_h only.
__global__ __launch_bounds__(256) void ln1_kernel(
    const f16* __restrict__ ya, const f16* __restrict__ yb,
    const float* __restrict__ inp, const float* __restrict__ g,
    const float* __restrict__ beta, f16* __restrict__ xh) {
  const int r = blockIdx.x, tid = threadIdx.x;
  __shared__ float red[256];
  float t[4];
  float s = 0.f;
#pragma unroll
  for (int q = 0; q < 4; ++q) {
    int c = tid + q * 256;
    t[q] = (float)ya[(size_t)r * DM + c] + (float)yb[(size_t)r * DM + c] +
           inp[(size_t)r * DM + c];
    s += t[q];
  }
  red[tid] = s;
  __syncthreads();
  for (int st = 128; st > 0; st >>= 1) {
    if (tid < st) red[tid] += red[tid + st];
    __syncthreads();
  }
  const float mean = red[0] * (1.f / DM);
  __syncthreads();
  float vs = 0.f;
#pragma unroll
  for (int q = 0; q < 4; ++q) {
    float d0 = t[q] - mean;
    vs += d0 * d0;
  }
  red[tid] = vs;
  __syncthreads();
  for (int st = 128; st > 0; st >>= 1) {
    if (tid < st) red[tid] += red[tid + st];
    __syncthreads();
  }
  const float rstd = rsqrtf(red[0] * (1.f / DM) + 1e-5f);
#pragma unroll
  for (int q = 0; q < 4; ++q) {
    int c = tid + q * 256;
    const float val = (t[q] - mean) * rstd * g[c] + beta[c];
    xh[(size_t)r * DM + c] = (f16)val;
  }
}

// ln2: out = LN(x_h + y2a + y2b + b2), fp32 out.
__global__ __launch_bounds__(256) void ln2_kernel(
    const f16* __restrict__ xh, const f16* __restrict__ y2a,
    const f16* __restrict__ y2b, const float* __restrict__ b2,
    const float* __restrict__ g, const float* __restrict__ beta,
    float* __restrict__ out) {
  const int r = blockIdx.x, tid = threadIdx.x;
  __shared__ float red[256];
  float t[4];
  float s = 0.f;
#pragma unroll
  for (int q = 0; q < 4; ++q) {
    int c = tid + q * 256;
    t[q] = (float)xh[(size_t)r * DM + c] + (float)y2a[(size_t)r * DM + c] +
           (float)y2b[(size_t)r * DM + c] + b2[c];
    s += t[q];
  }
  red[tid] = s;
  __syncthreads();
  for (int st = 128; st > 0; st >>= 1) {
    if (tid < st) red[tid] += red[tid + st];
    __syncthreads();
  }
  const float mean = red[0] * (1.f / DM);
  __syncthreads();
  float vs = 0.f;
#pragma unroll
  for (int q = 0; q < 4; ++q) {
    float d0 = t[q] - mean;
    vs += d0 * d0;
  }
  red[tid] = vs;
  __syncthreads();
  for (int st = 128; st > 0; st >>= 1) {
    if (tid < st) red[tid] += red[tid + st];
    __syncthreads();
  }
  const float rstd = rsqrtf(red[0] * (1.f / DM) + 1e-5f);
#pragma unroll
  for (int q = 0; q < 4; ++q) {
    int c = tid + q * 256;
    out[(size_t)r * DM + c] = (t[q] - mean) * rstd * g[c] + beta[c];
  }
}

extern "C" void kernel_launch(void* const* d_in, const int* in_sizes, int n_in,
                              void* d_out, int out_size, void* d_ws, size_t ws_size,
                              hipStream_t stream) {
  const int o = (n_in >= 17) ? 1 : 0;
  const float* inputs = (const float*)d_in[0];
  const float* r      = (const float*)d_in[1];
  const float* u      = (const float*)d_in[2];
  const float* v      = (const float*)d_in[3];
  const float* memp   = (const float*)d_in[4];
  const float* W_qkv  = (const float*)d_in[5 + o];
  const float* W_r    = (const float*)d_in[6 + o];
  const float* W_o    = (const float*)d_in[7 + o];
  const float* ln1_g  = (const float*)d_in[8 + o];
  const float* ln1_b  = (const float*)d_in[9 + o];
  const float* ln2_g  = (const float*)d_in[10 + o];
  const float* ln2_b  = (const float*)d_in[11 + o];
  const float* W1     = (const float*)d_in[12 + o];
  const float* b1     = (const float*)d_in[13 + o];
  const float* W2     = (const float*)d_in[14 + o];
  const float* b2     = (const float*)d_in[15 + o];

  // Workspace liveness (peak 52,428,800 B) — unchanged from R7
  char* ws = (char*)d_ws;
  f16*  WqkvT = (f16*)(ws);
  f16*  r16   = (f16*)(ws + 6291456);
  f16*  WrT   = (f16*)(ws + 9437184);
  bf16* qkv   = (bf16*)(ws + 11534336);
  bf16* rh    = (bf16*)(ws + 49283072);
  f16*  cat_h = (f16*)d_out;
  f16*  ctx_h = (f16*)(ws);
  f16*  WoT   = (f16*)(ws + 8388608);
  f16*  ya    = (f16*)(ws + 10485760);
  f16*  yb    = (f16*)(ws + 18874368);
  f16*  x_h   = (f16*)(ws + 27262976);
  f16*  W1T   = (f16*)(ws + 35651584);
  f16*  h_hi  = (f16*)(ws);
  f16*  h_lo  = (f16*)d_out;
  f16*  W2T   = (f16*)(ws + 44040192);
  f16*  y2a   = (f16*)(ws + 18874368);
  f16*  y2b   = (f16*)(ws + 35651584);

  dim3 blk(256);
  const int BIG = 1 << 30;

  // --- phase 1: converts + QKV/R projections + attention ---
  convh3_kernel<<<dim3(7680), blk, 0, stream>>>(
      memp, inputs, r, cat_h, cat_h + (size_t)2048 * 1024, r16);
  convTm_kernel<<<dim3(1024), blk, 0, stream>>>(
      W_qkv, WqkvT, 1024, 3072, 48,
      768, W_r, WrT, 1024, 1024, 16,
      1024, nullptr, nullptr, 0, 0, 1);
  // QKV split: mem rows (0..2047) only need k,v cols [1024,3072);
  // input rows (2048..6143) need all cols. Saves 1/9 of the GEMM.
  hgemm_kernel<bf16><<<dim3(16, 16), blk, 0, stream>>>(
      cat_h, WqkvT + (size_t)1024 * 1024, qkv + 1024, 3072, 1024, nullptr, 0,
      nullptr, nullptr, BIG, nullptr, nullptr, 1);
  hgemm_kernel<bf16><<<dim3(24, 32), blk, 0, stream>>>(
      cat_h + (size_t)2048 * 1024, WqkvT, qkv + (size_t)2048 * 3072,
      3072, 1024, nullptr, 0,
      nullptr, nullptr, BIG, nullptr, nullptr, 1);
  hgemm_kernel<bf16><<<dim3(8, 12), blk, 0, stream>>>(
      r16, WrT, rh, 1024, 1024, nullptr, 0,
      nullptr, nullptr, BIG, nullptr, nullptr, 1);
  fattn_kernel<<<dim3(1024), blk, 0, stream>>>(qkv, rh, u, v, ctx_h);

  // --- phase 2: weight transposes + output proj + LN1 + MLP + LN2 ---
  convTm_kernel<<<dim3(2304), blk, 0, stream>>>(
      W_o, WoT, 1024, 1024, 16,
      256, W1, W1T, 1024, 4096, 64,
      1280, W2, W2T, 4096, 1024, 16);
  hgemm_kernel<f16><<<dim3(8, 64), blk, 0, stream>>>(
      ctx_h, WoT, ya, 1024, 1024, nullptr, 0,
      nullptr, nullptr, BIG, yb, nullptr, 2);
  ln1_kernel<<<dim3(4096), blk, 0, stream>>>(ya, yb, inputs, ln1_g, ln1_b, x_h);
  hgemm_kernel<f16><<<dim3(32, 32), blk, 0, stream>>>(
      x_h, W1T, h_lo, 4096, 1024, b1, 1,
      x_h + (size_t)2048 * 1024, h_hi, 2048, nullptr, nullptr, 1);
  hgemm_kernel<f16><<<dim3(8, 64), blk, 0, stream>>>(
      h_lo, W2T, y2a, 1024, 4096, nullptr, 0,
      h_hi, y2a + (size_t)2048 * 1024, 2048,
      y2b, y2b + (size_t)2048 * 1024, 2);
  ln2_kernel<<<dim3(4096), blk, 0, stream>>>(x_h, y2a, y2b, b2, ln2_g, ln2_b,
                                             (float*)d_out);
}

// Round 9
// 451.654 us; speedup vs baseline: 4.3340x; 1.0143x over previous
//
#include <hip/hip_runtime.h>
#include <hip/hip_bf16.h>

typedef __hip_bfloat16 bf16;
typedef _Float16 f16;
typedef __attribute__((ext_vector_type(8))) short short8;
typedef __attribute__((ext_vector_type(4))) float f32x4;
typedef __attribute__((ext_vector_type(8))) _Float16 f16x8;
typedef __attribute__((ext_vector_type(4))) _Float16 f16x4;

#define Q_LEN 1024
#define B_SZ 4
#define DM 1024
#define H_CNT 16
#define HD 64
#define MEM_LEN 512
#define KLEN 1536
#define MLP 4096

__device__ __forceinline__ void store_c(float* p, float v) { *p = v; }
__device__ __forceinline__ void store_c(bf16* p, float v) { *p = __float2bfloat16(v); }
__device__ __forceinline__ void store_c(f16* p, float v) { *p = (f16)v; }

__device__ __forceinline__ float b2f(short s) {
  union { unsigned u; float f; } x;
  x.u = ((unsigned)(unsigned short)s) << 16;
  return x.f;
}
__device__ __forceinline__ short f2b(float f) {
  union { float f; unsigned u; } x;
  x.f = f;
  unsigned r = x.u + 0x7fff + ((x.u >> 16) & 1);  // RNE; inputs finite
  return (short)(r >> 16);
}

// async global->LDS, 16B per lane; LDS dest = wave-uniform base + lane*16
__device__ __forceinline__ void gload16(const void* g, void* l) {
  __builtin_amdgcn_global_load_lds(
      (__attribute__((address_space(1))) unsigned int*)(g),
      (__attribute__((address_space(3))) unsigned int*)(l), 16, 0, 0);
}

// ------- merged fp32 -> fp16 convert: 3 segments in one launch -------
__global__ __launch_bounds__(256) void convh3_kernel(
    const float* __restrict__ X0, const float* __restrict__ X1,
    const float* __restrict__ X2, f16* __restrict__ Y0,
    f16* __restrict__ Y1, f16* __restrict__ Y2) {
  const int blk = blockIdx.x, tid = threadIdx.x;
  const float* X;
  f16* Y;
  int i;
  if (blk < 2048) { X = X0; Y = Y0; i = blk * 256 + tid; }
  else if (blk < 6144) { X = X1; Y = Y1; i = (blk - 2048) * 256 + tid; }
  else { X = X2; Y = Y2; i = (blk - 6144) * 256 + tid; }
  f32x4 v = *(const f32x4*)&X[(size_t)i * 4];
  f16x4 h;
#pragma unroll
  for (int j = 0; j < 4; ++j) h[j] = (f16)v[j];
  *(f16x4*)&Y[(size_t)i * 4] = h;
}

// ------- merged fp32 [K][N] -> fp16 [N][K] transpose: 3 descriptors -------
__global__ __launch_bounds__(256) void convTm_kernel(
    const float* W0, f16* T0, int K0, int N0, int nx0,
    int s1, const float* W1p, f16* T1, int K1, int N1, int nx1,
    int s2, const float* W2p, f16* T2, int K2, int N2, int nx2) {
  __shared__ float tile[64][65];
  const int blk = blockIdx.x, tid = threadIdx.x;
  const float* W;
  f16* WT;
  int K, N, nx, local;
  if (blk < s1) { W = W0; WT = T0; K = K0; N = N0; nx = nx0; local = blk; }
  else if (blk < s2) { W = W1p; WT = T1; K = K1; N = N1; nx = nx1; local = blk - s1; }
  else { W = W2p; WT = T2; K = K2; N = N2; nx = nx2; local = blk - s2; }
  const int n0 = (local % nx) * 64, k0 = (local / nx) * 64;
  const int tn = tid & 63, tk4 = tid >> 6;
#pragma unroll
  for (int p = 0; p < 16; ++p) {
    const int kk = tk4 + p * 4;
    tile[kk][tn] = W[(size_t)(k0 + kk) * N + n0 + tn];
  }
  __syncthreads();
#pragma unroll
  for (int p = 0; p < 16; ++p) {
    const int nn = tk4 + p * 4;
    WT[(size_t)(n0 + nn) * K + k0 + tn] = (f16)tile[tn][nn];
  }
}

// ---------------- fp16 MFMA GEMM: C = A[M,K] * BT[N,K]^T ----------------
// R9: BM template (128 or 64). BM=64: 64x128 tile, LDS 24KB, acc[2][4],
// one A-gload/step. Doubles resident blocks/CU for skinny-N GEMMs
// (Wo/W2/mem-kv: 2->4, 1->2 blocks/CU) — the latency-bound limiter.
// 2-buffer depth-1 pipeline + split-K + XCD swizzle kept from R6/R5.
template <typename TC, int BM>
__global__ __launch_bounds__(256, 4) void hgemm_kernel(
    const f16* __restrict__ A, const f16* __restrict__ BT, TC* C,
    int N, int K, const float* __restrict__ bias, int relu,
    const f16* __restrict__ Aalt, TC* Calt, int split,
    TC* Cb, TC* Cbalt, int ksplit) {
  constexpr int MR = BM / 32;           // per-wave M-fragment repeats
  __shared__ __align__(16) f16 sA[2][BM * 32];
  __shared__ __align__(16) f16 sB[2][128 * 32];
  const int tid = threadIdx.x;
  const int w = tid >> 6, lane = tid & 63;
  const int quad = lane >> 4, m16 = lane & 15;
  const int wr = w >> 1, wc = w & 1;
  // XCD-aware swizzle: all our grids have nwg % 8 == 0 (bijective).
  const int gx = gridDim.x;
  const int nwg = gx * gridDim.y;
  const int lin = blockIdx.y * gx + blockIdx.x;
  const int cpx = nwg >> 3;
  const int swz = (lin & 7) * cpx + (lin >> 3);
  const int bx = swz % gx;
  int by = swz / gx;
  int koff = 0, Kloc = K;
  if (ksplit == 2) {
    const int mh = gridDim.y >> 1;
    if (by >= mh) { by -= mh; koff = K >> 1; C = Cb; Calt = Cbalt; }
    Kloc = K >> 1;
  }
  const int col0 = bx * 128;
  int r0 = by * BM;
  const f16* Ause = A;
  TC* Cuse = C;
  if (r0 >= split) { Ause = Aalt; Cuse = Calt; r0 -= split; }

  // staging: thread t covers LDS row (t>>2) (+64 for BM=128's 2nd A gload
  // and B's 2nd gload), chunk t&3; fetches global chunk (t&3)^((row>>1)&3)
  const int strow = tid >> 2;
  const int schunk = tid & 3;
  const int sw = schunk ^ ((strow >> 1) & 3);
  const f16* gA0 = Ause + (size_t)(r0 + strow) * K + koff + sw * 8;
  const f16* gB0 = BT + (size_t)(col0 + strow) * K + koff + sw * 8;
  f16* ldsA0 = &sA[0][0] + (size_t)w * 512;
  f16* ldsB0 = &sB[0][0] + (size_t)w * 512;

  // ds_read offsets (f16 elems): row rt, swizzled chunk quad^((rt>>1)&3)
  // (rows ≡ m16 mod 16, so (m16>>1)&3 == (row>>1)&3 for both BM variants)
  const int qs = quad ^ ((m16 >> 1) & 3);
  int aoff[MR], boff[4];
#pragma unroll
  for (int i = 0; i < MR; ++i)
    aoff[i] = (wr * (BM / 2) + i * 16 + m16) * 32 + qs * 8;
#pragma unroll
  for (int i = 0; i < 4; ++i)
    boff[i] = (wc * 64 + i * 16 + m16) * 32 + qs * 8;

  const int nkt = Kloc >> 5;
  f32x4 acc[MR][4] = {};

  auto stage = [&](int buf, int t) {
    const int k0 = t << 5;
    const size_t bufoA = (size_t)buf * (BM * 32);
    const size_t bufoB = (size_t)buf * 4096;
    gload16(gA0 + k0, ldsA0 + bufoA);
    if constexpr (BM == 128)
      gload16(gA0 + (size_t)64 * K + k0, ldsA0 + bufoA + 2048);
    gload16(gB0 + k0, ldsB0 + bufoB);
    gload16(gB0 + (size_t)64 * K + k0, ldsB0 + bufoB + 2048);
  };

  stage(0, 0);
  int cur = 0;
  for (int t = 0; t < nkt; ++t) {
    // own loads for tile t (issued one full k-step ago) landed
    asm volatile("s_waitcnt vmcnt(0)" ::: "memory");
    __builtin_amdgcn_s_barrier();  // all waves' tile-t loads visible
    if (t + 1 < nkt) stage(cur ^ 1, t + 1);  // buf read at t-1; all past it
    f16x8 af[MR], bfr[4];
#pragma unroll
    for (int i = 0; i < MR; ++i) af[i] = *(const f16x8*)&sA[cur][aoff[i]];
#pragma unroll
    for (int i = 0; i < 4; ++i) bfr[i] = *(const f16x8*)&sB[cur][boff[i]];
    __builtin_amdgcn_s_setprio(1);
#pragma unroll
    for (int mi = 0; mi < MR; ++mi)
#pragma unroll
      for (int ni = 0; ni < 4; ++ni)
        acc[mi][ni] = __builtin_amdgcn_mfma_f32_16x16x32_f16(
            af[mi], bfr[ni], acc[mi][ni], 0, 0, 0);
    __builtin_amdgcn_s_setprio(0);
    cur ^= 1;
  }

  // Epilogue: D layout col=lane&15, row=quad*4+rg (16x16 family)
#pragma unroll
  for (int mi = 0; mi < MR; ++mi) {
    const int row = r0 + wr * (BM / 2) + mi * 16 + quad * 4;
#pragma unroll
    for (int ni = 0; ni < 4; ++ni) {
      const int col = col0 + wc * 64 + ni * 16 + m16;
      const float bv = bias ? bias[col] : 0.f;
#pragma unroll
      for (int rg = 0; rg < 4; ++rg) {
        float vv = acc[mi][ni][rg] + bv;
        if (relu) vv = vv > 0.f ? vv : 0.f;
        store_c(&Cuse[(size_t)(row + rg) * N + col], vv);
      }
    }
  }
}

// ---------------- Fused flash-MFMA attention (unchanged from R8) ----------------
__global__ __launch_bounds__(256, 4) void fattn_kernel(
    const bf16* __restrict__ qkvp,  // [1536*4, 3072] rows k*B+b, bf16
    const bf16* __restrict__ rhp,   // [1536, 1024] bf16
    const float* __restrict__ u, const float* __restrict__ v,
    f16* __restrict__ ctxh) {       // [4096, 1024] f16
  const int lin = blockIdx.x;      // 1024 blocks
  const int p = lin & 63;          // (b,h) pair; p%8 = XCD
  const int b = p & 3, h = p >> 2;
  // magic square: residue classes {k, k+4, k+8, k+12} all sum to 30
  const int permv[16] = {15, 14, 13, 12, 10, 11, 8, 9, 4, 5, 6, 7, 1, 0, 3, 2};
  const int i0 = permv[lin >> 6] * 64;
  const int tid = threadIdx.x;
  const int w = tid >> 6, lane = tid & 63;
  const int quad = lane >> 4, m16 = lane & 15;

  __shared__ short sVt[64 * 40];   // V^T tile: [d][j]
  __shared__ short sR[96 * 72];    // R ring buffer (phys = (32kt+trel)%96)
  __shared__ short sProb[64 * 40]; // probs bf16, per-wave strips

  const short* qkv = (const short*)qkvp;
  const short* rh  = (const short*)rhp;

  // Per-lane Q fragments: aQu = q+u (AC), aQv = q+v (BD). Rows w*16+m16.
  short8 aQu0, aQu1, aQv0, aQv1;
  {
    const size_t qro = ((size_t)(512 + i0 + w * 16 + m16) * 4 + b) * 3072 + h * 64 + quad * 8;
    short8 qa = *(const short8*)&qkv[qro];
    short8 qb = *(const short8*)&qkv[qro + 32];
    const float* up = u + h * 64 + quad * 8;
    const float* vp = v + h * 64 + quad * 8;
#pragma unroll
    for (int j = 0; j < 8; ++j) {
      const float qaf = b2f(qa[j]), qbf = b2f(qb[j]);
      aQu0[j] = f2b(qaf + up[j]);
      aQu1[j] = f2b(qbf + up[j + 32]);
      aQv0[j] = f2b(qaf + vp[j]);
      aQv1[j] = f2b(qbf + vp[j + 32]);
    }
  }

  // staging maps
  const int st_row = tid >> 3, st_d0 = (tid & 7) * 8;        // R chunk (32 rows)
  const int vj = lane & 31, vd0 = w * 16 + (lane >> 5) * 8;  // V^T scatter

  // Initial R window fill: trel 0..95, t = 960-i0+trel (never negative)
#pragma unroll
  for (int p_ = 0; p_ < 3; ++p_) {
    int t = 960 - i0 + p_ * 32 + st_row;
    t = t > 1535 ? 1535 : t;  // clamped rows only feed masked elems
    *(short8*)&sR[(p_ * 32 + st_row) * 72 + st_d0] =
        *(const short8*)&rh[(size_t)t * 1024 + h * 64 + st_d0];
  }
  // V tile 0 scatter
  {
    short8 v8 = *(const short8*)&qkv[((size_t)vj * 4 + b) * 3072 + 2048 + h * 64 + vd0];
#pragma unroll
    for (int q = 0; q < 8; ++q) sVt[(vd0 + q) * 40 + vj] = v8[q];
  }
  // K fragments tile 0 (per-lane, direct from global)
  short8 rKf[4];
#pragma unroll
  for (int n0i = 0; n0i < 2; ++n0i) {
    const size_t kro = ((size_t)(n0i * 16 + m16) * 4 + b) * 3072 + 1024 + h * 64 + quad * 8;
    rKf[n0i * 2] = *(const short8*)&qkv[kro];
    rKf[n0i * 2 + 1] = *(const short8*)&qkv[kro + 32];
  }

  short8 ones;
#pragma unroll
  for (int q = 0; q < 8; ++q) ones[q] = (short)0x3F80;  // bf16 1.0

  f32x4 O[4] = {};
  f32x4 L = {};
  float m = -1e30f;
  int bk = 0;               // (32*kt) % 96: ring base; also write slot base
  int tnext = 1056 - i0;    // t-base of chunk staged for tile kt+1

  const int n_kt = ((i0 + 575) >> 5) + 1;  // valid j <= i+512, i <= i0+63
  for (int kt = 0; kt < n_kt; ++kt) {
    const int j0 = kt * 32;
    const bool pf = (kt + 1 < n_kt);
    __syncthreads();  // staged LDS writes visible

    // prefetch next tile: V + new R chunk into regs (latency hidden)
    short8 nV, nR;
    if (pf) {
      nV = *(const short8*)&qkv[((size_t)(j0 + 32 + vj) * 4 + b) * 3072 + 2048 + h * 64 + vd0];
      int t = tnext + st_row;
      t = t > 1535 ? 1535 : t;
      nR = *(const short8*)&rh[(size_t)t * 1024 + h * 64 + st_d0];
    }

    // AC tiles from register K fragments
    f32x4 ac[2];
#pragma unroll
    for (int n0i = 0; n0i < 2; ++n0i) {
      f32x4 a = {};
      a = __builtin_amdgcn_mfma_f32_16x16x32_bf16(aQu0, rKf[n0i * 2], a, 0, 0, 0);
      a = __builtin_amdgcn_mfma_f32_16x16x32_bf16(aQu1, rKf[n0i * 2 + 1], a, 0, 0, 0);
      ac[n0i] = a;
    }
    // prefetch next K fragments (regs free after AC)
    if (pf) {
#pragma unroll
      for (int n0i = 0; n0i < 2; ++n0i) {
        const size_t kro = ((size_t)(j0 + 32 + n0i * 16 + m16) * 4 + b) * 3072 + 1024 + h * 64 + quad * 8;
        rKf[n0i * 2] = *(const short8*)&qkv[kro];
        rKf[n0i * 2 + 1] = *(const short8*)&qkv[kro + 32];
      }
    }

    // P = Qv.R tiles (ring rows), wave trel window [48-16w, 94-16w]
    f32x4 pb[3];
#pragma unroll
    for (int pt = 0; pt < 3; ++pt) {
      const int p0 = 48 - 16 * w + 16 * pt;
      int pr = bk + p0;
      if (pr >= 96) pr -= 96;
      int row = pr + m16;
      if (row >= 96) row -= 96;
      const short8 bR0 = *(const short8*)&sR[row * 72 + quad * 8];
      const short8 bR1 = *(const short8*)&sR[row * 72 + 32 + quad * 8];
      f32x4 pf_ = {};
      pf_ = __builtin_amdgcn_mfma_f32_16x16x32_bf16(aQv0, bR0, pf_, 0, 0, 0);
      pf_ = __builtin_amdgcn_mfma_f32_16x16x32_bf16(aQv1, bR1, pf_, 0, 0, 0);
      pb[pt] = pf_;
    }

    // Scores; rel-shift P gather via in-wave shuffles (same quad, same rg)
    float S0[4], S1[4];
    float mxl = -1e30f;
#pragma unroll
    for (int rg = 0; rg < 4; ++rg) {
      const int rloc = quad * 4 + rg;
      const int irow = i0 + w * 16 + rloc;
      const int c0 = m16 - rloc + 15;  // in [0,30]
      const int src = (lane & 48) | (c0 & 15);
      const float t0 = __shfl(pb[0][rg], src);
      const float t1 = __shfl(pb[1][rg], src);
      const float t2 = __shfl(pb[2][rg], src);
      const float p0v = (c0 < 16) ? t0 : t1;
      const float p1v = (c0 < 16) ? t1 : t2;
      float s0 = (ac[0][rg] + p0v) * 0.125f;
      float s1 = (ac[1][rg] + p1v) * 0.125f;
      if (j0 + m16 > irow + 512) s0 = -1e30f;
      if (j0 + 16 + m16 > irow + 512) s1 = -1e30f;
      S0[rg] = s0;
      S1[rg] = s1;
      mxl = fmaxf(mxl, fmaxf(s0, s1));
    }
    // wave-shared max (valid upper bound for all 16 rows of this wave)
    mxl = fmaxf(mxl, __shfl_xor(mxl, 1));
    mxl = fmaxf(mxl, __shfl_xor(mxl, 2));
    mxl = fmaxf(mxl, __shfl_xor(mxl, 4));
    mxl = fmaxf(mxl, __shfl_xor(mxl, 8));
    mxl = fmaxf(mxl, __shfl_xor(mxl, 16));
    mxl = fmaxf(mxl, __shfl_xor(mxl, 32));
    // defer-max (T13): rescale only when max grew materially (wave-uniform)
    if (mxl > m + 8.f) {
      const float al = __expf(m - mxl);
      m = mxl;
#pragma unroll
      for (int d0i = 0; d0i < 4; ++d0i)
#pragma unroll
        for (int rg = 0; rg < 4; ++rg) O[d0i][rg] *= al;
#pragma unroll
      for (int rg = 0; rg < 4; ++rg) L[rg] *= al;
    }
#pragma unroll
    for (int rg = 0; rg < 4; ++rg) {
      const int rloc = quad * 4 + rg;
      const float e0 = __expf(S0[rg] - m);
      const float e1 = __expf(S1[rg] - m);
      unsigned pk;
      asm("v_cvt_pk_bf16_f32 %0, %1, %2" : "=v"(pk) : "v"(e0), "v"(e1));
      sProb[(w * 16 + rloc) * 40 + m16] = (short)(pk & 0xffff);
      sProb[(w * 16 + rloc) * 40 + 16 + m16] = (short)(pk >> 16);
    }

    // PV + row-sum accumulation (ones B-fragment broadcasts l to all cols)
    const short8 aP = *(const short8*)&sProb[(w * 16 + m16) * 40 + quad * 8];
    L = __builtin_amdgcn_mfma_f32_16x16x32_bf16(aP, ones, L, 0, 0, 0);
#pragma unroll
    for (int d0i = 0; d0i < 4; ++d0i) {
      const short8 bV = *(const short8*)&sVt[(d0i * 16 + m16) * 40 + quad * 8];
      O[d0i] = __builtin_amdgcn_mfma_f32_16x16x32_bf16(aP, bV, O[d0i], 0, 0, 0);
    }

    __syncthreads();  // all LDS reads done before restage
    if (pf) {
#pragma unroll
      for (int q = 0; q < 8; ++q) sVt[(vd0 + q) * 40 + vj] = nV[q];
      *(short8*)&sR[(bk + st_row) * 72 + st_d0] = nR;  // new chunk slot
    }
    bk += 32;
    if (bk >= 96) bk = 0;
    tnext += 32;
  }

  // Epilogue: ctxh[i*B+b][h*64+d] = (f16)(O/L)
#pragma unroll
  for (int d0i = 0; d0i < 4; ++d0i) {
#pragma unroll
    for (int rg = 0; rg < 4; ++rg) {
      const int irow = i0 + w * 16 + quad * 4 + rg;
      ctxh[((size_t)irow * 4 + b) * 1024 + h * 64 + d0i * 16 + m16] =
          (f16)(O[d0i][rg] / L[rg]);
    }
  }
}

// ---------------- LayerNorms ----------------
// ln1: x = LN(ya + yb + inputs); emits f16 x_h only.
__global__ __launch_bounds__(256) void ln1_kernel(
    const f16* __restrict__ ya, const f16* __restrict__ yb,
    const float* __restrict__ inp, const float* __restrict__ g,
    const float* __restrict__ beta, f16* __restrict__ xh) {
  const int r = blockIdx.x, tid = threadIdx.x;
  __shared__ float red[256];
  float t[4];
  float s = 0.f;
#pragma unroll
  for (int q = 0; q < 4; ++q) {
    int c = tid + q * 256;
    t[q] = (float)ya[(size_t)r * DM + c] + (float)yb[(size_t)r * DM + c] +
           inp[(size_t)r * DM + c];
    s += t[q];
  }
  red[tid] = s;
  __syncthreads();
  for (int st = 128; st > 0; st >>= 1) {
    if (tid < st) red[tid] += red[tid + st];
    __syncthreads();
  }
  const float mean = red[0] * (1.f / DM);
  __syncthreads();
  float vs = 0.f;
#pragma unroll
  for (int q = 0; q < 4; ++q) {
    float d0 = t[q] - mean;
    vs += d0 * d0;
  }
  red[tid] = vs;
  __syncthreads();
  for (int st = 128; st > 0; st >>= 1) {
    if (tid < st) red[tid] += red[tid + st];
    __syncthreads();
  }
  const float rstd = rsqrtf(red[0] * (1.f / DM) + 1e-5f);
#pragma unroll
  for (int q = 0; q < 4; ++q) {
    int c = tid + q * 256;
    const float val = (t[q] - mean) * rstd * g[c] + beta[c];
    xh[(size_t)r * DM + c] = (f16)val;
  }
}

// ln2: out = LN(x_h + y2a + y2b + b2), fp32 out.
__global__ __launch_bounds__(256) void ln2_kernel(
    const f16* __restrict__ xh, const f16* __restrict__ y2a,
    const f16* __restrict__ y2b, const float* __restrict__ b2,
    const float* __restrict__ g, const float* __restrict__ beta,
    float* __restrict__ out) {
  const int r = blockIdx.x, tid = threadIdx.x;
  __shared__ float red[256];
  float t[4];
  float s = 0.f;
#pragma unroll
  for (int q = 0; q < 4; ++q) {
    int c = tid + q * 256;
    t[q] = (float)xh[(size_t)r * DM + c] + (float)y2a[(size_t)r * DM + c] +
           (float)y2b[(size_t)r * DM + c] + b2[c];
    s += t[q];
  }
  red[tid] = s;
  __syncthreads();
  for (int st = 128; st > 0; st >>= 1) {
    if (tid < st) red[tid] += red[tid + st];
    __syncthreads();
  }
  const float mean = red[0] * (1.f / DM);
  __syncthreads();
  float vs = 0.f;
#pragma unroll
  for (int q = 0; q < 4; ++q) {
    float d0 = t[q] - mean;
    vs += d0 * d0;
  }
  red[tid] = vs;
  __syncthreads();
  for (int st = 128; st > 0; st >>= 1) {
    if (tid < st) red[tid] += red[tid + st];
    __syncthreads();
  }
  const float rstd = rsqrtf(red[0] * (1.f / DM) + 1e-5f);
#pragma unroll
  for (int q = 0; q < 4; ++q) {
    int c = tid + q * 256;
    out[(size_t)r * DM + c] = (t[q] - mean) * rstd * g[c] + beta[c];
  }
}

extern "C" void kernel_launch(void* const* d_in, const int* in_sizes, int n_in,
                              void* d_out, int out_size, void* d_ws, size_t ws_size,
                              hipStream_t stream) {
  const int o = (n_in >= 17) ? 1 : 0;
  const float* inputs = (const float*)d_in[0];
  const float* r      = (const float*)d_in[1];
  const float* u      = (const float*)d_in[2];
  const float* v      = (const float*)d_in[3];
  const float* memp   = (const float*)d_in[4];
  const float* W_qkv  = (const float*)d_in[5 + o];
  const float* W_r    = (const float*)d_in[6 + o];
  const float* W_o    = (const float*)d_in[7 + o];
  const float* ln1_g  = (const float*)d_in[8 + o];
  const float* ln1_b  = (const float*)d_in[9 + o];
  const float* ln2_g  = (const float*)d_in[10 + o];
  const float* ln2_b  = (const float*)d_in[11 + o];
  const float* W1     = (const float*)d_in[12 + o];
  const float* b1     = (const float*)d_in[13 + o];
  const float* W2     = (const float*)d_in[14 + o];
  const float* b2     = (const float*)d_in[15 + o];

  // Workspace liveness (peak 52,428,800 B) — unchanged from R7/R8
  char* ws = (char*)d_ws;
  f16*  WqkvT = (f16*)(ws);
  f16*  r16   = (f16*)(ws + 6291456);
  f16*  WrT   = (f16*)(ws + 9437184);
  bf16* qkv   = (bf16*)(ws + 11534336);
  bf16* rh    = (bf16*)(ws + 49283072);
  f16*  cat_h = (f16*)d_out;
  f16*  ctx_h = (f16*)(ws);
  f16*  WoT   = (f16*)(ws + 8388608);
  f16*  ya    = (f16*)(ws + 10485760);
  f16*  yb    = (f16*)(ws + 18874368);
  f16*  x_h   = (f16*)(ws + 27262976);
  f16*  W1T   = (f16*)(ws + 35651584);
  f16*  h_hi  = (f16*)(ws);
  f16*  h_lo  = (f16*)d_out;
  f16*  W2T   = (f16*)(ws + 44040192);
  f16*  y2a   = (f16*)(ws + 18874368);
  f16*  y2b   = (f16*)(ws + 35651584);

  dim3 blk(256);
  const int BIG = 1 << 30;

  // --- phase 1: converts + QKV/R projections + attention ---
  convh3_kernel<<<dim3(7680), blk, 0, stream>>>(
      memp, inputs, r, cat_h, cat_h + (size_t)2048 * 1024, r16);
  convTm_kernel<<<dim3(1024), blk, 0, stream>>>(
      W_qkv, WqkvT, 1024, 3072, 48,
      768, W_r, WrT, 1024, 1024, 16,
      1024, nullptr, nullptr, 0, 0, 1);
  // QKV split: mem rows (0..2047) only need k,v cols [1024,3072) — BM=64
  // grid 512 (2 blocks/CU); input rows (2048..6143) all cols — BM=128.
  hgemm_kernel<bf16, 64><<<dim3(16, 32), blk, 0, stream>>>(
      cat_h, WqkvT + (size_t)1024 * 1024, qkv + 1024, 3072, 1024, nullptr, 0,
      nullptr, nullptr, BIG, nullptr, nullptr, 1);
  hgemm_kernel<bf16, 128><<<dim3(24, 32), blk, 0, stream>>>(
      cat_h + (size_t)2048 * 1024, WqkvT, qkv + (size_t)2048 * 3072,
      3072, 1024, nullptr, 0,
      nullptr, nullptr, BIG, nullptr, nullptr, 1);
  hgemm_kernel<bf16, 64><<<dim3(8, 24), blk, 0, stream>>>(
      r16, WrT, rh, 1024, 1024, nullptr, 0,
      nullptr, nullptr, BIG, nullptr, nullptr, 1);
  fattn_kernel<<<dim3(1024), blk, 0, stream>>>(qkv, rh, u, v, ctx_h);

  // --- phase 2: weight transposes + output proj + LN1 + MLP + LN2 ---
  convTm_kernel<<<dim3(2304), blk, 0, stream>>>(
      W_o, WoT, 1024, 1024, 16,
      256, W1, W1T, 1024, 4096, 64,
      1280, W2, W2T, 4096, 1024, 16);
  hgemm_kernel<f16, 64><<<dim3(8, 128), blk, 0, stream>>>(
      ctx_h, WoT, ya, 1024, 1024, nullptr, 0,
      nullptr, nullptr, BIG, yb, nullptr, 2);
  ln1_kernel<<<dim3(4096), blk, 0, stream>>>(ya, yb, inputs, ln1_g, ln1_b, x_h);
  hgemm_kernel<f16, 128><<<dim3(32, 32), blk, 0, stream>>>(
      x_h, W1T, h_lo, 4096, 1024, b1, 1,
      x_h + (size_t)2048 * 1024, h_hi, 2048, nullptr, nullptr, 1);
  hgemm_kernel<f16, 64><<<dim3(8, 128), blk, 0, stream>>>(
      h_lo, W2T, y2a, 1024, 4096, nullptr, 0,
      h_hi, y2a + (size_t)2048 * 1024, 2048,
      y2b, y2b + (size_t)2048 * 1024, 2);
  ln2_kernel<<<dim3(4096), blk, 0, stream>>>(x_h, y2a, y2b, b2, ln2_g, ln2_b,
                                             (float*)d_out);
}